// Round 4
// baseline (592.126 us; speedup 1.0000x reference)
//
#include <hip/hip_runtime.h>
#include <math.h>

#define NN 8192
#define EE 262144
#define GG 64
#define CC 10
#define KK1 4096
#define KK2 2048
#define KK3 1024

__device__ __forceinline__ float eluf(float x) { return x > 0.f ? x : expm1f(x); }
__device__ __forceinline__ float sigf(float x) { return 1.f / (1.f + expf(-x)); }
__device__ __forceinline__ unsigned f2s(float f) {
    unsigned u = __float_as_uint(f);
    return (u & 0x80000000u) ? ~u : (u | 0x80000000u);
}

// ---- edge init: dedup representative flag + weighted in-degree (level 1) ----
__global__ void k_edge_init(const int* __restrict__ ei, unsigned* __restrict__ bitmap,
                            unsigned char* __restrict__ rep, int* __restrict__ cnt1) {
    int e = blockIdx.x * blockDim.x + threadIdx.x;
    if (e >= EE) return;
    int s = ei[e], d = ei[EE + e];
    unsigned key = ((unsigned)s << 13) | (unsigned)d;   // N = 8192 = 2^13
    unsigned old = atomicOr(&bitmap[key >> 5], 1u << (key & 31u));
    rep[e] = ((old >> (key & 31u)) & 1u) ? 0 : 1;
    atomicAdd(&cnt1[d], 1);
}

__global__ void k_dinv(const int* __restrict__ cnt, float* __restrict__ dinv, int n) {
    int j = blockIdx.x * blockDim.x + threadIdx.x;
    if (j < n) dinv[j] = 1.f / sqrtf((float)(cnt[j] + 1));
}

// ---- exclusive prefix scan over n<=8192 counts -> rowstart[n+1] and cursor copy ----
__global__ void k_prefix(const int* __restrict__ cnt, int* __restrict__ rs,
                         int* __restrict__ cur, int n) {
    __shared__ int ts[1024];
    int tid = threadIdx.x;
    int ept = n >> 10;                 // 1,2,4,8
    int base = tid * ept;
    int local[8];
    int s = 0;
    for (int i = 0; i < ept; i++) { local[i] = cnt[base + i]; s += local[i]; }
    ts[tid] = s;
    __syncthreads();
    for (int off = 1; off < 1024; off <<= 1) {
        int v = ts[tid];
        int add = (tid >= off) ? ts[tid - off] : 0;
        __syncthreads();
        ts[tid] = v + add;
        __syncthreads();
    }
    int run = (tid == 0) ? 0 : ts[tid - 1];
    for (int i = 0; i < ept; i++) { rs[base + i] = run; cur[base + i] = run; run += local[i]; }
    if (tid == 1023) rs[n] = run;
}

// ---- level-1 CSR scatter: all edges, with multiplicity ----
__global__ void k_csr_l1(const int* __restrict__ ei, int* __restrict__ cur,
                         int* __restrict__ csr) {
    int e = blockIdx.x * blockDim.x + threadIdx.x;
    if (e >= EE) return;
    csr[atomicAdd(&cur[ei[EE + e]], 1)] = ei[e];
}

// ---- pooled level: degree count (dedup'd, both endpoints selected) ----
__global__ void k_deg_lvl(const int* __restrict__ ei, const unsigned char* __restrict__ rep,
                          const int* __restrict__ pos, int* __restrict__ cnt) {
    int e = blockIdx.x * blockDim.x + threadIdx.x;
    if (e >= EE || !rep[e]) return;
    int ps = pos[ei[e]], pd = pos[ei[EE + e]];
    if (ps >= 0 && pd >= 0) atomicAdd(&cnt[pd], 1);
}
// ---- pooled level: CSR scatter ----
__global__ void k_csr_lvl(const int* __restrict__ ei, const unsigned char* __restrict__ rep,
                          const int* __restrict__ pos, int* __restrict__ cur,
                          int* __restrict__ csr) {
    int e = blockIdx.x * blockDim.x + threadIdx.x;
    if (e >= EE || !rep[e]) return;
    int ps = pos[ei[e]], pd = pos[ei[EE + e]];
    if (ps >= 0 && pd >= 0) csr[atomicAdd(&cur[pd], 1)] = ps;
}

// ---- tiled register-blocked GEMM: Y[M,F] = X[M,K] @ W[K,F] ----
// 256 threads; tile BM x BN; each thread TM x 4 outputs; K staged in chunks of 32.
// Requires: M%BM==0, K%32==0, F%BN==0, (BN/4)*(BM/TM)==256.
template<int BM, int BN, int TM>
__global__ void k_gemm(const float* __restrict__ X, const float* __restrict__ W,
                       float* __restrict__ Y, int M, int K, int F) {
    constexpr int TX = BN / 4;
    __shared__ float Xs[BM][33];       // [m][k], broadcast reads, conflict-free
    __shared__ float Ws[32][BN + 4];   // [k][n], pitch%4==0 -> float4-aligned
    int tid = threadIdx.x;
    int txn = tid % TX, tym = tid / TX;
    int m0 = blockIdx.x * BM, n0 = blockIdx.y * BN;
    float acc[TM][4];
#pragma unroll
    for (int i = 0; i < TM; i++)
#pragma unroll
        for (int j = 0; j < 4; j++) acc[i][j] = 0.f;
    for (int k0 = 0; k0 < K; k0 += 32) {
        for (int idx = tid; idx < BM * 32; idx += 256) {
            int r = idx >> 5, c = idx & 31;
            Xs[r][c] = X[(size_t)(m0 + r) * K + k0 + c];
        }
        for (int idx = tid; idx < 32 * BN; idx += 256) {
            int r = idx / BN, c = idx % BN;
            Ws[r][c] = W[(size_t)(k0 + r) * F + n0 + c];
        }
        __syncthreads();
#pragma unroll 4
        for (int kk = 0; kk < 32; kk++) {
            float4 wv = *(const float4*)&Ws[kk][txn * 4];
#pragma unroll
            for (int i = 0; i < TM; i++) {
                float xv = Xs[tym * TM + i][kk];
                acc[i][0] += xv * wv.x;
                acc[i][1] += xv * wv.y;
                acc[i][2] += xv * wv.z;
                acc[i][3] += xv * wv.w;
            }
        }
        __syncthreads();
    }
#pragma unroll
    for (int i = 0; i < TM; i++) {
        float4 v = make_float4(acc[i][0], acc[i][1], acc[i][2], acc[i][3]);
        *(float4*)&Y[(size_t)(m0 + tym * TM + i) * F + n0 + txn * 4] = v;
    }
}

// ---- CSR gather propagate + self term + bias + elu, all fused ----
__global__ void k_prop_csr(const int* __restrict__ csr, const int* __restrict__ rs,
                           const float* __restrict__ dinv, const float* __restrict__ xW,
                           const float* __restrict__ b, float* __restrict__ xout,
                           int n, int logF) {
    int t = blockIdx.x * blockDim.x + threadIdx.x;
    if (t >= (n << logF)) return;
    int d = t >> logF, f = t & ((1 << logF) - 1);
    int j0 = rs[d], j1 = rs[d + 1];
    float dd = dinv[d];
    float sum = dd * xW[t];
    for (int j = j0; j < j1; j++) {
        int s = csr[j];
        sum += dinv[s] * xW[(s << logF) + f];
    }
    xout[t] = eluf(dd * sum + b[f]);
}

// ---- score[r] = dot(x[r], p) / ||p|| ----
__global__ void k_score(const float* __restrict__ x, const float* __restrict__ p,
                        int n, int F, float* __restrict__ score) {
    int r = blockIdx.x * blockDim.x + threadIdx.x;
    if (r >= n) return;
    float nrm = 0.f, dp = 0.f;
    const float* xr = x + (size_t)r * F;
    for (int k = 0; k < F; k++) { nrm += p[k] * p[k]; dp += xr[k] * p[k]; }
    score[r] = dp / sqrtf(nrm);
}

// ==== parallel bitonic top-k (descending, ties -> smaller index; exact jax order) ====
__global__ void k_sort_chunk(const float* __restrict__ score,
                             unsigned long long* __restrict__ keys,
                             int last, int k, int* __restrict__ out_idx) {
    __shared__ unsigned long long sk[2048];
    int base = blockIdx.x << 11;
    int tid = threadIdx.x;
    for (int i = tid; i < 2048; i += 1024) {
        int gi = base + i;
        sk[i] = ((unsigned long long)f2s(score[gi]) << 32) | (unsigned)(~gi);
    }
    __syncthreads();
    for (int sz = 2; sz <= 2048; sz <<= 1) {
        for (int st = sz >> 1; st > 0; st >>= 1) {
            int i = ((tid & ~(st - 1)) << 1) | (tid & (st - 1));
            int j = i | st;
            unsigned long long a = sk[i], b = sk[j];
            bool desc = (((base + i) & sz) == 0);
            if (desc ? (a < b) : (a > b)) { sk[i] = b; sk[j] = a; }
            __syncthreads();
        }
    }
    if (last) {
        for (int i = tid; i < 2048; i += 1024) {
            int gi = base + i;
            if (gi < k) out_idx[gi] = (int)(~(unsigned)(sk[i] & 0xFFFFFFFFu));
        }
    } else {
        for (int i = tid; i < 2048; i += 1024) keys[base + i] = sk[i];
    }
}

__global__ void k_gpass(unsigned long long* __restrict__ keys, int sz, int st) {
    int p = blockIdx.x * blockDim.x + threadIdx.x;
    int i = ((p & ~(st - 1)) << 1) | (p & (st - 1));
    int j = i | st;
    unsigned long long a = keys[i], b = keys[j];
    bool desc = ((i & sz) == 0);
    if (desc ? (a < b) : (a > b)) { keys[i] = b; keys[j] = a; }
}

__global__ void k_lmerge(unsigned long long* __restrict__ keys, int sz,
                         int last, int k, int* __restrict__ out_idx) {
    __shared__ unsigned long long sk[2048];
    int base = blockIdx.x << 11;
    int tid = threadIdx.x;
    for (int i = tid; i < 2048; i += 1024) sk[i] = keys[base + i];
    __syncthreads();
    for (int st = 1024; st > 0; st >>= 1) {
        int i = ((tid & ~(st - 1)) << 1) | (tid & (st - 1));
        int j = i | st;
        unsigned long long a = sk[i], b = sk[j];
        bool desc = (((base + i) & sz) == 0);
        if (desc ? (a < b) : (a > b)) { sk[i] = b; sk[j] = a; }
        __syncthreads();
    }
    if (last) {
        for (int i = tid; i < 2048; i += 1024) {
            int gi = base + i;
            if (gi < k) out_idx[gi] = (int)(~(unsigned)(sk[i] & 0xFFFFFFFFu));
        }
    } else {
        for (int i = tid; i < 2048; i += 1024) keys[base + i] = sk[i];
    }
}

__global__ void k_pos2(const int* __restrict__ i2, int* __restrict__ pos2) {
    int r = blockIdx.x * blockDim.x + threadIdx.x;
    if (r < KK1) pos2[i2[r]] = r;
}
__global__ void k_pos3(const int* __restrict__ i2, const int* __restrict__ i4,
                       int* __restrict__ pos3) {
    int q = blockIdx.x * blockDim.x + threadIdx.x;
    if (q < KK2) pos3[i2[i4[q]]] = q;
}
__global__ void k_pos4(const int* __restrict__ i2, const int* __restrict__ i4,
                       const int* __restrict__ i6, int* __restrict__ pos4) {
    int r = blockIdx.x * blockDim.x + threadIdx.x;
    if (r < KK3) pos4[i2[i4[i6[r]]]] = r;
}

// ---- pooled features: xout[r] = elu(x[idx[r]] * sigmoid(score[idx[r]])) ----
__global__ void k_poolx(const float* __restrict__ x, const float* __restrict__ score,
                        const int* __restrict__ idx, int k, int F, float* __restrict__ xout) {
    int t = blockIdx.x * blockDim.x + threadIdx.x;
    if (t >= k * F) return;
    int r = t / F, f = t - r * F;
    int j = idx[r];
    xout[t] = eluf(x[(size_t)j * F + f] * sigf(score[j]));
}

// ---- unpool scatter (left part of concat), with elu ----
__global__ void k_scat(const float* __restrict__ xin, const int* __restrict__ idx,
                       float* __restrict__ xcat, int k, int Fl, int Fcat) {
    int t = blockIdx.x * blockDim.x + threadIdx.x;
    if (t >= k * Fl) return;
    int r = t / Fl, f = t - r * Fl;
    xcat[(size_t)idx[r] * Fcat + f] = eluf(xin[t]);
}
// ---- right part of concat, with elu ----
__global__ void k_catr(const float* __restrict__ xr, float* __restrict__ xcat,
                       int n, int Fr, int Fcat, int off) {
    int t = blockIdx.x * blockDim.x + threadIdx.x;
    if (t >= n * Fr) return;
    int q = t / Fr, f = t - q * Fr;
    xcat[(size_t)q * Fcat + off + f] = eluf(xr[t]);
}

// ---- graph segment boundaries from sorted batch ----
__global__ void k_gbounds(const int* __restrict__ batch, int* __restrict__ gstart) {
    int j = blockIdx.x * blockDim.x + threadIdx.x;
    if (j >= NN) return;
    int g = batch[j];
    int prev = (j == 0) ? -1 : batch[j - 1];
    for (int gg = prev + 1; gg <= g; gg++) gstart[gg] = j;
    if (j == NN - 1)
        for (int gg = g + 1; gg <= GG; gg++) gstart[gg] = NN;
}

// ---- atomic-free segment max/sum/count: one block per graph ----
__global__ void k_seg2(const float* __restrict__ x13, const int* __restrict__ gstart,
                       float* __restrict__ gmaxf, float* __restrict__ gsum,
                       int* __restrict__ gcnt) {
    __shared__ float sm[8][32], ss[8][32];
    int g = blockIdx.x;
    int j0 = gstart[g], j1 = gstart[g + 1];
    int t = threadIdx.x;
    int f = t & 31, r = t >> 5;
    float m = -INFINITY, s = 0.f;
    for (int j = j0 + r; j < j1; j += 8) {
        float v = x13[(j << 5) + f];
        m = fmaxf(m, v);
        s += v;
    }
    sm[r][f] = m; ss[r][f] = s;
    __syncthreads();
    if (t < 32) {
        float mm = sm[0][t], sss = ss[0][t];
        for (int i = 1; i < 8; i++) { mm = fmaxf(mm, sm[i][t]); sss += ss[i][t]; }
        gmaxf[(g << 5) + t] = mm;
        gsum[(g << 5) + t] = sss;
        if (t == 0) gcnt[g] = j1 - j0;
    }
}

// ---- head ----
__global__ void k_head(const float* __restrict__ gmaxf, const float* __restrict__ gsum,
                       const int* __restrict__ gcnt, const float* __restrict__ Wl1,
                       const float* __restrict__ Wc, const float* __restrict__ bc,
                       float* __restrict__ out) {
    __shared__ float h0[GG * 64];
    __shared__ float h1[GG * 64];
    __shared__ float lg[GG * CC];
    int tid = threadIdx.x;
    for (int t = tid; t < GG * 64; t += blockDim.x) {
        int g = t >> 6, c = t & 63;
        float v;
        if (c < 32) v = gmaxf[(g << 5) + c];
        else v = gsum[(g << 5) + (c - 32)] / (float)gcnt[g];
        h0[t] = eluf(v);
    }
    __syncthreads();
    for (int t = tid; t < GG * 64; t += blockDim.x) {
        int g = t >> 6, j = t & 63;
        float s = 0.f;
        for (int k = 0; k < 64; k++) s += h0[(g << 6) + k] * Wl1[k * 64 + j];
        h1[t] = eluf(s);
    }
    __syncthreads();
    for (int t = tid; t < GG * CC; t += blockDim.x) {
        int g = t / CC, c = t - g * CC;
        float s = bc[c];
        for (int k = 0; k < 64; k++) s += h1[(g << 6) + k] * Wc[k * CC + c];
        lg[t] = s;
    }
    __syncthreads();
    if (tid < GG) {
        int g = tid;
        float m = -1e30f;
        for (int c = 0; c < CC; c++) m = fmaxf(m, lg[g * CC + c]);
        float se = 0.f;
        for (int c = 0; c < CC; c++) se += expf(lg[g * CC + c] - m);
        float lse = m + logf(se);
        for (int c = 0; c < CC; c++) out[g * CC + c] = lg[g * CC + c] - lse;
    }
}

static void run_topk(const float* score, unsigned long long* keys, int n, int k,
                     int* out_idx, hipStream_t stream) {
    int chunks = n >> 11;
    if (n == 2048) {
        k_sort_chunk<<<1, 1024, 0, stream>>>(score, keys, 1, k, out_idx);
        return;
    }
    k_sort_chunk<<<chunks, 1024, 0, stream>>>(score, keys, 0, k, out_idx);
    if (n == 4096) {
        k_gpass<<<(n / 2) / 256, 256, 0, stream>>>(keys, 4096, 2048);
        k_lmerge<<<k >> 11, 1024, 0, stream>>>(keys, 4096, 1, k, out_idx);
    } else { // 8192
        k_gpass<<<(n / 2) / 256, 256, 0, stream>>>(keys, 4096, 2048);
        k_lmerge<<<chunks, 1024, 0, stream>>>(keys, 4096, 0, k, out_idx);
        k_gpass<<<(n / 2) / 256, 256, 0, stream>>>(keys, 8192, 4096);
        k_gpass<<<(n / 2) / 256, 256, 0, stream>>>(keys, 8192, 2048);
        k_lmerge<<<k >> 11, 1024, 0, stream>>>(keys, 8192, 1, k, out_idx);
    }
}

extern "C" void kernel_launch(void* const* d_in, const int* in_sizes, int n_in,
                              void* d_out, int out_size, void* d_ws, size_t ws_size,
                              hipStream_t stream) {
    const float* x = (const float*)d_in[0];
    const int* ei = (const int*)d_in[1];
    const int* batch = (const int*)d_in[2];
    const float* W1 = (const float*)d_in[3];  const float* b1 = (const float*)d_in[4];
    const float* W2 = (const float*)d_in[5];  const float* b2 = (const float*)d_in[6];
    const float* W3 = (const float*)d_in[7];  const float* b3 = (const float*)d_in[8];
    const float* W4 = (const float*)d_in[9];  const float* b4 = (const float*)d_in[10];
    const float* W5 = (const float*)d_in[11]; const float* b5 = (const float*)d_in[12];
    const float* W6 = (const float*)d_in[13]; const float* b6 = (const float*)d_in[14];
    const float* W7 = (const float*)d_in[15]; const float* b7 = (const float*)d_in[16];
    const float* p1 = (const float*)d_in[17];
    const float* p2 = (const float*)d_in[18];
    const float* p3 = (const float*)d_in[19];
    const float* Wl1 = (const float*)d_in[20];
    const float* Wc = (const float*)d_in[21];
    const float* bc = (const float*)d_in[22];
    float* out = (float*)d_out;
    (void)in_sizes; (void)n_in; (void)out_size; (void)ws_size;

    char* w = (char*)d_ws;
    size_t off = 0;
    auto alloc = [&](size_t bytes) -> char* {
        char* p = w + off;
        off = (off + bytes + 255) & ~(size_t)255;
        return p;
    };

    // ---- zero-initialized span ----
    size_t zero_begin = off;
    unsigned* bitmap = (unsigned*)alloc((size_t)NN * NN / 8);       // 8 MB
    int* cnt1 = (int*)alloc(NN * 4);
    int* cnt2 = (int*)alloc(KK1 * 4);
    int* cnt3 = (int*)alloc(KK2 * 4);
    int* cnt4 = (int*)alloc(KK3 * 4);
    float* x8 = (float*)alloc((size_t)KK2 * 384 * 4);
    float* x10 = (float*)alloc((size_t)KK1 * 192 * 4);
    float* x12 = (float*)alloc((size_t)NN * 96 * 4);
    size_t zero_len = off - zero_begin;

    // ---- 0xFF-initialized span (pos arrays = -1) ----
    size_t ff_begin = off;
    int* pos2 = (int*)alloc(NN * 4);
    int* pos3 = (int*)alloc(NN * 4);
    int* pos4 = (int*)alloc(NN * 4);
    size_t ff_len = off - ff_begin;

    // ---- uninitialized scratch ----
    unsigned char* rep = (unsigned char*)alloc(EE);
    float* dinv1 = (float*)alloc(NN * 4);
    float* dinv2 = (float*)alloc(KK1 * 4);
    float* dinv3 = (float*)alloc(KK2 * 4);
    float* dinv4 = (float*)alloc(KK3 * 4);
    int* rs1 = (int*)alloc((NN + 1) * 4);  int* cur1 = (int*)alloc(NN * 4);
    int* rs2 = (int*)alloc((KK1 + 1) * 4); int* cur2 = (int*)alloc(KK1 * 4);
    int* rs3 = (int*)alloc((KK2 + 1) * 4); int* cur3 = (int*)alloc(KK2 * 4);
    int* rs4 = (int*)alloc((KK3 + 1) * 4); int* cur4 = (int*)alloc(KK3 * 4);
    int* csr1 = (int*)alloc((size_t)EE * 4);
    int* csr2 = (int*)alloc((size_t)EE * 4);
    int* csr3 = (int*)alloc((size_t)EE * 4);
    int* csr4 = (int*)alloc((size_t)EE * 4);
    float* xW = (float*)alloc((size_t)262144 * 4);
    float* x1 = (float*)alloc((size_t)NN * 32 * 4);
    float* x2 = (float*)alloc((size_t)KK1 * 32 * 4);
    float* x3 = (float*)alloc((size_t)KK1 * 64 * 4);
    float* x4 = (float*)alloc((size_t)KK2 * 64 * 4);
    float* x5 = (float*)alloc((size_t)KK2 * 128 * 4);
    float* x6 = (float*)alloc((size_t)KK3 * 128 * 4);
    float* x7 = (float*)alloc((size_t)KK3 * 256 * 4);
    float* x9 = (float*)alloc((size_t)KK2 * 128 * 4);
    float* x11 = (float*)alloc((size_t)KK1 * 64 * 4);
    float* x13 = (float*)alloc((size_t)NN * 32 * 4);
    float* score1 = (float*)alloc(NN * 4);
    float* score2 = (float*)alloc(KK1 * 4);
    float* score3 = (float*)alloc(KK2 * 4);
    int* i2 = (int*)alloc(KK1 * 4);
    int* i4 = (int*)alloc(KK2 * 4);
    int* i6 = (int*)alloc(KK3 * 4);
    unsigned long long* keys = (unsigned long long*)alloc((size_t)NN * 8);
    int* gstart = (int*)alloc((GG + 1) * 4);
    float* gmaxf = (float*)alloc(GG * 32 * 4);
    float* gsum = (float*)alloc(GG * 32 * 4);
    int* gcnt = (int*)alloc(GG * 4);

    hipMemsetAsync(w + zero_begin, 0, zero_len, stream);
    hipMemsetAsync(w + ff_begin, 0xFF, ff_len, stream);

    const int B = 256;
    // ---- setup: dedup flags + weighted level-1 degree; build CSR1 ----
    k_edge_init<<<EE / B, B, 0, stream>>>(ei, bitmap, rep, cnt1);
    k_dinv<<<NN / B, B, 0, stream>>>(cnt1, dinv1, NN);
    k_prefix<<<1, 1024, 0, stream>>>(cnt1, rs1, cur1, NN);
    k_csr_l1<<<EE / B, B, 0, stream>>>(ei, cur1, csr1);
    k_gbounds<<<NN / B, B, 0, stream>>>(batch, gstart);

    // ---- gcn1: x1 = elu(gcn(A, x, W1, b1)) ----
    k_gemm<32, 32, 1><<<dim3(NN / 32, 1), 256, 0, stream>>>(x, W1, xW, NN, 128, 32);
    k_prop_csr<<<(NN * 32) / B, B, 0, stream>>>(csr1, rs1, dinv1, xW, b1, x1, NN, 5);

    // ---- pool1: top-4096; build CSR2 ----
    k_score<<<NN / B, B, 0, stream>>>(x1, p1, NN, 32, score1);
    run_topk(score1, keys, NN, KK1, i2, stream);
    k_pos2<<<KK1 / B, B, 0, stream>>>(i2, pos2);
    k_poolx<<<(KK1 * 32) / B, B, 0, stream>>>(x1, score1, i2, KK1, 32, x2);
    k_deg_lvl<<<EE / B, B, 0, stream>>>(ei, rep, pos2, cnt2);
    k_dinv<<<KK1 / B, B, 0, stream>>>(cnt2, dinv2, KK1);
    k_prefix<<<1, 1024, 0, stream>>>(cnt2, rs2, cur2, KK1);
    k_csr_lvl<<<EE / B, B, 0, stream>>>(ei, rep, pos2, cur2, csr2);

    // ---- gcn2: x3 ----
    k_gemm<32, 64, 2><<<dim3(KK1 / 32, 1), 256, 0, stream>>>(x2, W2, xW, KK1, 32, 64);
    k_prop_csr<<<(KK1 * 64) / B, B, 0, stream>>>(csr2, rs2, dinv2, xW, b2, x3, KK1, 6);

    // ---- pool2: top-2048; build CSR3 ----
    k_score<<<KK1 / B, B, 0, stream>>>(x3, p2, KK1, 64, score2);
    run_topk(score2, keys, KK1, KK2, i4, stream);
    k_pos3<<<KK2 / B, B, 0, stream>>>(i2, i4, pos3);
    k_poolx<<<(KK2 * 64) / B, B, 0, stream>>>(x3, score2, i4, KK2, 64, x4);
    k_deg_lvl<<<EE / B, B, 0, stream>>>(ei, rep, pos3, cnt3);
    k_dinv<<<KK2 / B, B, 0, stream>>>(cnt3, dinv3, KK2);
    k_prefix<<<1, 1024, 0, stream>>>(cnt3, rs3, cur3, KK2);
    k_csr_lvl<<<EE / B, B, 0, stream>>>(ei, rep, pos3, cur3, csr3);

    // ---- gcn3: x5 ----
    k_gemm<32, 64, 2><<<dim3(KK2 / 32, 2), 256, 0, stream>>>(x4, W3, xW, KK2, 64, 128);
    k_prop_csr<<<(KK2 * 128) / B, B, 0, stream>>>(csr3, rs3, dinv3, xW, b3, x5, KK2, 7);

    // ---- pool3: top-1024; build CSR4 ----
    k_score<<<KK2 / B, B, 0, stream>>>(x5, p3, KK2, 128, score3);
    run_topk(score3, keys, KK2, KK3, i6, stream);
    k_pos4<<<KK3 / B, B, 0, stream>>>(i2, i4, i6, pos4);
    k_poolx<<<(KK3 * 128) / B, B, 0, stream>>>(x5, score3, i6, KK3, 128, x6);
    k_deg_lvl<<<EE / B, B, 0, stream>>>(ei, rep, pos4, cnt4);
    k_dinv<<<KK3 / B, B, 0, stream>>>(cnt4, dinv4, KK3);
    k_prefix<<<1, 1024, 0, stream>>>(cnt4, rs4, cur4, KK3);
    k_csr_lvl<<<EE / B, B, 0, stream>>>(ei, rep, pos4, cur4, csr4);

    // ---- gcn4: x7 ----
    k_gemm<32, 64, 2><<<dim3(KK3 / 32, 4), 256, 0, stream>>>(x6, W4, xW, KK3, 128, 256);
    k_prop_csr<<<(KK3 * 256) / B, B, 0, stream>>>(csr4, rs4, dinv4, xW, b4, x7, KK3, 8);

    // ---- unpool -> x8 ----
    k_scat<<<(KK3 * 256) / B, B, 0, stream>>>(x7, i6, x8, KK3, 256, 384);
    k_catr<<<(KK2 * 128) / B, B, 0, stream>>>(x5, x8, KK2, 128, 384, 256);

    // ---- gcn5: x9 ----
    k_gemm<32, 64, 2><<<dim3(KK2 / 32, 2), 256, 0, stream>>>(x8, W5, xW, KK2, 384, 128);
    k_prop_csr<<<(KK2 * 128) / B, B, 0, stream>>>(csr3, rs3, dinv3, xW, b5, x9, KK2, 7);

    // ---- unpool -> x10 ----
    k_scat<<<(KK2 * 128) / B, B, 0, stream>>>(x9, i4, x10, KK2, 128, 192);
    k_catr<<<(KK1 * 64) / B, B, 0, stream>>>(x3, x10, KK1, 64, 192, 128);

    // ---- gcn6: x11 ----
    k_gemm<32, 64, 2><<<dim3(KK1 / 32, 1), 256, 0, stream>>>(x10, W6, xW, KK1, 192, 64);
    k_prop_csr<<<(KK1 * 64) / B, B, 0, stream>>>(csr2, rs2, dinv2, xW, b6, x11, KK1, 6);

    // ---- unpool -> x12 ----
    k_scat<<<(KK1 * 64) / B, B, 0, stream>>>(x11, i2, x12, KK1, 64, 96);
    k_catr<<<(NN * 32) / B, B, 0, stream>>>(x1, x12, NN, 32, 96, 64);

    // ---- gcn7: x13 ----
    k_gemm<32, 32, 1><<<dim3(NN / 32, 1), 256, 0, stream>>>(x12, W7, xW, NN, 96, 32);
    k_prop_csr<<<(NN * 32) / B, B, 0, stream>>>(csr1, rs1, dinv1, xW, b7, x13, NN, 5);

    // ---- readout ----
    k_seg2<<<GG, 256, 0, stream>>>(x13, gstart, gmaxf, gsum, gcnt);
    k_head<<<1, 1024, 0, stream>>>(gmaxf, gsum, gcnt, Wl1, Wc, bc, out);
}

// Round 5
// 549.438 us; speedup vs baseline: 1.0777x; 1.0777x over previous
//
#include <hip/hip_runtime.h>
#include <math.h>

#define NN 8192
#define EE 262144
#define GG 64
#define CC 10
#define KK1 4096
#define KK2 2048
#define KK3 1024

typedef unsigned long long ull;

__device__ __forceinline__ float eluf(float x) { return x > 0.f ? x : expm1f(x); }
__device__ __forceinline__ float sigf(float x) { return 1.f / (1.f + expf(-x)); }
__device__ __forceinline__ unsigned f2s(float f) {
    unsigned u = __float_as_uint(f);
    return (u & 0x80000000u) ? ~u : (u | 0x80000000u);
}

// ---- edge init: dedup flag + weighted in-degree (L1) + graph bounds ----
__global__ void k_edge_init(const int* __restrict__ ei, unsigned* __restrict__ bitmap,
                            unsigned char* __restrict__ rep, int* __restrict__ cnt1,
                            const int* __restrict__ batch, int* __restrict__ gstart) {
    int e = blockIdx.x * blockDim.x + threadIdx.x;
    if (e >= EE) return;
    int s = ei[e], d = ei[EE + e];
    unsigned key = ((unsigned)s << 13) | (unsigned)d;   // N = 8192 = 2^13
    unsigned old = atomicOr(&bitmap[key >> 5], 1u << (key & 31u));
    rep[e] = ((old >> (key & 31u)) & 1u) ? 0 : 1;
    atomicAdd(&cnt1[d], 1);
    if (e < NN) {
        int g = batch[e];
        int prev = (e == 0) ? -1 : batch[e - 1];
        for (int gg = prev + 1; gg <= g; gg++) gstart[gg] = e;
        if (e == NN - 1)
            for (int gg = g + 1; gg <= GG; gg++) gstart[gg] = NN;
    }
}

// ---- prefix scan over counts -> rowstart[n+1], cursor copy, dinv ----
__global__ void k_prefix(const int* __restrict__ cnt, int* __restrict__ rs,
                         int* __restrict__ cur, float* __restrict__ dinv, int n) {
    __shared__ int ts[1024];
    int tid = threadIdx.x;
    int ept = n >> 10;                 // 1,2,4,8
    int base = tid * ept;
    int local[8];
    int s = 0;
    for (int i = 0; i < ept; i++) { local[i] = cnt[base + i]; s += local[i]; }
    ts[tid] = s;
    __syncthreads();
    for (int off = 1; off < 1024; off <<= 1) {
        int v = ts[tid];
        int add = (tid >= off) ? ts[tid - off] : 0;
        __syncthreads();
        ts[tid] = v + add;
        __syncthreads();
    }
    int run = (tid == 0) ? 0 : ts[tid - 1];
    for (int i = 0; i < ept; i++) {
        rs[base + i] = run; cur[base + i] = run;
        dinv[base + i] = 1.f / sqrtf((float)(local[i] + 1));
        run += local[i];
    }
    if (tid == 1023) rs[n] = run;
}

// ---- level-1 CSR scatter: all edges, with multiplicity ----
__global__ void k_csr_l1(const int* __restrict__ ei, int* __restrict__ cur,
                         int* __restrict__ csr) {
    int e = blockIdx.x * blockDim.x + threadIdx.x;
    if (e >= EE) return;
    csr[atomicAdd(&cur[ei[EE + e]], 1)] = ei[e];
}

// ---- pooled level: degree count ----
__global__ void k_deg_lvl(const int* __restrict__ ei, const unsigned char* __restrict__ rep,
                          const int* __restrict__ pos, int* __restrict__ cnt) {
    int e = blockIdx.x * blockDim.x + threadIdx.x;
    if (e >= EE || !rep[e]) return;
    int ps = pos[ei[e]], pd = pos[ei[EE + e]];
    if (ps >= 0 && pd >= 0) atomicAdd(&cnt[pd], 1);
}
// ---- pooled level: CSR scatter ----
__global__ void k_csr_lvl(const int* __restrict__ ei, const unsigned char* __restrict__ rep,
                          const int* __restrict__ pos, int* __restrict__ cur,
                          int* __restrict__ csr) {
    int e = blockIdx.x * blockDim.x + threadIdx.x;
    if (e >= EE || !rep[e]) return;
    int ps = pos[ei[e]], pd = pos[ei[EE + e]];
    if (ps >= 0 && pd >= 0) csr[atomicAdd(&cur[pd], 1)] = ps;
}

// ---- tiled register-blocked GEMM: Y[M,F] = X[M,K] @ W[K,F] ----
template<int BM, int BN, int TM>
__global__ void k_gemm(const float* __restrict__ X, const float* __restrict__ W,
                       float* __restrict__ Y, int M, int K, int F) {
    constexpr int TX = BN / 4;
    __shared__ float Xs[BM][33];
    __shared__ float Ws[32][BN + 4];
    int tid = threadIdx.x;
    int txn = tid % TX, tym = tid / TX;
    int m0 = blockIdx.x * BM, n0 = blockIdx.y * BN;
    float acc[TM][4];
#pragma unroll
    for (int i = 0; i < TM; i++)
#pragma unroll
        for (int j = 0; j < 4; j++) acc[i][j] = 0.f;
    for (int k0 = 0; k0 < K; k0 += 32) {
        for (int idx = tid; idx < BM * 32; idx += 256) {
            int r = idx >> 5, c = idx & 31;
            Xs[r][c] = X[(size_t)(m0 + r) * K + k0 + c];
        }
        for (int idx = tid; idx < 32 * BN; idx += 256) {
            int r = idx / BN, c = idx % BN;
            Ws[r][c] = W[(size_t)(k0 + r) * F + n0 + c];
        }
        __syncthreads();
#pragma unroll 4
        for (int kk = 0; kk < 32; kk++) {
            float4 wv = *(const float4*)&Ws[kk][txn * 4];
#pragma unroll
            for (int i = 0; i < TM; i++) {
                float xv = Xs[tym * TM + i][kk];
                acc[i][0] += xv * wv.x;
                acc[i][1] += xv * wv.y;
                acc[i][2] += xv * wv.z;
                acc[i][3] += xv * wv.w;
            }
        }
        __syncthreads();
    }
#pragma unroll
    for (int i = 0; i < TM; i++) {
        float4 v = make_float4(acc[i][0], acc[i][1], acc[i][2], acc[i][3]);
        *(float4*)&Y[(size_t)(m0 + tym * TM + i) * F + n0 + txn * 4] = v;
    }
}

// ---- CSR gather propagate + self + bias + elu (+ optional pooling score) ----
// grid must be exactly (n<<LOGF)/256 blocks of 256 (no bounds check).
template<int LOGF, int SCORE>
__global__ void k_prop(const int* __restrict__ csr, const int* __restrict__ rs,
                       const float* __restrict__ dinv, const float* __restrict__ xW,
                       const float* __restrict__ b, float* __restrict__ xout,
                       const float* __restrict__ p, float* __restrict__ score) {
    constexpr int F = 1 << LOGF;
    int t = blockIdx.x * 256 + threadIdx.x;
    int d = t >> LOGF, f = t & (F - 1);
    int j0 = rs[d], j1 = rs[d + 1];
    float dd = dinv[d];
    float sum = dd * xW[t];
    for (int j = j0; j < j1; j++) {
        int s = csr[j];
        sum += dinv[s] * xW[(s << LOGF) + f];
    }
    float v = eluf(dd * sum + b[f]);
    xout[t] = v;
    if (SCORE) {
        float pf = p[f];
        float sc = v * pf, nr = pf * pf;
        if (LOGF == 5) {
            for (int m = 16; m >= 1; m >>= 1) {
                sc += __shfl_xor(sc, m, 32); nr += __shfl_xor(nr, m, 32);
            }
            if ((threadIdx.x & 31) == 0) score[d] = sc / sqrtf(nr);
        } else if (LOGF == 6) {
            for (int m = 32; m >= 1; m >>= 1) {
                sc += __shfl_xor(sc, m, 64); nr += __shfl_xor(nr, m, 64);
            }
            if ((threadIdx.x & 63) == 0) score[d] = sc / sqrtf(nr);
        } else {                       // F = 128: two waves per row
            __shared__ float ssc[4], snr[4];
            for (int m = 32; m >= 1; m >>= 1) {
                sc += __shfl_xor(sc, m, 64); nr += __shfl_xor(nr, m, 64);
            }
            int wv = threadIdx.x >> 6;
            if ((threadIdx.x & 63) == 0) { ssc[wv] = sc; snr[wv] = nr; }
            __syncthreads();
            if (f == 0) score[d] = (ssc[wv] + ssc[wv + 1]) / sqrtf(snr[wv] + snr[wv + 1]);
        }
    }
}

// ==== parallel bitonic top-k (descending, ties -> smaller index; exact jax order) ====
__global__ void k_sort_chunk(const float* __restrict__ score, ull* __restrict__ keys,
                             int last, int k, int* __restrict__ out_idx) {
    __shared__ ull sk[2048];
    int base = blockIdx.x << 11;
    int tid = threadIdx.x;
    for (int i = tid; i < 2048; i += 1024) {
        int gi = base + i;
        sk[i] = ((ull)f2s(score[gi]) << 32) | (unsigned)(~gi);
    }
    __syncthreads();
    for (int sz = 2; sz <= 2048; sz <<= 1) {
        for (int st = sz >> 1; st > 0; st >>= 1) {
            int i = ((tid & ~(st - 1)) << 1) | (tid & (st - 1));
            int j = i | st;
            ull a = sk[i], b = sk[j];
            bool desc = (((base + i) & sz) == 0);
            if (desc ? (a < b) : (a > b)) { sk[i] = b; sk[j] = a; }
            __syncthreads();
        }
    }
    if (last) {
        for (int i = tid; i < 2048; i += 1024) {
            int gi = base + i;
            if (gi < k) out_idx[gi] = (int)(~(unsigned)(sk[i] & 0xFFFFFFFFu));
        }
    } else {
        for (int i = tid; i < 2048; i += 1024) keys[base + i] = sk[i];
    }
}

// whole stage sz (strides 2048..1) over a contiguous 4096-key block in LDS
__global__ void k_stage4k(ull* __restrict__ keys, int sz, int last, int k,
                          int* __restrict__ out_idx) {
    __shared__ ull sk[4096];
    int base = blockIdx.x << 12;
    int tid = threadIdx.x;
    for (int i = tid; i < 4096; i += 1024) sk[i] = keys[base + i];
    __syncthreads();
    for (int st = 2048; st > 0; st >>= 1) {
        for (int pp = tid; pp < 2048; pp += 1024) {
            int i = ((pp & ~(st - 1)) << 1) | (pp & (st - 1));
            int j = i | st;
            ull a = sk[i], b = sk[j];
            bool desc = (((base + i) & sz) == 0);
            if (desc ? (a < b) : (a > b)) { sk[i] = b; sk[j] = a; }
        }
        __syncthreads();
    }
    if (last) {
        for (int i = tid; i < 4096; i += 1024) {
            int gi = base + i;
            if (gi < k) out_idx[gi] = (int)(~(unsigned)(sk[i] & 0xFFFFFFFFu));
        }
    } else {
        for (int i = tid; i < 4096; i += 1024) keys[base + i] = sk[i];
    }
}

// n=8192 final stage, strides 4096+2048 (desc everywhere); each thread owns its orbit
__global__ void k_stage8k_hi(ull* __restrict__ keys) {
    int t = blockIdx.x * 256 + threadIdx.x;      // 0..2047
    ull a = keys[t], b = keys[t + 2048], c = keys[t + 4096], d = keys[t + 6144], x;
    if (a < c) { x = a; a = c; c = x; }
    if (b < d) { x = b; b = d; d = x; }
    if (a < b) { x = a; a = b; b = x; }
    if (c < d) { x = c; c = d; d = x; }
    keys[t] = a; keys[t + 2048] = b; keys[t + 4096] = c; keys[t + 6144] = d;
}

// local merge: strides 1024..1 per 2048-chunk
__global__ void k_lmerge(ull* __restrict__ keys, int sz, int last, int k,
                         int* __restrict__ out_idx) {
    __shared__ ull sk[2048];
    int base = blockIdx.x << 11;
    int tid = threadIdx.x;
    for (int i = tid; i < 2048; i += 1024) sk[i] = keys[base + i];
    __syncthreads();
    for (int st = 1024; st > 0; st >>= 1) {
        int i = ((tid & ~(st - 1)) << 1) | (tid & (st - 1));
        int j = i | st;
        ull a = sk[i], b = sk[j];
        bool desc = (((base + i) & sz) == 0);
        if (desc ? (a < b) : (a > b)) { sk[i] = b; sk[j] = a; }
        __syncthreads();
    }
    if (last) {
        for (int i = tid; i < 2048; i += 1024) {
            int gi = base + i;
            if (gi < k) out_idx[gi] = (int)(~(unsigned)(sk[i] & 0xFFFFFFFFu));
        }
    } else {
        for (int i = tid; i < 2048; i += 1024) keys[base + i] = sk[i];
    }
}

// ---- pooled features + pos/inv/orig maps in one pass ----
__global__ void k_poolxp(const float* __restrict__ x, const float* __restrict__ score,
                         const int* __restrict__ idx, int k, int F, float* __restrict__ xout,
                         const int* __restrict__ origPrev, int* __restrict__ origOut,
                         int* __restrict__ pos, int* __restrict__ invl) {
    int t = blockIdx.x * blockDim.x + threadIdx.x;
    if (t >= k * F) return;
    int r = t / F, f = t - r * F;
    int j = idx[r];
    xout[t] = eluf(x[(size_t)j * F + f] * sigf(score[j]));
    if (f == 0) {
        int orig = origPrev ? origPrev[j] : j;
        if (origOut) origOut[r] = orig;
        pos[orig] = r;
        if (invl) invl[j] = r;
    }
}

// ---- unpool gather + concat + elu (replaces scatter+catr, no pre-zero needed) ----
__global__ void k_unpool(const float* __restrict__ xl, const int* __restrict__ inv,
                         const float* __restrict__ xr, float* __restrict__ xcat,
                         int n, int Fl, int Fr) {
    int Fcat = Fl + Fr;
    int t = blockIdx.x * blockDim.x + threadIdx.x;
    if (t >= n * Fcat) return;
    int q = t / Fcat, f = t - q * Fcat;
    float v;
    if (f < Fl) {
        int r = inv[q];
        v = (r >= 0) ? xl[(size_t)r * Fl + f] : 0.f;
    } else {
        v = xr[(size_t)q * Fr + (f - Fl)];
    }
    xcat[t] = eluf(v);
}

// ---- atomic-free segment max/sum/count: one block per graph ----
__global__ void k_seg2(const float* __restrict__ x13, const int* __restrict__ gstart,
                       float* __restrict__ gmaxf, float* __restrict__ gsum,
                       int* __restrict__ gcnt) {
    __shared__ float sm[8][32], ss[8][32];
    int g = blockIdx.x;
    int j0 = gstart[g], j1 = gstart[g + 1];
    int t = threadIdx.x;
    int f = t & 31, r = t >> 5;
    float m = -INFINITY, s = 0.f;
    for (int j = j0 + r; j < j1; j += 8) {
        float v = x13[(j << 5) + f];
        m = fmaxf(m, v);
        s += v;
    }
    sm[r][f] = m; ss[r][f] = s;
    __syncthreads();
    if (t < 32) {
        float mm = sm[0][t], sss = ss[0][t];
        for (int i = 1; i < 8; i++) { mm = fmaxf(mm, sm[i][t]); sss += ss[i][t]; }
        gmaxf[(g << 5) + t] = mm;
        gsum[(g << 5) + t] = sss;
        if (t == 0) gcnt[g] = j1 - j0;
    }
}

// ---- head ----
__global__ void k_head(const float* __restrict__ gmaxf, const float* __restrict__ gsum,
                       const int* __restrict__ gcnt, const float* __restrict__ Wl1,
                       const float* __restrict__ Wc, const float* __restrict__ bc,
                       float* __restrict__ out) {
    __shared__ float h0[GG * 64];
    __shared__ float h1[GG * 64];
    __shared__ float lg[GG * CC];
    int tid = threadIdx.x;
    for (int t = tid; t < GG * 64; t += blockDim.x) {
        int g = t >> 6, c = t & 63;
        float v;
        if (c < 32) v = gmaxf[(g << 5) + c];
        else v = gsum[(g << 5) + (c - 32)] / (float)gcnt[g];
        h0[t] = eluf(v);
    }
    __syncthreads();
    for (int t = tid; t < GG * 64; t += blockDim.x) {
        int g = t >> 6, j = t & 63;
        float s = 0.f;
        for (int k = 0; k < 64; k++) s += h0[(g << 6) + k] * Wl1[k * 64 + j];
        h1[t] = eluf(s);
    }
    __syncthreads();
    for (int t = tid; t < GG * CC; t += blockDim.x) {
        int g = t / CC, c = t - g * CC;
        float s = bc[c];
        for (int k = 0; k < 64; k++) s += h1[(g << 6) + k] * Wc[k * CC + c];
        lg[t] = s;
    }
    __syncthreads();
    if (tid < GG) {
        int g = tid;
        float m = -1e30f;
        for (int c = 0; c < CC; c++) m = fmaxf(m, lg[g * CC + c]);
        float se = 0.f;
        for (int c = 0; c < CC; c++) se += expf(lg[g * CC + c] - m);
        float lse = m + logf(se);
        for (int c = 0; c < CC; c++) out[g * CC + c] = lg[g * CC + c] - lse;
    }
}

static void run_topk(const float* score, ull* keys, int n, int k, int* out_idx,
                     hipStream_t stream) {
    if (n == 2048) {
        k_sort_chunk<<<1, 1024, 0, stream>>>(score, keys, 1, k, out_idx);
        return;
    }
    k_sort_chunk<<<n >> 11, 1024, 0, stream>>>(score, keys, 0, k, out_idx);
    if (n == 4096) {
        k_stage4k<<<1, 1024, 0, stream>>>(keys, 4096, 1, k, out_idx);
    } else {                                   // 8192
        k_stage4k<<<2, 1024, 0, stream>>>(keys, 4096, 0, k, out_idx);
        k_stage8k_hi<<<8, 256, 0, stream>>>(keys);
        k_lmerge<<<k >> 11, 1024, 0, stream>>>(keys, 8192, 1, k, out_idx);
    }
}

extern "C" void kernel_launch(void* const* d_in, const int* in_sizes, int n_in,
                              void* d_out, int out_size, void* d_ws, size_t ws_size,
                              hipStream_t stream) {
    const float* x = (const float*)d_in[0];
    const int* ei = (const int*)d_in[1];
    const int* batch = (const int*)d_in[2];
    const float* W1 = (const float*)d_in[3];  const float* b1 = (const float*)d_in[4];
    const float* W2 = (const float*)d_in[5];  const float* b2 = (const float*)d_in[6];
    const float* W3 = (const float*)d_in[7];  const float* b3 = (const float*)d_in[8];
    const float* W4 = (const float*)d_in[9];  const float* b4 = (const float*)d_in[10];
    const float* W5 = (const float*)d_in[11]; const float* b5 = (const float*)d_in[12];
    const float* W6 = (const float*)d_in[13]; const float* b6 = (const float*)d_in[14];
    const float* W7 = (const float*)d_in[15]; const float* b7 = (const float*)d_in[16];
    const float* p1 = (const float*)d_in[17];
    const float* p2 = (const float*)d_in[18];
    const float* p3 = (const float*)d_in[19];
    const float* Wl1 = (const float*)d_in[20];
    const float* Wc = (const float*)d_in[21];
    const float* bc = (const float*)d_in[22];
    float* out = (float*)d_out;
    (void)in_sizes; (void)n_in; (void)out_size; (void)ws_size;

    char* w = (char*)d_ws;
    size_t off = 0;
    auto alloc = [&](size_t bytes) -> char* {
        char* p = w + off;
        off = (off + bytes + 255) & ~(size_t)255;
        return p;
    };

    // ---- zero-initialized span ----
    size_t zero_begin = off;
    unsigned* bitmap = (unsigned*)alloc((size_t)NN * NN / 8);       // 8 MB
    int* cnt1 = (int*)alloc(NN * 4);
    int* cnt2 = (int*)alloc(KK1 * 4);
    int* cnt3 = (int*)alloc(KK2 * 4);
    int* cnt4 = (int*)alloc(KK3 * 4);
    size_t zero_len = off - zero_begin;

    // ---- 0xFF-initialized span (pos/inv arrays = -1) ----
    size_t ff_begin = off;
    int* pos2 = (int*)alloc(NN * 4);
    int* pos3 = (int*)alloc(NN * 4);
    int* pos4 = (int*)alloc(NN * 4);
    int* inv4 = (int*)alloc(KK1 * 4);
    int* inv6 = (int*)alloc(KK2 * 4);
    size_t ff_len = off - ff_begin;

    // ---- uninitialized scratch ----
    unsigned char* rep = (unsigned char*)alloc(EE);
    float* dinv1 = (float*)alloc(NN * 4);
    float* dinv2 = (float*)alloc(KK1 * 4);
    float* dinv3 = (float*)alloc(KK2 * 4);
    float* dinv4 = (float*)alloc(KK3 * 4);
    int* rs1 = (int*)alloc((NN + 1) * 4);  int* cur1 = (int*)alloc(NN * 4);
    int* rs2 = (int*)alloc((KK1 + 1) * 4); int* cur2 = (int*)alloc(KK1 * 4);
    int* rs3 = (int*)alloc((KK2 + 1) * 4); int* cur3 = (int*)alloc(KK2 * 4);
    int* rs4 = (int*)alloc((KK3 + 1) * 4); int* cur4 = (int*)alloc(KK3 * 4);
    int* csr1 = (int*)alloc((size_t)EE * 4);
    int* csr2 = (int*)alloc((size_t)EE * 4);
    int* csr3 = (int*)alloc((size_t)EE * 4);
    int* csr4 = (int*)alloc((size_t)EE * 4);
    float* xW = (float*)alloc((size_t)262144 * 4);
    float* x1 = (float*)alloc((size_t)NN * 32 * 4);
    float* x2 = (float*)alloc((size_t)KK1 * 32 * 4);
    float* x3 = (float*)alloc((size_t)KK1 * 64 * 4);
    float* x4 = (float*)alloc((size_t)KK2 * 64 * 4);
    float* x5 = (float*)alloc((size_t)KK2 * 128 * 4);
    float* x6 = (float*)alloc((size_t)KK3 * 128 * 4);
    float* x7 = (float*)alloc((size_t)KK3 * 256 * 4);
    float* x8 = (float*)alloc((size_t)KK2 * 384 * 4);
    float* x9 = (float*)alloc((size_t)KK2 * 128 * 4);
    float* x10 = (float*)alloc((size_t)KK1 * 192 * 4);
    float* x11 = (float*)alloc((size_t)KK1 * 64 * 4);
    float* x12 = (float*)alloc((size_t)NN * 96 * 4);
    float* x13 = (float*)alloc((size_t)NN * 32 * 4);
    float* score1 = (float*)alloc(NN * 4);
    float* score2 = (float*)alloc(KK1 * 4);
    float* score3 = (float*)alloc(KK2 * 4);
    int* i2 = (int*)alloc(KK1 * 4);
    int* i4 = (int*)alloc(KK2 * 4);
    int* i6 = (int*)alloc(KK3 * 4);
    int* orig2 = (int*)alloc(KK2 * 4);
    ull* keys = (ull*)alloc((size_t)NN * 8);
    int* gstart = (int*)alloc((GG + 1) * 4);
    float* gmaxf = (float*)alloc(GG * 32 * 4);
    float* gsum = (float*)alloc(GG * 32 * 4);
    int* gcnt = (int*)alloc(GG * 4);

    hipMemsetAsync(w + zero_begin, 0, zero_len, stream);
    hipMemsetAsync(w + ff_begin, 0xFF, ff_len, stream);

    const int B = 256;
    // ---- setup: dedup + deg1 + gbounds; CSR1 ----
    k_edge_init<<<EE / B, B, 0, stream>>>(ei, bitmap, rep, cnt1, batch, gstart);
    k_prefix<<<1, 1024, 0, stream>>>(cnt1, rs1, cur1, dinv1, NN);
    k_csr_l1<<<EE / B, B, 0, stream>>>(ei, cur1, csr1);

    // ---- gcn1 (+score1) ----
    k_gemm<32, 32, 1><<<dim3(NN / 32, 1), 256, 0, stream>>>(x, W1, xW, NN, 128, 32);
    k_prop<5, 1><<<(NN * 32) / B, B, 0, stream>>>(csr1, rs1, dinv1, xW, b1, x1, p1, score1);

    // ---- pool1: top-4096; CSR2 ----
    run_topk(score1, keys, NN, KK1, i2, stream);
    k_poolxp<<<(KK1 * 32) / B, B, 0, stream>>>(x1, score1, i2, KK1, 32, x2,
                                               nullptr, nullptr, pos2, nullptr);
    k_deg_lvl<<<EE / B, B, 0, stream>>>(ei, rep, pos2, cnt2);
    k_prefix<<<1, 1024, 0, stream>>>(cnt2, rs2, cur2, dinv2, KK1);
    k_csr_lvl<<<EE / B, B, 0, stream>>>(ei, rep, pos2, cur2, csr2);

    // ---- gcn2 (+score2) ----
    k_gemm<32, 64, 2><<<dim3(KK1 / 32, 1), 256, 0, stream>>>(x2, W2, xW, KK1, 32, 64);
    k_prop<6, 1><<<(KK1 * 64) / B, B, 0, stream>>>(csr2, rs2, dinv2, xW, b2, x3, p2, score2);

    // ---- pool2: top-2048; CSR3 ----
    run_topk(score2, keys, KK1, KK2, i4, stream);
    k_poolxp<<<(KK2 * 64) / B, B, 0, stream>>>(x3, score2, i4, KK2, 64, x4,
                                               i2, orig2, pos3, inv4);
    k_deg_lvl<<<EE / B, B, 0, stream>>>(ei, rep, pos3, cnt3);
    k_prefix<<<1, 1024, 0, stream>>>(cnt3, rs3, cur3, dinv3, KK2);
    k_csr_lvl<<<EE / B, B, 0, stream>>>(ei, rep, pos3, cur3, csr3);

    // ---- gcn3 (+score3) ----
    k_gemm<32, 64, 2><<<dim3(KK2 / 32, 2), 256, 0, stream>>>(x4, W3, xW, KK2, 64, 128);
    k_prop<7, 1><<<(KK2 * 128) / B, B, 0, stream>>>(csr3, rs3, dinv3, xW, b3, x5, p3, score3);

    // ---- pool3: top-1024; CSR4 ----
    run_topk(score3, keys, KK2, KK3, i6, stream);
    k_poolxp<<<(KK3 * 128) / B, B, 0, stream>>>(x5, score3, i6, KK3, 128, x6,
                                                orig2, nullptr, pos4, inv6);
    k_deg_lvl<<<EE / B, B, 0, stream>>>(ei, rep, pos4, cnt4);
    k_prefix<<<1, 1024, 0, stream>>>(cnt4, rs4, cur4, dinv4, KK3);
    k_csr_lvl<<<EE / B, B, 0, stream>>>(ei, rep, pos4, cur4, csr4);

    // ---- gcn4 ----
    k_gemm<32, 64, 2><<<dim3(KK3 / 32, 4), 256, 0, stream>>>(x6, W4, xW, KK3, 128, 256);
    k_prop<8, 0><<<(KK3 * 256) / B, B, 0, stream>>>(csr4, rs4, dinv4, xW, b4, x7,
                                                    nullptr, nullptr);

    // ---- unpool3 -> x8 ----
    k_unpool<<<(KK2 * 384) / B, B, 0, stream>>>(x7, inv6, x5, x8, KK2, 256, 128);

    // ---- gcn5 ----
    k_gemm<32, 64, 2><<<dim3(KK2 / 32, 2), 256, 0, stream>>>(x8, W5, xW, KK2, 384, 128);
    k_prop<7, 0><<<(KK2 * 128) / B, B, 0, stream>>>(csr3, rs3, dinv3, xW, b5, x9,
                                                    nullptr, nullptr);

    // ---- unpool2 -> x10 ----
    k_unpool<<<(KK1 * 192) / B, B, 0, stream>>>(x9, inv4, x3, x10, KK1, 128, 64);

    // ---- gcn6 ----
    k_gemm<32, 64, 2><<<dim3(KK1 / 32, 1), 256, 0, stream>>>(x10, W6, xW, KK1, 192, 64);
    k_prop<6, 0><<<(KK1 * 64) / B, B, 0, stream>>>(csr2, rs2, dinv2, xW, b6, x11,
                                                   nullptr, nullptr);

    // ---- unpool1 -> x12 (inv over N is pos2) ----
    k_unpool<<<(NN * 96) / B, B, 0, stream>>>(x11, pos2, x1, x12, NN, 64, 32);

    // ---- gcn7 ----
    k_gemm<32, 32, 1><<<dim3(NN / 32, 1), 256, 0, stream>>>(x12, W7, xW, NN, 96, 32);
    k_prop<5, 0><<<(NN * 32) / B, B, 0, stream>>>(csr1, rs1, dinv1, xW, b7, x13,
                                                  nullptr, nullptr);

    // ---- readout ----
    k_seg2<<<GG, 256, 0, stream>>>(x13, gstart, gmaxf, gsum, gcnt);
    k_head<<<1, 1024, 0, stream>>>(gmaxf, gsum, gcnt, Wl1, Wc, bc, out);
}

// Round 6
// 537.824 us; speedup vs baseline: 1.1010x; 1.0216x over previous
//
#include <hip/hip_runtime.h>
#include <math.h>

#define NN 8192
#define EE 262144
#define GG 64
#define CC 10
#define KK1 4096
#define KK2 2048
#define KK3 1024

typedef unsigned long long ull;

__device__ __forceinline__ float eluf(float x) { return x > 0.f ? x : expm1f(x); }
__device__ __forceinline__ float sigf(float x) { return 1.f / (1.f + expf(-x)); }
__device__ __forceinline__ unsigned f2s(float f) {
    unsigned u = __float_as_uint(f);
    return (u & 0x80000000u) ? ~u : (u | 0x80000000u);
}

// ---- edge init: dedup flag (bitmap) + weighted in-degree (L1) + graph bounds ----
__global__ void k_edge_init(const int* __restrict__ ei, unsigned* __restrict__ bitmap,
                            unsigned char* __restrict__ rep, int* __restrict__ cnt1,
                            const int* __restrict__ batch, int* __restrict__ gstart) {
    int e = blockIdx.x * blockDim.x + threadIdx.x;
    if (e >= EE) return;
    int s = ei[e], d = ei[EE + e];
    unsigned key = ((unsigned)s << 13) | (unsigned)d;   // N = 8192 = 2^13
    unsigned old = atomicOr(&bitmap[key >> 5], 1u << (key & 31u));
    rep[e] = ((old >> (key & 31u)) & 1u) ? 0 : 1;
    atomicAdd(&cnt1[d], 1);
    if (e < NN) {
        int g = batch[e];
        int prev = (e == 0) ? -1 : batch[e - 1];
        for (int gg = prev + 1; gg <= g; gg++) gstart[gg] = e;
        if (e == NN - 1)
            for (int gg = g + 1; gg <= GG; gg++) gstart[gg] = NN;
    }
}

// ---- prefix scan over cnt1 -> rs1[n+1], cursors, dinv1 ----
__global__ void k_prefix(const int* __restrict__ cnt, int* __restrict__ rs,
                         int* __restrict__ cur, float* __restrict__ dinv, int n) {
    __shared__ int ts[1024];
    int tid = threadIdx.x;
    int ept = n >> 10;
    int base = tid * ept;
    int local[8];
    int s = 0;
    for (int i = 0; i < ept; i++) { local[i] = cnt[base + i]; s += local[i]; }
    ts[tid] = s;
    __syncthreads();
    for (int off = 1; off < 1024; off <<= 1) {
        int v = ts[tid];
        int add = (tid >= off) ? ts[tid - off] : 0;
        __syncthreads();
        ts[tid] = v + add;
        __syncthreads();
    }
    int run = (tid == 0) ? 0 : ts[tid - 1];
    for (int i = 0; i < ept; i++) {
        rs[base + i] = run; cur[base + i] = run;
        dinv[base + i] = 1.f / sqrtf((float)(local[i] + 1));
        run += local[i];
    }
    if (tid == 1023) rs[n] = run;
}

// ---- level-1 CSR scatter, dup flag in sign bit ----
__global__ void k_csr_l1(const int* __restrict__ ei, const unsigned char* __restrict__ rep,
                         int* __restrict__ cur, int* __restrict__ csr) {
    int e = blockIdx.x * blockDim.x + threadIdx.x;
    if (e >= EE) return;
    int s = ei[e];
    csr[atomicAdd(&cur[ei[EE + e]], 1)] = rep[e] ? s : (s | 0x80000000);
}

// ---- subset filter: build level CSR from previous level CSR, wave per row ----
// L1=1: previous = csr1 (rs-addressed, dup-flagged, orig ids), invmap = pos over orig.
// L1=0: previous = level CSR (rowoff/deg addressed), invmap = prevlevel->newlevel.
template<int L1>
__global__ void k_sub(const int* __restrict__ idx, int nrows,
                      const int* __restrict__ csrP, const int* __restrict__ roffP,
                      const int* __restrict__ degP, const int* __restrict__ rsl1,
                      const int* __restrict__ invmap,
                      int* __restrict__ csrO, int* __restrict__ roffO,
                      int* __restrict__ degO, float* __restrict__ dinvO) {
    int wid = (blockIdx.x * blockDim.x + threadIdx.x) >> 6;
    int lane = threadIdx.x & 63;
    if (wid >= nrows) return;
    int j = idx[wid];
    int j0, len;
    if (L1) { j0 = rsl1[j]; len = rsl1[j + 1] - j0; }
    else    { j0 = roffP[j]; len = degP[j]; }
    int cnt = 0;
    for (int base = 0; base < len; base += 64) {
        bool sel = false;
        int val = 0;
        if (base + lane < len) {
            int e = csrP[j0 + base + lane];
            if (!L1 || e >= 0) {               // skip duplicate-flagged entries
                int s = L1 ? (e & 0x7fffffff) : e;
                int v = invmap[s];
                if (v >= 0) { sel = true; val = v; }
            }
        }
        ull m = __ballot(sel);
        if (sel) {
            int off = __popcll(m & ((1ull << lane) - 1ull));
            csrO[j0 + cnt + off] = val;
        }
        cnt += __popcll(m);
    }
    if (lane == 0) {
        roffO[wid] = j0;
        degO[wid] = cnt;
        dinvO[wid] = 1.f / sqrtf((float)(cnt + 1));
    }
}

// ---- tiled register-blocked GEMM: Y[M,F] = X[M,K] @ W[K,F] ----
template<int BM, int BN, int TM>
__global__ void k_gemm(const float* __restrict__ X, const float* __restrict__ W,
                       float* __restrict__ Y, int M, int K, int F) {
    constexpr int TX = BN / 4;
    __shared__ float Xs[BM][33];
    __shared__ float Ws[32][BN + 4];
    int tid = threadIdx.x;
    int txn = tid % TX, tym = tid / TX;
    int m0 = blockIdx.x * BM, n0 = blockIdx.y * BN;
    float acc[TM][4];
#pragma unroll
    for (int i = 0; i < TM; i++)
#pragma unroll
        for (int j = 0; j < 4; j++) acc[i][j] = 0.f;
    for (int k0 = 0; k0 < K; k0 += 32) {
        for (int idx = tid; idx < BM * 32; idx += 256) {
            int r = idx >> 5, c = idx & 31;
            Xs[r][c] = X[(size_t)(m0 + r) * K + k0 + c];
        }
        for (int idx = tid; idx < 32 * BN; idx += 256) {
            int r = idx / BN, c = idx % BN;
            Ws[r][c] = W[(size_t)(k0 + r) * F + n0 + c];
        }
        __syncthreads();
#pragma unroll 4
        for (int kk = 0; kk < 32; kk++) {
            float4 wv = *(const float4*)&Ws[kk][txn * 4];
#pragma unroll
            for (int i = 0; i < TM; i++) {
                float xv = Xs[tym * TM + i][kk];
                acc[i][0] += xv * wv.x;
                acc[i][1] += xv * wv.y;
                acc[i][2] += xv * wv.z;
                acc[i][3] += xv * wv.w;
            }
        }
        __syncthreads();
    }
#pragma unroll
    for (int i = 0; i < TM; i++) {
        float4 v = make_float4(acc[i][0], acc[i][1], acc[i][2], acc[i][3]);
        *(float4*)&Y[(size_t)(m0 + tym * TM + i) * F + n0 + txn * 4] = v;
    }
}

// ---- GEMM with fused unpool+concat+elu on the X operand ----
// X[m,kk] = elu( kk<Fl ? (inv[m]>=0 ? xl[inv[m],kk] : 0) : xr[m,kk-Fl] ), K = Fl+Fr
template<int BM, int BN, int TM>
__global__ void k_gemm_up(const float* __restrict__ xl, const int* __restrict__ inv,
                          const float* __restrict__ xr, int Fl, int Fr,
                          const float* __restrict__ W, float* __restrict__ Y,
                          int M, int K, int F) {
    constexpr int TX = BN / 4;
    __shared__ float Xs[BM][33];
    __shared__ float Ws[32][BN + 4];
    __shared__ int sIdx[BM];
    int tid = threadIdx.x;
    int txn = tid % TX, tym = tid / TX;
    int m0 = blockIdx.x * BM, n0 = blockIdx.y * BN;
    if (tid < BM) sIdx[tid] = inv[m0 + tid];
    float acc[TM][4];
#pragma unroll
    for (int i = 0; i < TM; i++)
#pragma unroll
        for (int j = 0; j < 4; j++) acc[i][j] = 0.f;
    __syncthreads();
    for (int k0 = 0; k0 < K; k0 += 32) {
        for (int idx = tid; idx < BM * 32; idx += 256) {
            int r = idx >> 5, c = idx & 31;
            int kk = k0 + c;
            float v;
            if (kk < Fl) {
                int rr = sIdx[r];
                v = (rr >= 0) ? xl[(size_t)rr * Fl + kk] : 0.f;
            } else {
                v = xr[(size_t)(m0 + r) * Fr + (kk - Fl)];
            }
            Xs[r][c] = eluf(v);
        }
        for (int idx = tid; idx < 32 * BN; idx += 256) {
            int r = idx / BN, c = idx % BN;
            Ws[r][c] = W[(size_t)(k0 + r) * F + n0 + c];
        }
        __syncthreads();
#pragma unroll 4
        for (int kk = 0; kk < 32; kk++) {
            float4 wv = *(const float4*)&Ws[kk][txn * 4];
#pragma unroll
            for (int i = 0; i < TM; i++) {
                float xv = Xs[tym * TM + i][kk];
                acc[i][0] += xv * wv.x;
                acc[i][1] += xv * wv.y;
                acc[i][2] += xv * wv.z;
                acc[i][3] += xv * wv.w;
            }
        }
        __syncthreads();
    }
#pragma unroll
    for (int i = 0; i < TM; i++) {
        float4 v = make_float4(acc[i][0], acc[i][1], acc[i][2], acc[i][3]);
        *(float4*)&Y[(size_t)(m0 + tym * TM + i) * F + n0 + txn * 4] = v;
    }
}

// ---- CSR gather propagate + self + bias + elu (+ optional pooling score) ----
// L1=1: row = rsA[d]..rsA[d+1], entries dup-flag-masked (multiplicity kept).
// L1=0: row = rsA[d]..rsA[d]+rsB[d].
template<int LOGF, int SCORE, int L1>
__global__ void k_prop(const int* __restrict__ csr, const int* __restrict__ rsA,
                       const int* __restrict__ rsB, const float* __restrict__ dinv,
                       const float* __restrict__ xW, const float* __restrict__ b,
                       float* __restrict__ xout, const float* __restrict__ p,
                       float* __restrict__ score) {
    constexpr int F = 1 << LOGF;
    int t = blockIdx.x * 256 + threadIdx.x;
    int d = t >> LOGF, f = t & (F - 1);
    int j0, j1;
    if (L1) { j0 = rsA[d]; j1 = rsA[d + 1]; }
    else    { j0 = rsA[d]; j1 = j0 + rsB[d]; }
    float dd = dinv[d];
    float sum = dd * xW[t];
    for (int j = j0; j < j1; j++) {
        int e = csr[j];
        int s = L1 ? (e & 0x7fffffff) : e;
        sum += dinv[s] * xW[(s << LOGF) + f];
    }
    float v = eluf(dd * sum + b[f]);
    xout[t] = v;
    if (SCORE) {
        float pf = p[f];
        float sc = v * pf, nr = pf * pf;
        if (LOGF == 5) {
            for (int m = 16; m >= 1; m >>= 1) {
                sc += __shfl_xor(sc, m, 32); nr += __shfl_xor(nr, m, 32);
            }
            if ((threadIdx.x & 31) == 0) score[d] = sc / sqrtf(nr);
        } else if (LOGF == 6) {
            for (int m = 32; m >= 1; m >>= 1) {
                sc += __shfl_xor(sc, m, 64); nr += __shfl_xor(nr, m, 64);
            }
            if ((threadIdx.x & 63) == 0) score[d] = sc / sqrtf(nr);
        } else {
            __shared__ float ssc[4], snr[4];
            for (int m = 32; m >= 1; m >>= 1) {
                sc += __shfl_xor(sc, m, 64); nr += __shfl_xor(nr, m, 64);
            }
            int wv = threadIdx.x >> 6;
            if ((threadIdx.x & 63) == 0) { ssc[wv] = sc; snr[wv] = nr; }
            __syncthreads();
            if (f == 0) score[d] = (ssc[wv] + ssc[wv + 1]) / sqrtf(snr[wv] + snr[wv + 1]);
        }
    }
}

// ==== bitonic top-k (descending, ties -> smaller index; exact jax order) ====
template<int NK>
__global__ void k_sortblk(const float* __restrict__ score, ull* __restrict__ keys,
                          int last, int k, int* __restrict__ out_idx) {
    __shared__ ull sk[NK];
    int base = blockIdx.x * NK;
    int tid = threadIdx.x;
    for (int i = tid; i < NK; i += 1024) {
        int gi = base + i;
        sk[i] = ((ull)f2s(score[gi]) << 32) | (unsigned)(~gi);
    }
    __syncthreads();
    for (int sz = 2; sz <= NK; sz <<= 1) {
        for (int st = sz >> 1; st > 0; st >>= 1) {
            for (int pp = tid; pp < NK / 2; pp += 1024) {
                int i = ((pp & ~(st - 1)) << 1) | (pp & (st - 1));
                int jj = i | st;
                ull a = sk[i], bb = sk[jj];
                bool desc = (((base + i) & sz) == 0);
                if (desc ? (a < bb) : (a > bb)) { sk[i] = bb; sk[jj] = a; }
            }
            __syncthreads();
        }
    }
    if (last) {
        for (int i = tid; i < NK; i += 1024) {
            int gi = base + i;
            if (gi < k) out_idx[gi] = (int)(~(unsigned)(sk[i] & 0xFFFFFFFFu));
        }
    } else {
        for (int i = tid; i < NK; i += 1024) keys[base + i] = sk[i];
    }
}

// final 8192 merge (input: two sorted-4096 halves, desc|asc = bitonic); desc everywhere
__global__ void k_merge8k(const ull* __restrict__ keys, int k, int* __restrict__ out_idx) {
    __shared__ ull sk[8192];
    int tid = threadIdx.x;
    for (int i = tid; i < 8192; i += 1024) sk[i] = keys[i];
    __syncthreads();
    for (int st = 4096; st > 0; st >>= 1) {
        for (int pp = tid; pp < 4096; pp += 1024) {
            int i = ((pp & ~(st - 1)) << 1) | (pp & (st - 1));
            int jj = i | st;
            ull a = sk[i], bb = sk[jj];
            if (a < bb) { sk[i] = bb; sk[jj] = a; }
        }
        __syncthreads();
    }
    for (int i = tid; i < k; i += 1024)
        out_idx[i] = (int)(~(unsigned)(sk[i] & 0xFFFFFFFFu));
}

// ---- pooled features + inverse map in one pass ----
__global__ void k_poolxp(const float* __restrict__ x, const float* __restrict__ score,
                         const int* __restrict__ idx, int k, int F,
                         float* __restrict__ xout, int* __restrict__ invmap) {
    int t = blockIdx.x * blockDim.x + threadIdx.x;
    if (t >= k * F) return;
    int r = t / F, f = t - r * F;
    int j = idx[r];
    xout[t] = eluf(x[(size_t)j * F + f] * sigf(score[j]));
    if (f == 0) invmap[j] = r;
}

// ---- atomic-free segment max/sum/count: one block per graph ----
__global__ void k_seg2(const float* __restrict__ x13, const int* __restrict__ gstart,
                       float* __restrict__ gmaxf, float* __restrict__ gsum,
                       int* __restrict__ gcnt) {
    __shared__ float sm[8][32], ss[8][32];
    int g = blockIdx.x;
    int j0 = gstart[g], j1 = gstart[g + 1];
    int t = threadIdx.x;
    int f = t & 31, r = t >> 5;
    float m = -INFINITY, s = 0.f;
    for (int j = j0 + r; j < j1; j += 8) {
        float v = x13[(j << 5) + f];
        m = fmaxf(m, v);
        s += v;
    }
    sm[r][f] = m; ss[r][f] = s;
    __syncthreads();
    if (t < 32) {
        float mm = sm[0][t], sss = ss[0][t];
        for (int i = 1; i < 8; i++) { mm = fmaxf(mm, sm[i][t]); sss += ss[i][t]; }
        gmaxf[(g << 5) + t] = mm;
        gsum[(g << 5) + t] = sss;
        if (t == 0) gcnt[g] = j1 - j0;
    }
}

// ---- head ----
__global__ void k_head(const float* __restrict__ gmaxf, const float* __restrict__ gsum,
                       const int* __restrict__ gcnt, const float* __restrict__ Wl1,
                       const float* __restrict__ Wc, const float* __restrict__ bc,
                       float* __restrict__ out) {
    __shared__ float h0[GG * 64];
    __shared__ float h1[GG * 64];
    __shared__ float lg[GG * CC];
    int tid = threadIdx.x;
    for (int t = tid; t < GG * 64; t += blockDim.x) {
        int g = t >> 6, c = t & 63;
        float v;
        if (c < 32) v = gmaxf[(g << 5) + c];
        else v = gsum[(g << 5) + (c - 32)] / (float)gcnt[g];
        h0[t] = eluf(v);
    }
    __syncthreads();
    for (int t = tid; t < GG * 64; t += blockDim.x) {
        int g = t >> 6, j = t & 63;
        float s = 0.f;
        for (int k = 0; k < 64; k++) s += h0[(g << 6) + k] * Wl1[k * 64 + j];
        h1[t] = eluf(s);
    }
    __syncthreads();
    for (int t = tid; t < GG * CC; t += blockDim.x) {
        int g = t / CC, c = t - g * CC;
        float s = bc[c];
        for (int k = 0; k < 64; k++) s += h1[(g << 6) + k] * Wc[k * CC + c];
        lg[t] = s;
    }
    __syncthreads();
    if (tid < GG) {
        int g = tid;
        float m = -1e30f;
        for (int c = 0; c < CC; c++) m = fmaxf(m, lg[g * CC + c]);
        float se = 0.f;
        for (int c = 0; c < CC; c++) se += expf(lg[g * CC + c] - m);
        float lse = m + logf(se);
        for (int c = 0; c < CC; c++) out[g * CC + c] = lg[g * CC + c] - lse;
    }
}

extern "C" void kernel_launch(void* const* d_in, const int* in_sizes, int n_in,
                              void* d_out, int out_size, void* d_ws, size_t ws_size,
                              hipStream_t stream) {
    const float* x = (const float*)d_in[0];
    const int* ei = (const int*)d_in[1];
    const int* batch = (const int*)d_in[2];
    const float* W1 = (const float*)d_in[3];  const float* b1 = (const float*)d_in[4];
    const float* W2 = (const float*)d_in[5];  const float* b2 = (const float*)d_in[6];
    const float* W3 = (const float*)d_in[7];  const float* b3 = (const float*)d_in[8];
    const float* W4 = (const float*)d_in[9];  const float* b4 = (const float*)d_in[10];
    const float* W5 = (const float*)d_in[11]; const float* b5 = (const float*)d_in[12];
    const float* W6 = (const float*)d_in[13]; const float* b6 = (const float*)d_in[14];
    const float* W7 = (const float*)d_in[15]; const float* b7 = (const float*)d_in[16];
    const float* p1 = (const float*)d_in[17];
    const float* p2 = (const float*)d_in[18];
    const float* p3 = (const float*)d_in[19];
    const float* Wl1 = (const float*)d_in[20];
    const float* Wc = (const float*)d_in[21];
    const float* bc = (const float*)d_in[22];
    float* out = (float*)d_out;
    (void)in_sizes; (void)n_in; (void)out_size; (void)ws_size;

    char* w = (char*)d_ws;
    size_t off = 0;
    auto alloc = [&](size_t bytes) -> char* {
        char* p = w + off;
        off = (off + bytes + 255) & ~(size_t)255;
        return p;
    };

    // ---- zero-initialized span ----
    size_t zero_begin = off;
    unsigned* bitmap = (unsigned*)alloc((size_t)NN * NN / 8);   // 8 MB
    int* cnt1 = (int*)alloc(NN * 4);
    size_t zero_len = off - zero_begin;

    // ---- 0xFF-initialized span (inverse maps = -1) ----
    size_t ff_begin = off;
    int* pos2 = (int*)alloc(NN * 4);     // orig -> level2
    int* inv4 = (int*)alloc(KK1 * 4);    // level2 -> level3
    int* inv6 = (int*)alloc(KK2 * 4);    // level3 -> level4
    size_t ff_len = off - ff_begin;

    // ---- uninitialized scratch ----
    unsigned char* rep = (unsigned char*)alloc(EE);
    float* dinv1 = (float*)alloc(NN * 4);
    float* dinv2 = (float*)alloc(KK1 * 4);
    float* dinv3 = (float*)alloc(KK2 * 4);
    float* dinv4 = (float*)alloc(KK3 * 4);
    int* rs1 = (int*)alloc((NN + 1) * 4);
    int* cur1 = (int*)alloc(NN * 4);
    int* roff2 = (int*)alloc(KK1 * 4); int* deg2 = (int*)alloc(KK1 * 4);
    int* roff3 = (int*)alloc(KK2 * 4); int* deg3 = (int*)alloc(KK2 * 4);
    int* roff4 = (int*)alloc(KK3 * 4); int* deg4 = (int*)alloc(KK3 * 4);
    int* csr1 = (int*)alloc((size_t)EE * 4);
    int* csr2 = (int*)alloc((size_t)EE * 4);
    int* csr3 = (int*)alloc((size_t)EE * 4);
    int* csr4 = (int*)alloc((size_t)EE * 4);
    float* xW = (float*)alloc((size_t)262144 * 4);
    float* x1 = (float*)alloc((size_t)NN * 32 * 4);
    float* x2 = (float*)alloc((size_t)KK1 * 32 * 4);
    float* x3 = (float*)alloc((size_t)KK1 * 64 * 4);
    float* x4 = (float*)alloc((size_t)KK2 * 64 * 4);
    float* x5 = (float*)alloc((size_t)KK2 * 128 * 4);
    float* x6 = (float*)alloc((size_t)KK3 * 128 * 4);
    float* x7 = (float*)alloc((size_t)KK3 * 256 * 4);
    float* x9 = (float*)alloc((size_t)KK2 * 128 * 4);
    float* x11 = (float*)alloc((size_t)KK1 * 64 * 4);
    float* x13 = (float*)alloc((size_t)NN * 32 * 4);
    float* score1 = (float*)alloc(NN * 4);
    float* score2 = (float*)alloc(KK1 * 4);
    float* score3 = (float*)alloc(KK2 * 4);
    int* i2 = (int*)alloc(KK1 * 4);
    int* i4 = (int*)alloc(KK2 * 4);
    int* i6 = (int*)alloc(KK3 * 4);
    ull* keys = (ull*)alloc((size_t)NN * 8);
    int* gstart = (int*)alloc((GG + 1) * 4);
    float* gmaxf = (float*)alloc(GG * 32 * 4);
    float* gsum = (float*)alloc(GG * 32 * 4);
    int* gcnt = (int*)alloc(GG * 4);

    hipMemsetAsync(w + zero_begin, 0, zero_len, stream);
    hipMemsetAsync(w + ff_begin, 0xFF, ff_len, stream);

    const int B = 256;
    // ---- level-1 graph machinery ----
    k_edge_init<<<EE / B, B, 0, stream>>>(ei, bitmap, rep, cnt1, batch, gstart);
    k_prefix<<<1, 1024, 0, stream>>>(cnt1, rs1, cur1, dinv1, NN);
    k_csr_l1<<<EE / B, B, 0, stream>>>(ei, rep, cur1, csr1);

    // ---- gcn1 (+score1) ----
    k_gemm<32, 32, 1><<<dim3(NN / 32, 1), 256, 0, stream>>>(x, W1, xW, NN, 128, 32);
    k_prop<5, 1, 1><<<(NN * 32) / B, B, 0, stream>>>(csr1, rs1, nullptr, dinv1, xW, b1,
                                                     x1, p1, score1);

    // ---- pool1: top-4096 of 8192; CSR2 via subset filter ----
    k_sortblk<4096><<<2, 1024, 0, stream>>>(score1, keys, 0, KK1, i2);
    k_merge8k<<<1, 1024, 0, stream>>>(keys, KK1, i2);
    k_poolxp<<<(KK1 * 32) / B, B, 0, stream>>>(x1, score1, i2, KK1, 32, x2, pos2);
    k_sub<1><<<KK1 / 4, 256, 0, stream>>>(i2, KK1, csr1, nullptr, nullptr, rs1, pos2,
                                          csr2, roff2, deg2, dinv2);

    // ---- gcn2 (+score2) ----
    k_gemm<32, 64, 2><<<dim3(KK1 / 32, 1), 256, 0, stream>>>(x2, W2, xW, KK1, 32, 64);
    k_prop<6, 1, 0><<<(KK1 * 64) / B, B, 0, stream>>>(csr2, roff2, deg2, dinv2, xW, b2,
                                                      x3, p2, score2);

    // ---- pool2: top-2048 of 4096 ----
    k_sortblk<4096><<<1, 1024, 0, stream>>>(score2, keys, 1, KK2, i4);
    k_poolxp<<<(KK2 * 64) / B, B, 0, stream>>>(x3, score2, i4, KK2, 64, x4, inv4);
    k_sub<0><<<KK2 / 4, 256, 0, stream>>>(i4, KK2, csr2, roff2, deg2, nullptr, inv4,
                                          csr3, roff3, deg3, dinv3);

    // ---- gcn3 (+score3) ----
    k_gemm<32, 64, 2><<<dim3(KK2 / 32, 2), 256, 0, stream>>>(x4, W3, xW, KK2, 64, 128);
    k_prop<7, 1, 0><<<(KK2 * 128) / B, B, 0, stream>>>(csr3, roff3, deg3, dinv3, xW, b3,
                                                       x5, p3, score3);

    // ---- pool3: top-1024 of 2048 ----
    k_sortblk<2048><<<1, 1024, 0, stream>>>(score3, keys, 1, KK3, i6);
    k_poolxp<<<(KK3 * 128) / B, B, 0, stream>>>(x5, score3, i6, KK3, 128, x6, inv6);
    k_sub<0><<<KK3 / 4, 256, 0, stream>>>(i6, KK3, csr3, roff3, deg3, nullptr, inv6,
                                          csr4, roff4, deg4, dinv4);

    // ---- gcn4 ----
    k_gemm<32, 64, 2><<<dim3(KK3 / 32, 4), 256, 0, stream>>>(x6, W4, xW, KK3, 128, 256);
    k_prop<8, 0, 0><<<(KK3 * 256) / B, B, 0, stream>>>(csr4, roff4, deg4, dinv4, xW, b4,
                                                       x7, nullptr, nullptr);

    // ---- gcn5 (unpool3 fused into X staging) ----
    k_gemm_up<32, 64, 2><<<dim3(KK2 / 32, 2), 256, 0, stream>>>(x7, inv6, x5, 256, 128,
                                                                W5, xW, KK2, 384, 128);
    k_prop<7, 0, 0><<<(KK2 * 128) / B, B, 0, stream>>>(csr3, roff3, deg3, dinv3, xW, b5,
                                                       x9, nullptr, nullptr);

    // ---- gcn6 (unpool2 fused) ----
    k_gemm_up<32, 64, 2><<<dim3(KK1 / 32, 1), 256, 0, stream>>>(x9, inv4, x3, 128, 64,
                                                                W6, xW, KK1, 192, 64);
    k_prop<6, 0, 0><<<(KK1 * 64) / B, B, 0, stream>>>(csr2, roff2, deg2, dinv2, xW, b6,
                                                      x11, nullptr, nullptr);

    // ---- gcn7 (unpool1 fused; original weighted adjacency) ----
    k_gemm_up<32, 32, 1><<<dim3(NN / 32, 1), 256, 0, stream>>>(x11, pos2, x1, 64, 32,
                                                               W7, xW, NN, 96, 32);
    k_prop<5, 0, 1><<<(NN * 32) / B, B, 0, stream>>>(csr1, rs1, nullptr, dinv1, xW, b7,
                                                     x13, nullptr, nullptr);

    // ---- readout ----
    k_seg2<<<GG, 256, 0, stream>>>(x13, gstart, gmaxf, gsum, gcnt);
    k_head<<<1, 1024, 0, stream>>>(gmaxf, gsum, gcnt, Wl1, Wc, bc, out);
}

// Round 7
// 497.085 us; speedup vs baseline: 1.1912x; 1.0820x over previous
//
#include <hip/hip_runtime.h>
#include <math.h>

#define NN 8192
#define EE 262144
#define GG 64
#define CC 10
#define KK1 4096
#define KK2 2048
#define KK3 1024

typedef unsigned long long ull;

__device__ __forceinline__ float eluf(float x) { return x > 0.f ? x : expm1f(x); }
__device__ __forceinline__ float sigf(float x) { return 1.f / (1.f + expf(-x)); }
__device__ __forceinline__ unsigned f2s(float f) {
    unsigned u = __float_as_uint(f);
    return (u & 0x80000000u) ? ~u : (u | 0x80000000u);
}

// ---- edge init: dedup flag (bitmap) + weighted in-degree (L1) + graph bounds ----
__global__ void k_edge_init(const int* __restrict__ ei, unsigned* __restrict__ bitmap,
                            unsigned char* __restrict__ rep, int* __restrict__ cnt1,
                            const int* __restrict__ batch, int* __restrict__ gstart) {
    int e = blockIdx.x * blockDim.x + threadIdx.x;
    if (e >= EE) return;
    int s = ei[e], d = ei[EE + e];
    unsigned key = ((unsigned)s << 13) | (unsigned)d;   // N = 8192 = 2^13
    unsigned old = atomicOr(&bitmap[key >> 5], 1u << (key & 31u));
    rep[e] = ((old >> (key & 31u)) & 1u) ? 0 : 1;
    atomicAdd(&cnt1[d], 1);
    if (e < NN) {
        int g = batch[e];
        int prev = (e == 0) ? -1 : batch[e - 1];
        for (int gg = prev + 1; gg <= g; gg++) gstart[gg] = e;
        if (e == NN - 1)
            for (int gg = g + 1; gg <= GG; gg++) gstart[gg] = NN;
    }
}

// ---- prefix scan over cnt1 -> rs1[n+1], cursors, dinv1 ----
__global__ void k_prefix(const int* __restrict__ cnt, int* __restrict__ rs,
                         int* __restrict__ cur, float* __restrict__ dinv, int n) {
    __shared__ int ts[1024];
    int tid = threadIdx.x;
    int ept = n >> 10;
    int base = tid * ept;
    int local[8];
    int s = 0;
    for (int i = 0; i < ept; i++) { local[i] = cnt[base + i]; s += local[i]; }
    ts[tid] = s;
    __syncthreads();
    for (int off = 1; off < 1024; off <<= 1) {
        int v = ts[tid];
        int add = (tid >= off) ? ts[tid - off] : 0;
        __syncthreads();
        ts[tid] = v + add;
        __syncthreads();
    }
    int run = (tid == 0) ? 0 : ts[tid - 1];
    for (int i = 0; i < ept; i++) {
        rs[base + i] = run; cur[base + i] = run;
        dinv[base + i] = 1.f / sqrtf((float)(local[i] + 1));
        run += local[i];
    }
    if (tid == 1023) rs[n] = run;
}

// ---- level-1 CSR scatter, dup flag in sign bit ----
__global__ void k_csr_l1(const int* __restrict__ ei, const unsigned char* __restrict__ rep,
                         int* __restrict__ cur, int* __restrict__ csr) {
    int e = blockIdx.x * blockDim.x + threadIdx.x;
    if (e >= EE) return;
    int s = ei[e];
    csr[atomicAdd(&cur[ei[EE + e]], 1)] = rep[e] ? s : (s | 0x80000000);
}

// ---- subset filter: build level CSR from previous level CSR, wave per row ----
template<int L1>
__global__ void k_sub(const int* __restrict__ idx, int nrows,
                      const int* __restrict__ csrP, const int* __restrict__ roffP,
                      const int* __restrict__ degP, const int* __restrict__ rsl1,
                      const int* __restrict__ invmap,
                      int* __restrict__ csrO, int* __restrict__ roffO,
                      int* __restrict__ degO, float* __restrict__ dinvO) {
    int wid = (blockIdx.x * blockDim.x + threadIdx.x) >> 6;
    int lane = threadIdx.x & 63;
    if (wid >= nrows) return;
    int j = idx[wid];
    int j0, len;
    if (L1) { j0 = rsl1[j]; len = rsl1[j + 1] - j0; }
    else    { j0 = roffP[j]; len = degP[j]; }
    int cnt = 0;
    for (int base = 0; base < len; base += 64) {
        bool sel = false;
        int val = 0;
        if (base + lane < len) {
            int e = csrP[j0 + base + lane];
            if (!L1 || e >= 0) {
                int s = L1 ? (e & 0x7fffffff) : e;
                int v = invmap[s];
                if (v >= 0) { sel = true; val = v; }
            }
        }
        ull m = __ballot(sel);
        if (sel) {
            int off = __popcll(m & ((1ull << lane) - 1ull));
            csrO[j0 + cnt + off] = val;
        }
        cnt += __popcll(m);
    }
    if (lane == 0) {
        roffO[wid] = j0;
        degO[wid] = cnt;
        dinvO[wid] = 1.f / sqrtf((float)(cnt + 1));
    }
}

// ---- tiled register-blocked GEMM: Y[M,F] = X[M,K] @ W[K,F] ----
template<int BM, int BN, int TM>
__global__ void k_gemm(const float* __restrict__ X, const float* __restrict__ W,
                       float* __restrict__ Y, int M, int K, int F) {
    constexpr int TX = BN / 4;
    __shared__ float Xs[BM][33];
    __shared__ float Ws[32][BN + 4];
    int tid = threadIdx.x;
    int txn = tid % TX, tym = tid / TX;
    int m0 = blockIdx.x * BM, n0 = blockIdx.y * BN;
    float acc[TM][4];
#pragma unroll
    for (int i = 0; i < TM; i++)
#pragma unroll
        for (int j = 0; j < 4; j++) acc[i][j] = 0.f;
    for (int k0 = 0; k0 < K; k0 += 32) {
        for (int idx = tid; idx < BM * 32; idx += 256) {
            int r = idx >> 5, c = idx & 31;
            Xs[r][c] = X[(size_t)(m0 + r) * K + k0 + c];
        }
        for (int idx = tid; idx < 32 * BN; idx += 256) {
            int r = idx / BN, c = idx % BN;
            Ws[r][c] = W[(size_t)(k0 + r) * F + n0 + c];
        }
        __syncthreads();
#pragma unroll 4
        for (int kk = 0; kk < 32; kk++) {
            float4 wv = *(const float4*)&Ws[kk][txn * 4];
#pragma unroll
            for (int i = 0; i < TM; i++) {
                float xv = Xs[tym * TM + i][kk];
                acc[i][0] += xv * wv.x;
                acc[i][1] += xv * wv.y;
                acc[i][2] += xv * wv.z;
                acc[i][3] += xv * wv.w;
            }
        }
        __syncthreads();
    }
#pragma unroll
    for (int i = 0; i < TM; i++) {
        float4 v = make_float4(acc[i][0], acc[i][1], acc[i][2], acc[i][3]);
        *(float4*)&Y[(size_t)(m0 + tym * TM + i) * F + n0 + txn * 4] = v;
    }
}

// ---- GEMM with fused unpool+concat+elu on the X operand ----
template<int BM, int BN, int TM>
__global__ void k_gemm_up(const float* __restrict__ xl, const int* __restrict__ inv,
                          const float* __restrict__ xr, int Fl, int Fr,
                          const float* __restrict__ W, float* __restrict__ Y,
                          int M, int K, int F) {
    constexpr int TX = BN / 4;
    __shared__ float Xs[BM][33];
    __shared__ float Ws[32][BN + 4];
    __shared__ int sIdx[BM];
    int tid = threadIdx.x;
    int txn = tid % TX, tym = tid / TX;
    int m0 = blockIdx.x * BM, n0 = blockIdx.y * BN;
    if (tid < BM) sIdx[tid] = inv[m0 + tid];
    float acc[TM][4];
#pragma unroll
    for (int i = 0; i < TM; i++)
#pragma unroll
        for (int j = 0; j < 4; j++) acc[i][j] = 0.f;
    __syncthreads();
    for (int k0 = 0; k0 < K; k0 += 32) {
        for (int idx = tid; idx < BM * 32; idx += 256) {
            int r = idx >> 5, c = idx & 31;
            int kk = k0 + c;
            float v;
            if (kk < Fl) {
                int rr = sIdx[r];
                v = (rr >= 0) ? xl[(size_t)rr * Fl + kk] : 0.f;
            } else {
                v = xr[(size_t)(m0 + r) * Fr + (kk - Fl)];
            }
            Xs[r][c] = eluf(v);
        }
        for (int idx = tid; idx < 32 * BN; idx += 256) {
            int r = idx / BN, c = idx % BN;
            Ws[r][c] = W[(size_t)(k0 + r) * F + n0 + c];
        }
        __syncthreads();
#pragma unroll 4
        for (int kk = 0; kk < 32; kk++) {
            float4 wv = *(const float4*)&Ws[kk][txn * 4];
#pragma unroll
            for (int i = 0; i < TM; i++) {
                float xv = Xs[tym * TM + i][kk];
                acc[i][0] += xv * wv.x;
                acc[i][1] += xv * wv.y;
                acc[i][2] += xv * wv.z;
                acc[i][3] += xv * wv.w;
            }
        }
        __syncthreads();
    }
#pragma unroll
    for (int i = 0; i < TM; i++) {
        float4 v = make_float4(acc[i][0], acc[i][1], acc[i][2], acc[i][3]);
        *(float4*)&Y[(size_t)(m0 + tym * TM + i) * F + n0 + txn * 4] = v;
    }
}

// ---- CSR gather propagate + self + bias + elu (+ optional pooling score) ----
template<int LOGF, int SCORE, int L1>
__global__ void k_prop(const int* __restrict__ csr, const int* __restrict__ rsA,
                       const int* __restrict__ rsB, const float* __restrict__ dinv,
                       const float* __restrict__ xW, const float* __restrict__ b,
                       float* __restrict__ xout, const float* __restrict__ p,
                       float* __restrict__ score) {
    constexpr int F = 1 << LOGF;
    int t = blockIdx.x * 256 + threadIdx.x;
    int d = t >> LOGF, f = t & (F - 1);
    int j0, j1;
    if (L1) { j0 = rsA[d]; j1 = rsA[d + 1]; }
    else    { j0 = rsA[d]; j1 = j0 + rsB[d]; }
    float dd = dinv[d];
    float sum = dd * xW[t];
    for (int j = j0; j < j1; j++) {
        int e = csr[j];
        int s = L1 ? (e & 0x7fffffff) : e;
        sum += dinv[s] * xW[(s << LOGF) + f];
    }
    float v = eluf(dd * sum + b[f]);
    xout[t] = v;
    if (SCORE) {
        float pf = p[f];
        float sc = v * pf, nr = pf * pf;
        if (LOGF == 5) {
            for (int m = 16; m >= 1; m >>= 1) {
                sc += __shfl_xor(sc, m, 32); nr += __shfl_xor(nr, m, 32);
            }
            if ((threadIdx.x & 31) == 0) score[d] = sc / sqrtf(nr);
        } else if (LOGF == 6) {
            for (int m = 32; m >= 1; m >>= 1) {
                sc += __shfl_xor(sc, m, 64); nr += __shfl_xor(nr, m, 64);
            }
            if ((threadIdx.x & 63) == 0) score[d] = sc / sqrtf(nr);
        } else {
            __shared__ float ssc[4], snr[4];
            for (int m = 32; m >= 1; m >>= 1) {
                sc += __shfl_xor(sc, m, 64); nr += __shfl_xor(nr, m, 64);
            }
            int wv = threadIdx.x >> 6;
            if ((threadIdx.x & 63) == 0) { ssc[wv] = sc; snr[wv] = nr; }
            __syncthreads();
            if (f == 0) score[d] = (ssc[wv] + ssc[wv + 1]) / sqrtf(snr[wv] + snr[wv + 1]);
        }
    }
}

// ==== hybrid register/LDS bitonic top-k ====
// Same comparator network as verified rounds (desc = ((gi & sz)==0), 64-bit keys,
// ties -> smaller index). Thread t holds positions base+t and base+t+1024.

__device__ __forceinline__ ull cex_shfl(ull v, int st, bool takeMax) {
    ull pv = __shfl_xor(v, st, 64);
    return takeMax ? (v > pv ? v : pv) : (v < pv ? v : pv);
}

// full sort of a 2048-key window (stages 2..2048)
__global__ void k_wsort(const float* __restrict__ score, ull* __restrict__ keys,
                        int last, int k, int* __restrict__ out_idx) {
    __shared__ ull sk[2048];
    int tid = threadIdx.x;
    int base = blockIdx.x << 11;
    int giA = base + tid, giB = giA + 1024;
    ull a = ((ull)f2s(score[giA]) << 32) | (unsigned)(~giA);
    ull b = ((ull)f2s(score[giB]) << 32) | (unsigned)(~giB);
    for (int sz = 2; sz <= 2048; sz <<= 1) {
        int st = sz >> 1;
        if (st >= 64) {
            sk[tid] = a; sk[tid + 1024] = b;
            __syncthreads();
            for (; st >= 64; st >>= 1) {
                int i = ((tid & ~(st - 1)) << 1) | (tid & (st - 1));
                int j = i | st;
                ull u = sk[i], v = sk[j];
                bool desc = (((base + i) & sz) == 0);
                if (desc ? (u < v) : (u > v)) { sk[i] = v; sk[j] = u; }
                __syncthreads();
            }
            a = sk[tid]; b = sk[tid + 1024];
        }
        for (; st >= 1; st >>= 1) {
            bool low = (tid & st) == 0;
            bool descA = ((giA & sz) == 0);
            bool descB = ((giB & sz) == 0);
            a = cex_shfl(a, st, descA == low);
            b = cex_shfl(b, st, descB == low);
        }
    }
    if (last) {
        if (giA < k) out_idx[giA] = (int)(~(unsigned)(a & 0xFFFFFFFFu));
        if (giB < k) out_idx[giB] = (int)(~(unsigned)(b & 0xFFFFFFFFu));
    } else {
        keys[giA] = a; keys[giB] = b;
    }
}

// one merge stage (strides 1024..1) over a 2048-key window
__global__ void k_wmerge(ull* __restrict__ keys, int sz, int last, int k,
                         int* __restrict__ out_idx) {
    __shared__ ull sk[2048];
    int tid = threadIdx.x;
    int base = blockIdx.x << 11;
    int giA = base + tid, giB = giA + 1024;
    sk[tid] = keys[giA]; sk[tid + 1024] = keys[giB];
    __syncthreads();
    for (int st = 1024; st >= 64; st >>= 1) {
        int i = ((tid & ~(st - 1)) << 1) | (tid & (st - 1));
        int j = i | st;
        ull u = sk[i], v = sk[j];
        bool desc = (((base + i) & sz) == 0);
        if (desc ? (u < v) : (u > v)) { sk[i] = v; sk[j] = u; }
        __syncthreads();
    }
    ull a = sk[tid], b = sk[tid + 1024];
    for (int st = 32; st >= 1; st >>= 1) {
        bool low = (tid & st) == 0;
        bool descA = ((giA & sz) == 0);
        bool descB = ((giB & sz) == 0);
        a = cex_shfl(a, st, descA == low);
        b = cex_shfl(b, st, descB == low);
    }
    if (last) {
        if (giA < k) out_idx[giA] = (int)(~(unsigned)(a & 0xFFFFFFFFu));
        if (giB < k) out_idx[giB] = (int)(~(unsigned)(b & 0xFFFFFFFFu));
    } else {
        keys[giA] = a; keys[giB] = b;
    }
}

// stage sz=4096, stride 2048 (global orbit pairs)
__global__ void k_orbit4k(ull* __restrict__ keys) {
    int t = blockIdx.x * 256 + threadIdx.x;
    int i = ((t & ~2047) << 1) | (t & 2047);
    int j = i | 2048;
    ull a = keys[i], b = keys[j];
    bool desc = ((i & 4096) == 0);
    if (desc ? (a < b) : (a > b)) { keys[i] = b; keys[j] = a; }
}

// n=8192 final stage, strides 4096+2048 (desc everywhere)
__global__ void k_stage8k_hi(ull* __restrict__ keys) {
    int t = blockIdx.x * 256 + threadIdx.x;      // 0..2047
    ull a = keys[t], b = keys[t + 2048], c = keys[t + 4096], d = keys[t + 6144], x;
    if (a < c) { x = a; a = c; c = x; }
    if (b < d) { x = b; b = d; d = x; }
    if (a < b) { x = a; a = b; b = x; }
    if (c < d) { x = c; c = d; d = x; }
    keys[t] = a; keys[t + 2048] = b; keys[t + 4096] = c; keys[t + 6144] = d;
}

// ---- pooled features + inverse map in one pass ----
__global__ void k_poolxp(const float* __restrict__ x, const float* __restrict__ score,
                         const int* __restrict__ idx, int k, int F,
                         float* __restrict__ xout, int* __restrict__ invmap) {
    int t = blockIdx.x * blockDim.x + threadIdx.x;
    if (t >= k * F) return;
    int r = t / F, f = t - r * F;
    int j = idx[r];
    xout[t] = eluf(x[(size_t)j * F + f] * sigf(score[j]));
    if (f == 0) invmap[j] = r;
}

// ---- atomic-free segment max/sum/count: one block per graph ----
__global__ void k_seg2(const float* __restrict__ x13, const int* __restrict__ gstart,
                       float* __restrict__ gmaxf, float* __restrict__ gsum,
                       int* __restrict__ gcnt) {
    __shared__ float sm[8][32], ss[8][32];
    int g = blockIdx.x;
    int j0 = gstart[g], j1 = gstart[g + 1];
    int t = threadIdx.x;
    int f = t & 31, r = t >> 5;
    float m = -INFINITY, s = 0.f;
    for (int j = j0 + r; j < j1; j += 8) {
        float v = x13[(j << 5) + f];
        m = fmaxf(m, v);
        s += v;
    }
    sm[r][f] = m; ss[r][f] = s;
    __syncthreads();
    if (t < 32) {
        float mm = sm[0][t], sss = ss[0][t];
        for (int i = 1; i < 8; i++) { mm = fmaxf(mm, sm[i][t]); sss += ss[i][t]; }
        gmaxf[(g << 5) + t] = mm;
        gsum[(g << 5) + t] = sss;
        if (t == 0) gcnt[g] = j1 - j0;
    }
}

// ---- head ----
__global__ void k_head(const float* __restrict__ gmaxf, const float* __restrict__ gsum,
                       const int* __restrict__ gcnt, const float* __restrict__ Wl1,
                       const float* __restrict__ Wc, const float* __restrict__ bc,
                       float* __restrict__ out) {
    __shared__ float h0[GG * 64];
    __shared__ float h1[GG * 64];
    __shared__ float lg[GG * CC];
    int tid = threadIdx.x;
    for (int t = tid; t < GG * 64; t += blockDim.x) {
        int g = t >> 6, c = t & 63;
        float v;
        if (c < 32) v = gmaxf[(g << 5) + c];
        else v = gsum[(g << 5) + (c - 32)] / (float)gcnt[g];
        h0[t] = eluf(v);
    }
    __syncthreads();
    for (int t = tid; t < GG * 64; t += blockDim.x) {
        int g = t >> 6, j = t & 63;
        float s = 0.f;
        for (int k = 0; k < 64; k++) s += h0[(g << 6) + k] * Wl1[k * 64 + j];
        h1[t] = eluf(s);
    }
    __syncthreads();
    for (int t = tid; t < GG * CC; t += blockDim.x) {
        int g = t / CC, c = t - g * CC;
        float s = bc[c];
        for (int k = 0; k < 64; k++) s += h1[(g << 6) + k] * Wc[k * CC + c];
        lg[t] = s;
    }
    __syncthreads();
    if (tid < GG) {
        int g = tid;
        float m = -1e30f;
        for (int c = 0; c < CC; c++) m = fmaxf(m, lg[g * CC + c]);
        float se = 0.f;
        for (int c = 0; c < CC; c++) se += expf(lg[g * CC + c] - m);
        float lse = m + logf(se);
        for (int c = 0; c < CC; c++) out[g * CC + c] = lg[g * CC + c] - lse;
    }
}

static void run_topk(const float* score, ull* keys, int n, int k, int* out_idx,
                     hipStream_t stream) {
    if (n == 2048) {
        k_wsort<<<1, 1024, 0, stream>>>(score, keys, 1, k, out_idx);
        return;
    }
    k_wsort<<<n >> 11, 1024, 0, stream>>>(score, keys, 0, k, out_idx);
    if (n == 4096) {
        k_orbit4k<<<8, 256, 0, stream>>>(keys);
        k_wmerge<<<1, 1024, 0, stream>>>(keys, 4096, 1, k, out_idx);   // ranks [0,2048)
    } else {                                   // 8192
        k_orbit4k<<<16, 256, 0, stream>>>(keys);
        k_wmerge<<<4, 1024, 0, stream>>>(keys, 4096, 0, k, out_idx);
        k_stage8k_hi<<<8, 256, 0, stream>>>(keys);
        k_wmerge<<<2, 1024, 0, stream>>>(keys, 8192, 1, k, out_idx);   // ranks [0,4096)
    }
}

extern "C" void kernel_launch(void* const* d_in, const int* in_sizes, int n_in,
                              void* d_out, int out_size, void* d_ws, size_t ws_size,
                              hipStream_t stream) {
    const float* x = (const float*)d_in[0];
    const int* ei = (const int*)d_in[1];
    const int* batch = (const int*)d_in[2];
    const float* W1 = (const float*)d_in[3];  const float* b1 = (const float*)d_in[4];
    const float* W2 = (const float*)d_in[5];  const float* b2 = (const float*)d_in[6];
    const float* W3 = (const float*)d_in[7];  const float* b3 = (const float*)d_in[8];
    const float* W4 = (const float*)d_in[9];  const float* b4 = (const float*)d_in[10];
    const float* W5 = (const float*)d_in[11]; const float* b5 = (const float*)d_in[12];
    const float* W6 = (const float*)d_in[13]; const float* b6 = (const float*)d_in[14];
    const float* W7 = (const float*)d_in[15]; const float* b7 = (const float*)d_in[16];
    const float* p1 = (const float*)d_in[17];
    const float* p2 = (const float*)d_in[18];
    const float* p3 = (const float*)d_in[19];
    const float* Wl1 = (const float*)d_in[20];
    const float* Wc = (const float*)d_in[21];
    const float* bc = (const float*)d_in[22];
    float* out = (float*)d_out;
    (void)in_sizes; (void)n_in; (void)out_size; (void)ws_size;

    char* w = (char*)d_ws;
    size_t off = 0;
    auto alloc = [&](size_t bytes) -> char* {
        char* p = w + off;
        off = (off + bytes + 255) & ~(size_t)255;
        return p;
    };

    // ---- zero-initialized span ----
    size_t zero_begin = off;
    unsigned* bitmap = (unsigned*)alloc((size_t)NN * NN / 8);   // 8 MB
    int* cnt1 = (int*)alloc(NN * 4);
    size_t zero_len = off - zero_begin;

    // ---- 0xFF-initialized span (inverse maps = -1) ----
    size_t ff_begin = off;
    int* pos2 = (int*)alloc(NN * 4);     // orig -> level2
    int* inv4 = (int*)alloc(KK1 * 4);    // level2 -> level3
    int* inv6 = (int*)alloc(KK2 * 4);    // level3 -> level4
    size_t ff_len = off - ff_begin;

    // ---- uninitialized scratch ----
    unsigned char* rep = (unsigned char*)alloc(EE);
    float* dinv1 = (float*)alloc(NN * 4);
    float* dinv2 = (float*)alloc(KK1 * 4);
    float* dinv3 = (float*)alloc(KK2 * 4);
    float* dinv4 = (float*)alloc(KK3 * 4);
    int* rs1 = (int*)alloc((NN + 1) * 4);
    int* cur1 = (int*)alloc(NN * 4);
    int* roff2 = (int*)alloc(KK1 * 4); int* deg2 = (int*)alloc(KK1 * 4);
    int* roff3 = (int*)alloc(KK2 * 4); int* deg3 = (int*)alloc(KK2 * 4);
    int* roff4 = (int*)alloc(KK3 * 4); int* deg4 = (int*)alloc(KK3 * 4);
    int* csr1 = (int*)alloc((size_t)EE * 4);
    int* csr2 = (int*)alloc((size_t)EE * 4);
    int* csr3 = (int*)alloc((size_t)EE * 4);
    int* csr4 = (int*)alloc((size_t)EE * 4);
    float* xW = (float*)alloc((size_t)262144 * 4);
    float* x1 = (float*)alloc((size_t)NN * 32 * 4);
    float* x2 = (float*)alloc((size_t)KK1 * 32 * 4);
    float* x3 = (float*)alloc((size_t)KK1 * 64 * 4);
    float* x4 = (float*)alloc((size_t)KK2 * 64 * 4);
    float* x5 = (float*)alloc((size_t)KK2 * 128 * 4);
    float* x6 = (float*)alloc((size_t)KK3 * 128 * 4);
    float* x7 = (float*)alloc((size_t)KK3 * 256 * 4);
    float* x9 = (float*)alloc((size_t)KK2 * 128 * 4);
    float* x11 = (float*)alloc((size_t)KK1 * 64 * 4);
    float* x13 = (float*)alloc((size_t)NN * 32 * 4);
    float* score1 = (float*)alloc(NN * 4);
    float* score2 = (float*)alloc(KK1 * 4);
    float* score3 = (float*)alloc(KK2 * 4);
    int* i2 = (int*)alloc(KK1 * 4);
    int* i4 = (int*)alloc(KK2 * 4);
    int* i6 = (int*)alloc(KK3 * 4);
    ull* keys = (ull*)alloc((size_t)NN * 8);
    int* gstart = (int*)alloc((GG + 1) * 4);
    float* gmaxf = (float*)alloc(GG * 32 * 4);
    float* gsum = (float*)alloc(GG * 32 * 4);
    int* gcnt = (int*)alloc(GG * 4);

    hipMemsetAsync(w + zero_begin, 0, zero_len, stream);
    hipMemsetAsync(w + ff_begin, 0xFF, ff_len, stream);

    const int B = 256;
    // ---- level-1 graph machinery ----
    k_edge_init<<<EE / B, B, 0, stream>>>(ei, bitmap, rep, cnt1, batch, gstart);
    k_prefix<<<1, 1024, 0, stream>>>(cnt1, rs1, cur1, dinv1, NN);
    k_csr_l1<<<EE / B, B, 0, stream>>>(ei, rep, cur1, csr1);

    // ---- gcn1 (+score1) ----
    k_gemm<32, 32, 1><<<dim3(NN / 32, 1), 256, 0, stream>>>(x, W1, xW, NN, 128, 32);
    k_prop<5, 1, 1><<<(NN * 32) / B, B, 0, stream>>>(csr1, rs1, nullptr, dinv1, xW, b1,
                                                     x1, p1, score1);

    // ---- pool1: top-4096 of 8192; CSR2 via subset filter ----
    run_topk(score1, keys, NN, KK1, i2, stream);
    k_poolxp<<<(KK1 * 32) / B, B, 0, stream>>>(x1, score1, i2, KK1, 32, x2, pos2);
    k_sub<1><<<KK1 / 4, 256, 0, stream>>>(i2, KK1, csr1, nullptr, nullptr, rs1, pos2,
                                          csr2, roff2, deg2, dinv2);

    // ---- gcn2 (+score2) ----
    k_gemm<32, 64, 2><<<dim3(KK1 / 32, 1), 256, 0, stream>>>(x2, W2, xW, KK1, 32, 64);
    k_prop<6, 1, 0><<<(KK1 * 64) / B, B, 0, stream>>>(csr2, roff2, deg2, dinv2, xW, b2,
                                                      x3, p2, score2);

    // ---- pool2: top-2048 of 4096 ----
    run_topk(score2, keys, KK1, KK2, i4, stream);
    k_poolxp<<<(KK2 * 64) / B, B, 0, stream>>>(x3, score2, i4, KK2, 64, x4, inv4);
    k_sub<0><<<KK2 / 4, 256, 0, stream>>>(i4, KK2, csr2, roff2, deg2, nullptr, inv4,
                                          csr3, roff3, deg3, dinv3);

    // ---- gcn3 (+score3) ----
    k_gemm<32, 64, 2><<<dim3(KK2 / 32, 2), 256, 0, stream>>>(x4, W3, xW, KK2, 64, 128);
    k_prop<7, 1, 0><<<(KK2 * 128) / B, B, 0, stream>>>(csr3, roff3, deg3, dinv3, xW, b3,
                                                       x5, p3, score3);

    // ---- pool3: top-1024 of 2048 ----
    run_topk(score3, keys, KK2, KK3, i6, stream);
    k_poolxp<<<(KK3 * 128) / B, B, 0, stream>>>(x5, score3, i6, KK3, 128, x6, inv6);
    k_sub<0><<<KK3 / 4, 256, 0, stream>>>(i6, KK3, csr3, roff3, deg3, nullptr, inv6,
                                          csr4, roff4, deg4, dinv4);

    // ---- gcn4 ----
    k_gemm<32, 64, 2><<<dim3(KK3 / 32, 4), 256, 0, stream>>>(x6, W4, xW, KK3, 128, 256);
    k_prop<8, 0, 0><<<(KK3 * 256) / B, B, 0, stream>>>(csr4, roff4, deg4, dinv4, xW, b4,
                                                       x7, nullptr, nullptr);

    // ---- gcn5 (unpool3 fused into X staging) ----
    k_gemm_up<32, 64, 2><<<dim3(KK2 / 32, 2), 256, 0, stream>>>(x7, inv6, x5, 256, 128,
                                                                W5, xW, KK2, 384, 128);
    k_prop<7, 0, 0><<<(KK2 * 128) / B, B, 0, stream>>>(csr3, roff3, deg3, dinv3, xW, b5,
                                                       x9, nullptr, nullptr);

    // ---- gcn6 (unpool2 fused) ----
    k_gemm_up<32, 64, 2><<<dim3(KK1 / 32, 1), 256, 0, stream>>>(x9, inv4, x3, 128, 64,
                                                                W6, xW, KK1, 192, 64);
    k_prop<6, 0, 0><<<(KK1 * 64) / B, B, 0, stream>>>(csr2, roff2, deg2, dinv2, xW, b6,
                                                      x11, nullptr, nullptr);

    // ---- gcn7 (unpool1 fused; original weighted adjacency) ----
    k_gemm_up<32, 32, 1><<<dim3(NN / 32, 1), 256, 0, stream>>>(x11, pos2, x1, 64, 32,
                                                               W7, xW, NN, 96, 32);
    k_prop<5, 0, 1><<<(NN * 32) / B, B, 0, stream>>>(csr1, rs1, nullptr, dinv1, xW, b7,
                                                     x13, nullptr, nullptr);

    // ---- readout ----
    k_seg2<<<GG, 256, 0, stream>>>(x13, gstart, gmaxf, gsum, gcnt);
    k_head<<<1, 1024, 0, stream>>>(gmaxf, gsum, gcnt, Wl1, Wc, bc, out);
}

// Round 9
// 411.640 us; speedup vs baseline: 1.4385x; 1.2076x over previous
//
#include <hip/hip_runtime.h>
#include <math.h>

#define NN 8192
#define EE 262144
#define GG 64
#define CC 10
#define KK1 4096
#define KK2 2048
#define KK3 1024

typedef unsigned long long ull;

__device__ __forceinline__ float eluf(float x) { return x > 0.f ? x : expm1f(x); }
__device__ __forceinline__ float sigf(float x) { return 1.f / (1.f + expf(-x)); }
__device__ __forceinline__ unsigned f2s(float f) {
    unsigned u = __float_as_uint(f);
    return (u & 0x80000000u) ? ~u : (u | 0x80000000u);
}

// ---- edge init: dedup flag (bitmap) + weighted in-degree (L1) + graph bounds ----
__global__ void k_edge_init(const int* __restrict__ ei, unsigned* __restrict__ bitmap,
                            unsigned char* __restrict__ rep, int* __restrict__ cnt1,
                            const int* __restrict__ batch, int* __restrict__ gstart) {
    int e = blockIdx.x * blockDim.x + threadIdx.x;
    if (e >= EE) return;
    int s = ei[e], d = ei[EE + e];
    unsigned key = ((unsigned)s << 13) | (unsigned)d;   // N = 8192 = 2^13
    unsigned old = atomicOr(&bitmap[key >> 5], 1u << (key & 31u));
    rep[e] = ((old >> (key & 31u)) & 1u) ? 0 : 1;
    atomicAdd(&cnt1[d], 1);
    if (e < NN) {
        int g = batch[e];
        int prev = (e == 0) ? -1 : batch[e - 1];
        for (int gg = prev + 1; gg <= g; gg++) gstart[gg] = e;
        if (e == NN - 1)
            for (int gg = g + 1; gg <= GG; gg++) gstart[gg] = NN;
    }
}

// ---- prefix scan over cnt1 -> rs1[n+1], cursors, dinv1 ----
__global__ void k_prefix(const int* __restrict__ cnt, int* __restrict__ rs,
                         int* __restrict__ cur, float* __restrict__ dinv, int n) {
    __shared__ int ts[1024];
    int tid = threadIdx.x;
    int ept = n >> 10;
    int base = tid * ept;
    int local[8];
    int s = 0;
    for (int i = 0; i < ept; i++) { local[i] = cnt[base + i]; s += local[i]; }
    ts[tid] = s;
    __syncthreads();
    for (int off = 1; off < 1024; off <<= 1) {
        int v = ts[tid];
        int add = (tid >= off) ? ts[tid - off] : 0;
        __syncthreads();
        ts[tid] = v + add;
        __syncthreads();
    }
    int run = (tid == 0) ? 0 : ts[tid - 1];
    for (int i = 0; i < ept; i++) {
        rs[base + i] = run; cur[base + i] = run;
        dinv[base + i] = 1.f / sqrtf((float)(local[i] + 1));
        run += local[i];
    }
    if (tid == 1023) rs[n] = run;
}

// ---- level-1 CSR scatter, dup flag in sign bit ----
__global__ void k_csr_l1(const int* __restrict__ ei, const unsigned char* __restrict__ rep,
                         int* __restrict__ cur, int* __restrict__ csr) {
    int e = blockIdx.x * blockDim.x + threadIdx.x;
    if (e >= EE) return;
    int s = ei[e];
    csr[atomicAdd(&cur[ei[EE + e]], 1)] = rep[e] ? s : (s | 0x80000000);
}

// ---- merged pool-features + subset-filter kernel ----
// blocks [0,nPool): xout[r,f] = elu(x[idx[r],f]*sig(score[idx[r]]))
// blocks [nPool,..): wave-per-row CSR subset filter (needs invmap complete = topk output)
template<int L1>
__global__ void k_pool_sub(const float* __restrict__ x, const float* __restrict__ score,
                           const int* __restrict__ idx, int k, int F,
                           float* __restrict__ xout, int nPool,
                           const int* __restrict__ csrP, const int* __restrict__ roffP,
                           const int* __restrict__ degP, const int* __restrict__ rsl1,
                           const int* __restrict__ invmap,
                           int* __restrict__ csrO, int* __restrict__ roffO,
                           int* __restrict__ degO, float* __restrict__ dinvO) {
    if ((int)blockIdx.x < nPool) {
        int t = blockIdx.x * 256 + threadIdx.x;
        if (t >= k * F) return;
        int r = t / F, f = t - r * F;
        int j = idx[r];
        xout[t] = eluf(x[(size_t)j * F + f] * sigf(score[j]));
        return;
    }
    int wid = (((int)blockIdx.x - nPool) * 256 + (int)threadIdx.x) >> 6;
    int lane = threadIdx.x & 63;
    if (wid >= k) return;
    int j = idx[wid];
    int j0, len;
    if (L1) { j0 = rsl1[j]; len = rsl1[j + 1] - j0; }
    else    { j0 = roffP[j]; len = degP[j]; }
    int cnt = 0;
    for (int base = 0; base < len; base += 64) {
        bool sel = false;
        int val = 0;
        if (base + lane < len) {
            int e = csrP[j0 + base + lane];
            if (!L1 || e >= 0) {
                int s = L1 ? (e & 0x7fffffff) : e;
                int v = invmap[s];
                if (v >= 0) { sel = true; val = v; }
            }
        }
        ull m = __ballot(sel);
        if (sel) {
            int off = __popcll(m & ((1ull << lane) - 1ull));
            csrO[j0 + cnt + off] = val;
        }
        cnt += __popcll(m);
    }
    if (lane == 0) {
        roffO[wid] = j0;
        degO[wid] = cnt;
        dinvO[wid] = 1.f / sqrtf((float)(cnt + 1));
    }
}

// ---- tiled register-blocked GEMM: Y[M,F] = X[M,K] @ W[K,F], BN=32 ----
__global__ void k_gemm(const float* __restrict__ X, const float* __restrict__ W,
                       float* __restrict__ Y, int M, int K, int F) {
    __shared__ float Xs[32][33];
    __shared__ float Ws[32][36];
    int tid = threadIdx.x;
    int txn = tid & 7, tym = tid >> 3;
    int m0 = blockIdx.x * 32, n0 = blockIdx.y * 32;
    float4 acc = make_float4(0.f, 0.f, 0.f, 0.f);
    for (int k0 = 0; k0 < K; k0 += 32) {
        {
            int r = tid >> 3, c4 = (tid & 7) << 2;
            *(float4*)&Xs[r][c4] = *(const float4*)&X[(size_t)(m0 + r) * K + k0 + c4];
            *(float4*)&Ws[r][c4] = *(const float4*)&W[(size_t)(k0 + r) * F + n0 + c4];
        }
        __syncthreads();
#pragma unroll 8
        for (int kk = 0; kk < 32; kk++) {
            float4 wv = *(const float4*)&Ws[kk][txn * 4];
            float xv = Xs[tym][kk];
            acc.x += xv * wv.x; acc.y += xv * wv.y;
            acc.z += xv * wv.z; acc.w += xv * wv.w;
        }
        __syncthreads();
    }
    *(float4*)&Y[(size_t)(m0 + tym) * F + n0 + txn * 4] = acc;
}

// ---- GEMM with fused unpool+concat+elu on the X operand, BN=32 ----
// X[m,kk] = elu( kk<Fl ? (inv[m]>=0 ? xl[inv[m],kk] : 0) : xr[m,kk-Fl] ), K = Fl+Fr
__global__ void k_gemm_up(const float* __restrict__ xl, const int* __restrict__ inv,
                          const float* __restrict__ xr, int Fl, int Fr,
                          const float* __restrict__ W, float* __restrict__ Y,
                          int M, int K, int F) {
    __shared__ float Xs[32][33];
    __shared__ float Ws[32][36];
    __shared__ int sIdx[32];
    int tid = threadIdx.x;
    int txn = tid & 7, tym = tid >> 3;
    int m0 = blockIdx.x * 32, n0 = blockIdx.y * 32;
    if (tid < 32) sIdx[tid] = inv[m0 + tid];
    float4 acc = make_float4(0.f, 0.f, 0.f, 0.f);
    __syncthreads();
    for (int k0 = 0; k0 < K; k0 += 32) {
        {
            int r = tid >> 3, c4 = (tid & 7) << 2;
            int kk = k0 + c4;
            float4 v;
            if (kk < Fl) {           // Fl,Fr multiples of 32 -> whole float4 on one side
                int rr = sIdx[r];
                v = (rr >= 0) ? *(const float4*)&xl[(size_t)rr * Fl + kk]
                              : make_float4(0.f, 0.f, 0.f, 0.f);
            } else {
                v = *(const float4*)&xr[(size_t)(m0 + r) * Fr + (kk - Fl)];
            }
            v.x = eluf(v.x); v.y = eluf(v.y); v.z = eluf(v.z); v.w = eluf(v.w);
            *(float4*)&Xs[r][c4] = v;
            *(float4*)&Ws[r][c4] = *(const float4*)&W[(size_t)(k0 + r) * F + n0 + c4];
        }
        __syncthreads();
#pragma unroll 8
        for (int kk = 0; kk < 32; kk++) {
            float4 wv = *(const float4*)&Ws[kk][txn * 4];
            float xv = Xs[tym][kk];
            acc.x += xv * wv.x; acc.y += xv * wv.y;
            acc.z += xv * wv.z; acc.w += xv * wv.w;
        }
        __syncthreads();
    }
    *(float4*)&Y[(size_t)(m0 + tym) * F + n0 + txn * 4] = acc;
}

// ---- CSR gather propagate (float4/thread) + self + bias + elu (+ score) ----
// grid must be exactly n*(F/4)/256 blocks of 256.
template<int LOGF, int SCORE, int L1>
__global__ void k_prop(const int* __restrict__ csr, const int* __restrict__ rsA,
                       const int* __restrict__ rsB, const float* __restrict__ dinv,
                       const float* __restrict__ xW, const float* __restrict__ b,
                       float* __restrict__ xout, const float* __restrict__ p,
                       float* __restrict__ score) {
    constexpr int FQ = 1 << (LOGF - 2);          // float4s per row
    const float4* xW4 = (const float4*)xW;
    int t = blockIdx.x * 256 + threadIdx.x;
    int d = t >> (LOGF - 2), q = t & (FQ - 1);
    int j0, j1;
    if (L1) { j0 = rsA[d]; j1 = rsA[d + 1]; }
    else    { j0 = rsA[d]; j1 = j0 + rsB[d]; }
    float dd = dinv[d];
    float4 v0 = xW4[t];
    float4 sum = make_float4(dd * v0.x, dd * v0.y, dd * v0.z, dd * v0.w);
    for (int j = j0; j < j1; j++) {
        int e = csr[j];
        int s = L1 ? (e & 0x7fffffff) : e;
        float ds = dinv[s];
        float4 xv = xW4[(s << (LOGF - 2)) + q];
        sum.x += ds * xv.x; sum.y += ds * xv.y;
        sum.z += ds * xv.z; sum.w += ds * xv.w;
    }
    float4 bv = *(const float4*)&b[q << 2];
    float4 o;
    o.x = eluf(dd * sum.x + bv.x);
    o.y = eluf(dd * sum.y + bv.y);
    o.z = eluf(dd * sum.z + bv.z);
    o.w = eluf(dd * sum.w + bv.w);
    ((float4*)xout)[t] = o;
    if (SCORE) {
        float4 pv = *(const float4*)&p[q << 2];
        float sc = o.x * pv.x + o.y * pv.y + o.z * pv.z + o.w * pv.w;
        float nr = pv.x * pv.x + pv.y * pv.y + pv.z * pv.z + pv.w * pv.w;
#pragma unroll
        for (int m = FQ >> 1; m >= 1; m >>= 1) {
            sc += __shfl_xor(sc, m, 64);
            nr += __shfl_xor(nr, m, 64);
        }
        if (q == 0) score[d] = sc / sqrtf(nr);
    }
}

// ==== hybrid register/LDS bitonic top-k (network identical to verified rounds) ====
__device__ __forceinline__ ull cex_shfl(ull v, int st, bool takeMax) {
    ull pv = __shfl_xor(v, st, 64);
    return takeMax ? (v > pv ? v : pv) : (v < pv ? v : pv);
}

// full sort of a 2048-key window (stages 2..2048)
__global__ void k_wsort(const float* __restrict__ score, ull* __restrict__ keys,
                        int last, int k, int* __restrict__ out_idx,
                        int* __restrict__ invmap) {
    __shared__ ull sk[2048];
    int tid = threadIdx.x;
    int base = blockIdx.x << 11;
    int giA = base + tid, giB = giA + 1024;
    ull a = ((ull)f2s(score[giA]) << 32) | (unsigned)(~giA);
    ull b = ((ull)f2s(score[giB]) << 32) | (unsigned)(~giB);
    for (int sz = 2; sz <= 2048; sz <<= 1) {
        int st = sz >> 1;
        if (st >= 64) {
            sk[tid] = a; sk[tid + 1024] = b;
            __syncthreads();
            for (; st >= 64; st >>= 1) {
                int i = ((tid & ~(st - 1)) << 1) | (tid & (st - 1));
                int j = i | st;
                ull u = sk[i], v = sk[j];
                bool desc = (((base + i) & sz) == 0);
                if (desc ? (u < v) : (u > v)) { sk[i] = v; sk[j] = u; }
                __syncthreads();
            }
            a = sk[tid]; b = sk[tid + 1024];
        }
        for (; st >= 1; st >>= 1) {
            bool low = (tid & st) == 0;
            bool descA = ((giA & sz) == 0);
            bool descB = ((giB & sz) == 0);
            a = cex_shfl(a, st, descA == low);
            b = cex_shfl(b, st, descB == low);
        }
    }
    if (last) {
        if (giA < k) {
            int j = (int)(~(unsigned)(a & 0xFFFFFFFFu));
            out_idx[giA] = j; invmap[j] = giA;
        }
        if (giB < k) {
            int j = (int)(~(unsigned)(b & 0xFFFFFFFFu));
            out_idx[giB] = j; invmap[j] = giB;
        }
    } else {
        keys[giA] = a; keys[giB] = b;
    }
}

// one merge stage (strides 1024..1) over a 2048-key window
__global__ void k_wmerge(ull* __restrict__ keys, int sz, int last, int k,
                         int* __restrict__ out_idx, int* __restrict__ invmap) {
    __shared__ ull sk[2048];
    int tid = threadIdx.x;
    int base = blockIdx.x << 11;
    int giA = base + tid, giB = giA + 1024;
    sk[tid] = keys[giA]; sk[tid + 1024] = keys[giB];
    __syncthreads();
    for (int st = 1024; st >= 64; st >>= 1) {
        int i = ((tid & ~(st - 1)) << 1) | (tid & (st - 1));
        int j = i | st;
        ull u = sk[i], v = sk[j];
        bool desc = (((base + i) & sz) == 0);
        if (desc ? (u < v) : (u > v)) { sk[i] = v; sk[j] = u; }
        __syncthreads();
    }
    ull a = sk[tid], b = sk[tid + 1024];
    for (int st = 32; st >= 1; st >>= 1) {
        bool low = (tid & st) == 0;
        bool descA = ((giA & sz) == 0);
        bool descB = ((giB & sz) == 0);
        a = cex_shfl(a, st, descA == low);
        b = cex_shfl(b, st, descB == low);
    }
    if (last) {
        if (giA < k) {
            int j = (int)(~(unsigned)(a & 0xFFFFFFFFu));
            out_idx[giA] = j; invmap[j] = giA;
        }
        if (giB < k) {
            int j = (int)(~(unsigned)(b & 0xFFFFFFFFu));
            out_idx[giB] = j; invmap[j] = giB;
        }
    } else {
        keys[giA] = a; keys[giB] = b;
    }
}

// stage sz=4096, stride 2048 (global orbit pairs)
__global__ void k_orbit4k(ull* __restrict__ keys) {
    int t = blockIdx.x * 256 + threadIdx.x;
    int i = ((t & ~2047) << 1) | (t & 2047);
    int j = i | 2048;
    ull a = keys[i], b = keys[j];
    bool desc = ((i & 4096) == 0);
    if (desc ? (a < b) : (a > b)) { keys[i] = b; keys[j] = a; }
}

// n=8192 final stage, strides 4096+2048 (desc everywhere)
__global__ void k_stage8k_hi(ull* __restrict__ keys) {
    int t = blockIdx.x * 256 + threadIdx.x;      // 0..2047
    ull a = keys[t], b = keys[t + 2048], c = keys[t + 4096], d = keys[t + 6144], x;
    if (a < c) { x = a; a = c; c = x; }
    if (b < d) { x = b; b = d; d = x; }
    if (a < b) { x = a; a = b; b = x; }
    if (c < d) { x = c; c = d; d = x; }
    keys[t] = a; keys[t + 2048] = b; keys[t + 4096] = c; keys[t + 6144] = d;
}

// ---- atomic-free segment max/sum/count: one block per graph ----
__global__ void k_seg2(const float* __restrict__ x13, const int* __restrict__ gstart,
                       float* __restrict__ gmaxf, float* __restrict__ gsum,
                       int* __restrict__ gcnt) {
    __shared__ float sm[8][32], ss[8][32];
    int g = blockIdx.x;
    int j0 = gstart[g], j1 = gstart[g + 1];
    int t = threadIdx.x;
    int f = t & 31, r = t >> 5;
    float m = -INFINITY, s = 0.f;
    for (int j = j0 + r; j < j1; j += 8) {
        float v = x13[(j << 5) + f];
        m = fmaxf(m, v);
        s += v;
    }
    sm[r][f] = m; ss[r][f] = s;
    __syncthreads();
    if (t < 32) {
        float mm = sm[0][t], sss = ss[0][t];
        for (int i = 1; i < 8; i++) { mm = fmaxf(mm, sm[i][t]); sss += ss[i][t]; }
        gmaxf[(g << 5) + t] = mm;
        gsum[(g << 5) + t] = sss;
        if (t == 0) gcnt[g] = j1 - j0;
    }
}

// ---- head ----
__global__ void k_head(const float* __restrict__ gmaxf, const float* __restrict__ gsum,
                       const int* __restrict__ gcnt, const float* __restrict__ Wl1,
                       const float* __restrict__ Wc, const float* __restrict__ bc,
                       float* __restrict__ out) {
    __shared__ float h0[GG * 64];
    __shared__ float h1[GG * 64];
    __shared__ float lg[GG * CC];
    int tid = threadIdx.x;
    for (int t = tid; t < GG * 64; t += blockDim.x) {
        int g = t >> 6, c = t & 63;
        float v;
        if (c < 32) v = gmaxf[(g << 5) + c];
        else v = gsum[(g << 5) + (c - 32)] / (float)gcnt[g];
        h0[t] = eluf(v);
    }
    __syncthreads();
    for (int t = tid; t < GG * 64; t += blockDim.x) {
        int g = t >> 6, j = t & 63;
        float s = 0.f;
        for (int k = 0; k < 64; k++) s += h0[(g << 6) + k] * Wl1[k * 64 + j];
        h1[t] = eluf(s);
    }
    __syncthreads();
    for (int t = tid; t < GG * CC; t += blockDim.x) {
        int g = t / CC, c = t - g * CC;
        float s = bc[c];
        for (int k = 0; k < 64; k++) s += h1[(g << 6) + k] * Wc[k * CC + c];
        lg[t] = s;
    }
    __syncthreads();
    if (tid < GG) {
        int g = tid;
        float m = -1e30f;
        for (int c = 0; c < CC; c++) m = fmaxf(m, lg[g * CC + c]);
        float se = 0.f;
        for (int c = 0; c < CC; c++) se += expf(lg[g * CC + c] - m);
        float lse = m + logf(se);
        for (int c = 0; c < CC; c++) out[g * CC + c] = lg[g * CC + c] - lse;
    }
}

static void run_topk(const float* score, ull* keys, int n, int k, int* out_idx,
                     int* invmap, hipStream_t stream) {
    if (n == 2048) {
        k_wsort<<<1, 1024, 0, stream>>>(score, keys, 1, k, out_idx, invmap);
        return;
    }
    k_wsort<<<n >> 11, 1024, 0, stream>>>(score, keys, 0, k, out_idx, invmap);
    if (n == 4096) {
        k_orbit4k<<<8, 256, 0, stream>>>(keys);
        k_wmerge<<<1, 1024, 0, stream>>>(keys, 4096, 1, k, out_idx, invmap);
    } else {                                   // 8192
        k_orbit4k<<<16, 256, 0, stream>>>(keys);
        k_wmerge<<<4, 1024, 0, stream>>>(keys, 4096, 0, k, out_idx, invmap);
        k_stage8k_hi<<<8, 256, 0, stream>>>(keys);
        k_wmerge<<<2, 1024, 0, stream>>>(keys, 8192, 1, k, out_idx, invmap);
    }
}

extern "C" void kernel_launch(void* const* d_in, const int* in_sizes, int n_in,
                              void* d_out, int out_size, void* d_ws, size_t ws_size,
                              hipStream_t stream) {
    const float* x = (const float*)d_in[0];
    const int* ei = (const int*)d_in[1];
    const int* batch = (const int*)d_in[2];
    const float* W1 = (const float*)d_in[3];  const float* b1 = (const float*)d_in[4];
    const float* W2 = (const float*)d_in[5];  const float* b2 = (const float*)d_in[6];
    const float* W3 = (const float*)d_in[7];  const float* b3 = (const float*)d_in[8];
    const float* W4 = (const float*)d_in[9];  const float* b4 = (const float*)d_in[10];
    const float* W5 = (const float*)d_in[11]; const float* b5 = (const float*)d_in[12];
    const float* W6 = (const float*)d_in[13]; const float* b6 = (const float*)d_in[14];
    const float* W7 = (const float*)d_in[15]; const float* b7 = (const float*)d_in[16];
    const float* p1 = (const float*)d_in[17];
    const float* p2 = (const float*)d_in[18];
    const float* p3 = (const float*)d_in[19];
    const float* Wl1 = (const float*)d_in[20];
    const float* Wc = (const float*)d_in[21];
    const float* bc = (const float*)d_in[22];
    float* out = (float*)d_out;
    (void)in_sizes; (void)n_in; (void)out_size; (void)ws_size;

    char* w = (char*)d_ws;
    size_t off = 0;
    auto alloc = [&](size_t bytes) -> char* {
        char* p = w + off;
        off = (off + bytes + 255) & ~(size_t)255;
        return p;
    };

    // ---- zero-initialized span ----
    size_t zero_begin = off;
    unsigned* bitmap = (unsigned*)alloc((size_t)NN * NN / 8);   // 8 MB
    int* cnt1 = (int*)alloc(NN * 4);
    size_t zero_len = off - zero_begin;

    // ---- 0xFF-initialized span (inverse maps = -1) ----
    size_t ff_begin = off;
    int* pos2 = (int*)alloc(NN * 4);     // orig -> level2
    int* inv4 = (int*)alloc(KK1 * 4);    // level2 -> level3
    int* inv6 = (int*)alloc(KK2 * 4);    // level3 -> level4
    size_t ff_len = off - ff_begin;

    // ---- uninitialized scratch ----
    unsigned char* rep = (unsigned char*)alloc(EE);
    float* dinv1 = (float*)alloc(NN * 4);
    float* dinv2 = (float*)alloc(KK1 * 4);
    float* dinv3 = (float*)alloc(KK2 * 4);
    float* dinv4 = (float*)alloc(KK3 * 4);
    int* rs1 = (int*)alloc((NN + 1) * 4);
    int* cur1 = (int*)alloc(NN * 4);
    int* roff2 = (int*)alloc(KK1 * 4); int* deg2 = (int*)alloc(KK1 * 4);
    int* roff3 = (int*)alloc(KK2 * 4); int* deg3 = (int*)alloc(KK2 * 4);
    int* roff4 = (int*)alloc(KK3 * 4); int* deg4 = (int*)alloc(KK3 * 4);
    int* csr1 = (int*)alloc((size_t)EE * 4);
    int* csr2 = (int*)alloc((size_t)EE * 4);
    int* csr3 = (int*)alloc((size_t)EE * 4);
    int* csr4 = (int*)alloc((size_t)EE * 4);
    float* xW = (float*)alloc((size_t)262144 * 4);
    float* x1 = (float*)alloc((size_t)NN * 32 * 4);
    float* x2 = (float*)alloc((size_t)KK1 * 32 * 4);
    float* x3 = (float*)alloc((size_t)KK1 * 64 * 4);
    float* x4 = (float*)alloc((size_t)KK2 * 64 * 4);
    float* x5 = (float*)alloc((size_t)KK2 * 128 * 4);
    float* x6 = (float*)alloc((size_t)KK3 * 128 * 4);
    float* x7 = (float*)alloc((size_t)KK3 * 256 * 4);
    float* x9 = (float*)alloc((size_t)KK2 * 128 * 4);
    float* x11 = (float*)alloc((size_t)KK1 * 64 * 4);
    float* x13 = (float*)alloc((size_t)NN * 32 * 4);
    float* score1 = (float*)alloc(NN * 4);
    float* score2 = (float*)alloc(KK1 * 4);
    float* score3 = (float*)alloc(KK2 * 4);
    int* i2 = (int*)alloc(KK1 * 4);
    int* i4 = (int*)alloc(KK2 * 4);
    int* i6 = (int*)alloc(KK3 * 4);
    ull* keys = (ull*)alloc((size_t)NN * 8);
    int* gstart = (int*)alloc((GG + 1) * 4);
    float* gmaxf = (float*)alloc(GG * 32 * 4);
    float* gsum = (float*)alloc(GG * 32 * 4);
    int* gcnt = (int*)alloc(GG * 4);

    hipMemsetAsync(w + zero_begin, 0, zero_len, stream);
    hipMemsetAsync(w + ff_begin, 0xFF, ff_len, stream);

    const int B = 256;
    // ---- level-1 graph machinery ----
    k_edge_init<<<EE / B, B, 0, stream>>>(ei, bitmap, rep, cnt1, batch, gstart);
    k_prefix<<<1, 1024, 0, stream>>>(cnt1, rs1, cur1, dinv1, NN);
    k_csr_l1<<<EE / B, B, 0, stream>>>(ei, rep, cur1, csr1);

    // ---- gcn1 (+score1) ----
    k_gemm<<<dim3(NN / 32, 1), 256, 0, stream>>>(x, W1, xW, NN, 128, 32);
    k_prop<5, 1, 1><<<(NN * 8) / B, B, 0, stream>>>(csr1, rs1, nullptr, dinv1, xW, b1,
                                                    x1, p1, score1);

    // ---- pool1: top-4096 of 8192 (invmap=pos2 written in topk) ----
    run_topk(score1, keys, NN, KK1, i2, pos2, stream);
    k_pool_sub<1><<<512 + KK1 / 4, 256, 0, stream>>>(x1, score1, i2, KK1, 32, x2, 512,
                                                     csr1, nullptr, nullptr, rs1, pos2,
                                                     csr2, roff2, deg2, dinv2);

    // ---- gcn2 (+score2) ----
    k_gemm<<<dim3(KK1 / 32, 2), 256, 0, stream>>>(x2, W2, xW, KK1, 32, 64);
    k_prop<6, 1, 0><<<(KK1 * 16) / B, B, 0, stream>>>(csr2, roff2, deg2, dinv2, xW, b2,
                                                      x3, p2, score2);

    // ---- pool2: top-2048 of 4096 ----
    run_topk(score2, keys, KK1, KK2, i4, inv4, stream);
    k_pool_sub<0><<<512 + KK2 / 4, 256, 0, stream>>>(x3, score2, i4, KK2, 64, x4, 512,
                                                     csr2, roff2, deg2, nullptr, inv4,
                                                     csr3, roff3, deg3, dinv3);

    // ---- gcn3 (+score3) ----
    k_gemm<<<dim3(KK2 / 32, 4), 256, 0, stream>>>(x4, W3, xW, KK2, 64, 128);
    k_prop<7, 1, 0><<<(KK2 * 32) / B, B, 0, stream>>>(csr3, roff3, deg3, dinv3, xW, b3,
                                                      x5, p3, score3);

    // ---- pool3: top-1024 of 2048 ----
    run_topk(score3, keys, KK2, KK3, i6, inv6, stream);
    k_pool_sub<0><<<512 + KK3 / 4, 256, 0, stream>>>(x5, score3, i6, KK3, 128, x6, 512,
                                                     csr3, roff3, deg3, nullptr, inv6,
                                                     csr4, roff4, deg4, dinv4);

    // ---- gcn4 ----
    k_gemm<<<dim3(KK3 / 32, 8), 256, 0, stream>>>(x6, W4, xW, KK3, 128, 256);
    k_prop<8, 0, 0><<<(KK3 * 64) / B, B, 0, stream>>>(csr4, roff4, deg4, dinv4, xW, b4,
                                                      x7, nullptr, nullptr);

    // ---- gcn5 (unpool3 fused into X staging) ----
    k_gemm_up<<<dim3(KK2 / 32, 4), 256, 0, stream>>>(x7, inv6, x5, 256, 128,
                                                     W5, xW, KK2, 384, 128);
    k_prop<7, 0, 0><<<(KK2 * 32) / B, B, 0, stream>>>(csr3, roff3, deg3, dinv3, xW, b5,
                                                      x9, nullptr, nullptr);

    // ---- gcn6 (unpool2 fused) ----
    k_gemm_up<<<dim3(KK1 / 32, 2), 256, 0, stream>>>(x9, inv4, x3, 128, 64,
                                                     W6, xW, KK1, 192, 64);
    k_prop<6, 0, 0><<<(KK1 * 16) / B, B, 0, stream>>>(csr2, roff2, deg2, dinv2, xW, b6,
                                                      x11, nullptr, nullptr);

    // ---- gcn7 (unpool1 fused; original weighted adjacency) ----
    k_gemm_up<<<dim3(NN / 32, 1), 256, 0, stream>>>(x11, pos2, x1, 64, 32,
                                                    W7, xW, NN, 96, 32);
    k_prop<5, 0, 1><<<(NN * 8) / B, B, 0, stream>>>(csr1, rs1, nullptr, dinv1, xW, b7,
                                                    x13, nullptr, nullptr);

    // ---- readout ----
    k_seg2<<<GG, 256, 0, stream>>>(x13, gstart, gmaxf, gsum, gcnt);
    k_head<<<1, 1024, 0, stream>>>(gmaxf, gsum, gcnt, Wl1, Wc, bc, out);
}

// Round 10
// 367.928 us; speedup vs baseline: 1.6094x; 1.1188x over previous
//
#include <hip/hip_runtime.h>
#include <math.h>

#define NN 8192
#define EE 262144
#define GG 64
#define CC 10
#define KK1 4096
#define KK2 2048
#define KK3 1024
#define PITCH 128   // ELL row pitch; max in-degree of Poisson(32) is ~60, 128 is safe

typedef unsigned long long ull;

__device__ __forceinline__ float eluf(float x) { return x > 0.f ? x : expm1f(x); }
__device__ __forceinline__ float sigf(float x) { return 1.f / (1.f + expf(-x)); }
__device__ __forceinline__ unsigned f2s(float f) {
    unsigned u = __float_as_uint(f);
    return (u & 0x80000000u) ? ~u : (u | 0x80000000u);
}

// ---- fused init: blocks [0,1024) edge pass (dedup+ELL scatter+gstart);
//      blocks [1024,1280) gemm1 (x @ W1 -> xW), independent work ----
__global__ void k_init(const int* __restrict__ ei, unsigned* __restrict__ bitmap,
                       int* __restrict__ cnt1, int* __restrict__ csr1,
                       const int* __restrict__ batch, int* __restrict__ gstart,
                       const float* __restrict__ X, const float* __restrict__ W,
                       float* __restrict__ Y) {
    __shared__ float Xs[32][33];
    __shared__ float Ws[32][36];
    int tid = threadIdx.x;
    if ((int)blockIdx.x >= 1024) {
        // ---- gemm1: M=NN, K=128, F=32 ----
        int txn = tid & 7, tym = tid >> 3;
        int m0 = ((int)blockIdx.x - 1024) * 32;
        float4 acc = make_float4(0.f, 0.f, 0.f, 0.f);
        for (int k0 = 0; k0 < 128; k0 += 32) {
            int r = tid >> 3, c4 = (tid & 7) << 2;
            *(float4*)&Xs[r][c4] = *(const float4*)&X[(size_t)(m0 + r) * 128 + k0 + c4];
            *(float4*)&Ws[r][c4] = *(const float4*)&W[(size_t)(k0 + r) * 32 + c4];
            __syncthreads();
#pragma unroll 8
            for (int kk = 0; kk < 32; kk++) {
                float4 wv = *(const float4*)&Ws[kk][txn * 4];
                float xv = Xs[tym][kk];
                acc.x += xv * wv.x; acc.y += xv * wv.y;
                acc.z += xv * wv.z; acc.w += xv * wv.w;
            }
            __syncthreads();
        }
        *(float4*)&Y[(size_t)(m0 + tym) * 32 + txn * 4] = acc;
        return;
    }
    int e = blockIdx.x * 256 + tid;
    int s = ei[e], d = ei[EE + e];
    unsigned key = ((unsigned)s << 13) | (unsigned)d;   // N = 8192 = 2^13
    unsigned old = atomicOr(&bitmap[key >> 5], 1u << (key & 31u));
    int dup = (old >> (key & 31u)) & 1;
    int pos = atomicAdd(&cnt1[d], 1);
    csr1[(d << 7) + pos] = dup ? (s | 0x80000000) : s;   // dup flag in sign bit
    if (e < NN) {
        int g = batch[e];
        int prev = (e == 0) ? -1 : batch[e - 1];
        for (int gg = prev + 1; gg <= g; gg++) gstart[gg] = e;
        if (e == NN - 1)
            for (int gg = g + 1; gg <= GG; gg++) gstart[gg] = NN;
    }
}

__global__ void k_dinv1(const int* __restrict__ cnt, float* __restrict__ dinv) {
    int j = blockIdx.x * 256 + threadIdx.x;
    dinv[j] = 1.f / sqrtf((float)(cnt[j] + 1));
}

// ---- merged pool-features + subset-filter kernel ----
// blocks [0,nPool): xout[r,f] = elu(x[idx[r],f]*sig(score[idx[r]]))
// blocks [nPool,..): wave-per-row CSR subset filter
template<int L1>
__global__ void k_pool_sub(const float* __restrict__ x, const float* __restrict__ score,
                           const int* __restrict__ idx, int k, int F,
                           float* __restrict__ xout, int nPool,
                           const int* __restrict__ csrP, const int* __restrict__ roffP,
                           const int* __restrict__ degP,
                           const int* __restrict__ invmap,
                           int* __restrict__ csrO, int* __restrict__ roffO,
                           int* __restrict__ degO, float* __restrict__ dinvO) {
    if ((int)blockIdx.x < nPool) {
        int t = blockIdx.x * 256 + threadIdx.x;
        if (t >= k * F) return;
        int r = t / F, f = t - r * F;
        int j = idx[r];
        xout[t] = eluf(x[(size_t)j * F + f] * sigf(score[j]));
        return;
    }
    int wid = (((int)blockIdx.x - nPool) * 256 + (int)threadIdx.x) >> 6;
    int lane = threadIdx.x & 63;
    if (wid >= k) return;
    int j = idx[wid];
    int j0 = L1 ? (j << 7) : roffP[j];
    int len = degP[j];
    int cnt = 0;
    for (int base = 0; base < len; base += 64) {
        bool sel = false;
        int val = 0;
        if (base + lane < len) {
            int e = csrP[j0 + base + lane];
            if (!L1 || e >= 0) {               // skip duplicate-flagged entries
                int s = L1 ? (e & 0x7fffffff) : e;
                int v = invmap[s];
                if (v >= 0) { sel = true; val = v; }
            }
        }
        ull m = __ballot(sel);
        if (sel) {
            int off = __popcll(m & ((1ull << lane) - 1ull));
            csrO[j0 + cnt + off] = val;
        }
        cnt += __popcll(m);
    }
    if (lane == 0) {
        roffO[wid] = j0;
        degO[wid] = cnt;
        dinvO[wid] = 1.f / sqrtf((float)(cnt + 1));
    }
}

// ---- tiled register-blocked GEMM: Y[M,F] = X[M,K] @ W[K,F], BN=32 ----
__global__ void k_gemm(const float* __restrict__ X, const float* __restrict__ W,
                       float* __restrict__ Y, int M, int K, int F) {
    __shared__ float Xs[32][33];
    __shared__ float Ws[32][36];
    int tid = threadIdx.x;
    int txn = tid & 7, tym = tid >> 3;
    int m0 = blockIdx.x * 32, n0 = blockIdx.y * 32;
    float4 acc = make_float4(0.f, 0.f, 0.f, 0.f);
    for (int k0 = 0; k0 < K; k0 += 32) {
        {
            int r = tid >> 3, c4 = (tid & 7) << 2;
            *(float4*)&Xs[r][c4] = *(const float4*)&X[(size_t)(m0 + r) * K + k0 + c4];
            *(float4*)&Ws[r][c4] = *(const float4*)&W[(size_t)(k0 + r) * F + n0 + c4];
        }
        __syncthreads();
#pragma unroll 8
        for (int kk = 0; kk < 32; kk++) {
            float4 wv = *(const float4*)&Ws[kk][txn * 4];
            float xv = Xs[tym][kk];
            acc.x += xv * wv.x; acc.y += xv * wv.y;
            acc.z += xv * wv.z; acc.w += xv * wv.w;
        }
        __syncthreads();
    }
    *(float4*)&Y[(size_t)(m0 + tym) * F + n0 + txn * 4] = acc;
}

// ---- GEMM with fused unpool+concat+elu on the X operand, BN=32 ----
__global__ void k_gemm_up(const float* __restrict__ xl, const int* __restrict__ inv,
                          const float* __restrict__ xr, int Fl, int Fr,
                          const float* __restrict__ W, float* __restrict__ Y,
                          int M, int K, int F) {
    __shared__ float Xs[32][33];
    __shared__ float Ws[32][36];
    __shared__ int sIdx[32];
    int tid = threadIdx.x;
    int txn = tid & 7, tym = tid >> 3;
    int m0 = blockIdx.x * 32, n0 = blockIdx.y * 32;
    if (tid < 32) sIdx[tid] = inv[m0 + tid];
    float4 acc = make_float4(0.f, 0.f, 0.f, 0.f);
    __syncthreads();
    for (int k0 = 0; k0 < K; k0 += 32) {
        {
            int r = tid >> 3, c4 = (tid & 7) << 2;
            int kk = k0 + c4;
            float4 v;
            if (kk < Fl) {           // Fl,Fr multiples of 32 -> whole float4 on one side
                int rr = sIdx[r];
                v = (rr >= 0) ? *(const float4*)&xl[(size_t)rr * Fl + kk]
                              : make_float4(0.f, 0.f, 0.f, 0.f);
            } else {
                v = *(const float4*)&xr[(size_t)(m0 + r) * Fr + (kk - Fl)];
            }
            v.x = eluf(v.x); v.y = eluf(v.y); v.z = eluf(v.z); v.w = eluf(v.w);
            *(float4*)&Xs[r][c4] = v;
            *(float4*)&Ws[r][c4] = *(const float4*)&W[(size_t)(k0 + r) * F + n0 + c4];
        }
        __syncthreads();
#pragma unroll 8
        for (int kk = 0; kk < 32; kk++) {
            float4 wv = *(const float4*)&Ws[kk][txn * 4];
            float xv = Xs[tym][kk];
            acc.x += xv * wv.x; acc.y += xv * wv.y;
            acc.z += xv * wv.z; acc.w += xv * wv.w;
        }
        __syncthreads();
    }
    *(float4*)&Y[(size_t)(m0 + tym) * F + n0 + txn * 4] = acc;
}

// ---- CSR/ELL gather propagate (float4/thread) + self + bias + elu (+ score) ----
// L1=1: j0 = d<<7, j1 = j0+deg[d], entries dup-flag-masked (multiplicity kept).
// L1=0: j0 = roff[d], j1 = j0+deg[d].
template<int LOGF, int SCORE, int L1>
__global__ void k_prop(const int* __restrict__ csr, const int* __restrict__ roff,
                       const int* __restrict__ deg, const float* __restrict__ dinv,
                       const float* __restrict__ xW, const float* __restrict__ b,
                       float* __restrict__ xout, const float* __restrict__ p,
                       float* __restrict__ score) {
    constexpr int FQ = 1 << (LOGF - 2);          // float4s per row
    const float4* xW4 = (const float4*)xW;
    int t = blockIdx.x * 256 + threadIdx.x;
    int d = t >> (LOGF - 2), q = t & (FQ - 1);
    int j0 = L1 ? (d << 7) : roff[d];
    int j1 = j0 + deg[d];
    float dd = dinv[d];
    float4 v0 = xW4[t];
    float4 sum = make_float4(dd * v0.x, dd * v0.y, dd * v0.z, dd * v0.w);
    for (int j = j0; j < j1; j++) {
        int e = csr[j];
        int s = L1 ? (e & 0x7fffffff) : e;
        float ds = dinv[s];
        float4 xv = xW4[(s << (LOGF - 2)) + q];
        sum.x += ds * xv.x; sum.y += ds * xv.y;
        sum.z += ds * xv.z; sum.w += ds * xv.w;
    }
    float4 bv = *(const float4*)&b[q << 2];
    float4 o;
    o.x = eluf(dd * sum.x + bv.x);
    o.y = eluf(dd * sum.y + bv.y);
    o.z = eluf(dd * sum.z + bv.z);
    o.w = eluf(dd * sum.w + bv.w);
    ((float4*)xout)[t] = o;
    if (SCORE) {
        float4 pv = *(const float4*)&p[q << 2];
        float sc = o.x * pv.x + o.y * pv.y + o.z * pv.z + o.w * pv.w;
        float nr = pv.x * pv.x + pv.y * pv.y + pv.z * pv.z + pv.w * pv.w;
#pragma unroll
        for (int m = FQ >> 1; m >= 1; m >>= 1) {
            sc += __shfl_xor(sc, m, 64);
            nr += __shfl_xor(nr, m, 64);
        }
        if (q == 0) score[d] = sc / sqrtf(nr);
    }
}

// ==== hybrid register/LDS bitonic top-k (network identical to verified rounds) ====
__device__ __forceinline__ ull cex_shfl(ull v, int st, bool takeMax) {
    ull pv = __shfl_xor(v, st, 64);
    return takeMax ? (v > pv ? v : pv) : (v < pv ? v : pv);
}
__device__ __forceinline__ void cexr(ull& a, ull& b, bool desc) {
    if (desc ? (a < b) : (a > b)) { ull x = a; a = b; b = x; }
}

// full sort of a 2048-key window (stages 2..2048)
__global__ void k_wsort(const float* __restrict__ score, ull* __restrict__ keys,
                        int last, int k, int* __restrict__ out_idx,
                        int* __restrict__ invmap) {
    __shared__ ull sk[2048];
    int tid = threadIdx.x;
    int base = blockIdx.x << 11;
    int giA = base + tid, giB = giA + 1024;
    ull a = ((ull)f2s(score[giA]) << 32) | (unsigned)(~giA);
    ull b = ((ull)f2s(score[giB]) << 32) | (unsigned)(~giB);
    for (int sz = 2; sz <= 2048; sz <<= 1) {
        int st = sz >> 1;
        if (st >= 64) {
            sk[tid] = a; sk[tid + 1024] = b;
            __syncthreads();
            for (; st >= 64; st >>= 1) {
                int i = ((tid & ~(st - 1)) << 1) | (tid & (st - 1));
                int j = i | st;
                ull u = sk[i], v = sk[j];
                bool desc = (((base + i) & sz) == 0);
                if (desc ? (u < v) : (u > v)) { sk[i] = v; sk[j] = u; }
                __syncthreads();
            }
            a = sk[tid]; b = sk[tid + 1024];
        }
        for (; st >= 1; st >>= 1) {
            bool low = (tid & st) == 0;
            bool descA = ((giA & sz) == 0);
            bool descB = ((giB & sz) == 0);
            a = cex_shfl(a, st, descA == low);
            b = cex_shfl(b, st, descB == low);
        }
    }
    if (last) {
        if (giA < k) {
            int j = (int)(~(unsigned)(a & 0xFFFFFFFFu));
            out_idx[giA] = j; invmap[j] = giA;
        }
        if (giB < k) {
            int j = (int)(~(unsigned)(b & 0xFFFFFFFFu));
            out_idx[giB] = j; invmap[j] = giB;
        }
    } else {
        keys[giA] = a; keys[giB] = b;
    }
}

// stage sz=4096 complete (strides 2048..1) per 4096-key block; writes all back
__global__ void k_stage4k_m(ull* __restrict__ keys) {
    __shared__ ull sk[4096];
    int tid = threadIdx.x;
    int base = blockIdx.x << 12;
    bool desc = ((base & 4096) == 0);
    ull k0 = keys[base + tid], k1 = keys[base + tid + 1024];
    ull k2 = keys[base + tid + 2048], k3 = keys[base + tid + 3072];
    cexr(k0, k2, desc); cexr(k1, k3, desc);          // stride 2048
    sk[tid] = k0; sk[tid + 1024] = k1; sk[tid + 2048] = k2; sk[tid + 3072] = k3;
    __syncthreads();
    for (int st = 1024; st >= 64; st >>= 1) {
        for (int pp = tid; pp < 2048; pp += 1024) {
            int i = ((pp & ~(st - 1)) << 1) | (pp & (st - 1));
            int j = i | st;
            ull u = sk[i], v = sk[j];
            if (desc ? (u < v) : (u > v)) { sk[i] = v; sk[j] = u; }
        }
        __syncthreads();
    }
    k0 = sk[tid]; k1 = sk[tid + 1024]; k2 = sk[tid + 2048]; k3 = sk[tid + 3072];
    for (int st = 32; st >= 1; st >>= 1) {
        bool low = (tid & st) == 0;
        k0 = cex_shfl(k0, st, desc == low);
        k1 = cex_shfl(k1, st, desc == low);
        k2 = cex_shfl(k2, st, desc == low);
        k3 = cex_shfl(k3, st, desc == low);
    }
    keys[base + tid] = k0; keys[base + tid + 1024] = k1;
    keys[base + tid + 2048] = k2; keys[base + tid + 3072] = k3;
}

// n=8192 final stage sz=8192 (desc everywhere); ranks [0,4096) = k; one block
__global__ void k_stage8k_f(const ull* __restrict__ keys, int* __restrict__ out_idx,
                            int* __restrict__ invmap) {
    __shared__ ull sk[4096];
    int tid = threadIdx.x;
    ull a0 = keys[tid],        a1 = keys[tid + 1024];
    ull a2 = keys[tid + 2048], a3 = keys[tid + 3072];
    ull b0 = keys[tid + 4096], b1 = keys[tid + 5120];
    ull b2 = keys[tid + 6144], b3 = keys[tid + 7168];
    cexr(a0, b0, true); cexr(a1, b1, true);          // stride 4096 (keep low half)
    cexr(a2, b2, true); cexr(a3, b3, true);
    cexr(a0, a2, true); cexr(a1, a3, true);          // stride 2048 within [0,4096)
    sk[tid] = a0; sk[tid + 1024] = a1; sk[tid + 2048] = a2; sk[tid + 3072] = a3;
    __syncthreads();
    for (int st = 1024; st >= 64; st >>= 1) {
        for (int pp = tid; pp < 2048; pp += 1024) {
            int i = ((pp & ~(st - 1)) << 1) | (pp & (st - 1));
            int j = i | st;
            ull u = sk[i], v = sk[j];
            if (u < v) { sk[i] = v; sk[j] = u; }     // desc
        }
        __syncthreads();
    }
    a0 = sk[tid]; a1 = sk[tid + 1024]; a2 = sk[tid + 2048]; a3 = sk[tid + 3072];
    for (int st = 32; st >= 1; st >>= 1) {
        bool low = (tid & st) == 0;
        a0 = cex_shfl(a0, st, low);
        a1 = cex_shfl(a1, st, low);
        a2 = cex_shfl(a2, st, low);
        a3 = cex_shfl(a3, st, low);
    }
    int p, j;
    p = tid;        j = (int)(~(unsigned)(a0 & 0xFFFFFFFFu)); out_idx[p] = j; invmap[j] = p;
    p = tid + 1024; j = (int)(~(unsigned)(a1 & 0xFFFFFFFFu)); out_idx[p] = j; invmap[j] = p;
    p = tid + 2048; j = (int)(~(unsigned)(a2 & 0xFFFFFFFFu)); out_idx[p] = j; invmap[j] = p;
    p = tid + 3072; j = (int)(~(unsigned)(a3 & 0xFFFFFFFFu)); out_idx[p] = j; invmap[j] = p;
}

// n=4096 final stage sz=4096; ranks [0,2048) = k; one block
__global__ void k_stage4k_f(const ull* __restrict__ keys, int* __restrict__ out_idx,
                            int* __restrict__ invmap) {
    __shared__ ull sk[2048];
    int tid = threadIdx.x;
    ull a0 = keys[tid],        a1 = keys[tid + 1024];
    ull a2 = keys[tid + 2048], a3 = keys[tid + 3072];
    cexr(a0, a2, true); cexr(a1, a3, true);          // stride 2048 (keep low half)
    sk[tid] = a0; sk[tid + 1024] = a1;
    __syncthreads();
    for (int st = 1024; st >= 64; st >>= 1) {
        int i = ((tid & ~(st - 1)) << 1) | (tid & (st - 1));
        int j = i | st;
        ull u = sk[i], v = sk[j];
        if (u < v) { sk[i] = v; sk[j] = u; }         // desc
        __syncthreads();
    }
    a0 = sk[tid]; a1 = sk[tid + 1024];
    for (int st = 32; st >= 1; st >>= 1) {
        bool low = (tid & st) == 0;
        a0 = cex_shfl(a0, st, low);
        a1 = cex_shfl(a1, st, low);
    }
    int p, j;
    p = tid;        j = (int)(~(unsigned)(a0 & 0xFFFFFFFFu)); out_idx[p] = j; invmap[j] = p;
    p = tid + 1024; j = (int)(~(unsigned)(a1 & 0xFFFFFFFFu)); out_idx[p] = j; invmap[j] = p;
}

// ---- atomic-free segment max/sum/count: one block per graph ----
__global__ void k_seg2(const float* __restrict__ x13, const int* __restrict__ gstart,
                       float* __restrict__ gmaxf, float* __restrict__ gsum,
                       int* __restrict__ gcnt) {
    __shared__ float sm[8][32], ss[8][32];
    int g = blockIdx.x;
    int j0 = gstart[g], j1 = gstart[g + 1];
    int t = threadIdx.x;
    int f = t & 31, r = t >> 5;
    float m = -INFINITY, s = 0.f;
    for (int j = j0 + r; j < j1; j += 8) {
        float v = x13[(j << 5) + f];
        m = fmaxf(m, v);
        s += v;
    }
    sm[r][f] = m; ss[r][f] = s;
    __syncthreads();
    if (t < 32) {
        float mm = sm[0][t], sss = ss[0][t];
        for (int i = 1; i < 8; i++) { mm = fmaxf(mm, sm[i][t]); sss += ss[i][t]; }
        gmaxf[(g << 5) + t] = mm;
        gsum[(g << 5) + t] = sss;
        if (t == 0) gcnt[g] = j1 - j0;
    }
}

// ---- head ----
__global__ void k_head(const float* __restrict__ gmaxf, const float* __restrict__ gsum,
                       const int* __restrict__ gcnt, const float* __restrict__ Wl1,
                       const float* __restrict__ Wc, const float* __restrict__ bc,
                       float* __restrict__ out) {
    __shared__ float h0[GG * 64];
    __shared__ float h1[GG * 64];
    __shared__ float lg[GG * CC];
    int tid = threadIdx.x;
    for (int t = tid; t < GG * 64; t += blockDim.x) {
        int g = t >> 6, c = t & 63;
        float v;
        if (c < 32) v = gmaxf[(g << 5) + c];
        else v = gsum[(g << 5) + (c - 32)] / (float)gcnt[g];
        h0[t] = eluf(v);
    }
    __syncthreads();
    for (int t = tid; t < GG * 64; t += blockDim.x) {
        int g = t >> 6, j = t & 63;
        float s = 0.f;
        for (int k = 0; k < 64; k++) s += h0[(g << 6) + k] * Wl1[k * 64 + j];
        h1[t] = eluf(s);
    }
    __syncthreads();
    for (int t = tid; t < GG * CC; t += blockDim.x) {
        int g = t / CC, c = t - g * CC;
        float s = bc[c];
        for (int k = 0; k < 64; k++) s += h1[(g << 6) + k] * Wc[k * CC + c];
        lg[t] = s;
    }
    __syncthreads();
    if (tid < GG) {
        int g = tid;
        float m = -1e30f;
        for (int c = 0; c < CC; c++) m = fmaxf(m, lg[g * CC + c]);
        float se = 0.f;
        for (int c = 0; c < CC; c++) se += expf(lg[g * CC + c] - m);
        float lse = m + logf(se);
        for (int c = 0; c < CC; c++) out[g * CC + c] = lg[g * CC + c] - lse;
    }
}

static void run_topk(const float* score, ull* keys, int n, int k, int* out_idx,
                     int* invmap, hipStream_t stream) {
    if (n == 2048) {
        k_wsort<<<1, 1024, 0, stream>>>(score, keys, 1, k, out_idx, invmap);
    } else if (n == 4096) {
        k_wsort<<<2, 1024, 0, stream>>>(score, keys, 0, k, out_idx, invmap);
        k_stage4k_f<<<1, 1024, 0, stream>>>(keys, out_idx, invmap);
    } else {                                   // 8192
        k_wsort<<<4, 1024, 0, stream>>>(score, keys, 0, k, out_idx, invmap);
        k_stage4k_m<<<2, 1024, 0, stream>>>(keys);
        k_stage8k_f<<<1, 1024, 0, stream>>>(keys, out_idx, invmap);
    }
}

extern "C" void kernel_launch(void* const* d_in, const int* in_sizes, int n_in,
                              void* d_out, int out_size, void* d_ws, size_t ws_size,
                              hipStream_t stream) {
    const float* x = (const float*)d_in[0];
    const int* ei = (const int*)d_in[1];
    const int* batch = (const int*)d_in[2];
    const float* W1 = (const float*)d_in[3];  const float* b1 = (const float*)d_in[4];
    const float* W2 = (const float*)d_in[5];  const float* b2 = (const float*)d_in[6];
    const float* W3 = (const float*)d_in[7];  const float* b3 = (const float*)d_in[8];
    const float* W4 = (const float*)d_in[9];  const float* b4 = (const float*)d_in[10];
    const float* W5 = (const float*)d_in[11]; const float* b5 = (const float*)d_in[12];
    const float* W6 = (const float*)d_in[13]; const float* b6 = (const float*)d_in[14];
    const float* W7 = (const float*)d_in[15]; const float* b7 = (const float*)d_in[16];
    const float* p1 = (const float*)d_in[17];
    const float* p2 = (const float*)d_in[18];
    const float* p3 = (const float*)d_in[19];
    const float* Wl1 = (const float*)d_in[20];
    const float* Wc = (const float*)d_in[21];
    const float* bc = (const float*)d_in[22];
    float* out = (float*)d_out;
    (void)in_sizes; (void)n_in; (void)out_size; (void)ws_size;

    char* w = (char*)d_ws;
    size_t off = 0;
    auto alloc = [&](size_t bytes) -> char* {
        char* p = w + off;
        off = (off + bytes + 255) & ~(size_t)255;
        return p;
    };

    // ---- zero-initialized span ----
    size_t zero_begin = off;
    unsigned* bitmap = (unsigned*)alloc((size_t)NN * NN / 8);   // 8 MB
    int* cnt1 = (int*)alloc(NN * 4);
    size_t zero_len = off - zero_begin;

    // ---- 0xFF-initialized span (inverse maps = -1) ----
    size_t ff_begin = off;
    int* pos2 = (int*)alloc(NN * 4);     // orig -> level2
    int* inv4 = (int*)alloc(KK1 * 4);    // level2 -> level3
    int* inv6 = (int*)alloc(KK2 * 4);    // level3 -> level4
    size_t ff_len = off - ff_begin;

    // ---- uninitialized scratch ----
    float* dinv1 = (float*)alloc(NN * 4);
    float* dinv2 = (float*)alloc(KK1 * 4);
    float* dinv3 = (float*)alloc(KK2 * 4);
    float* dinv4 = (float*)alloc(KK3 * 4);
    int* roff2 = (int*)alloc(KK1 * 4); int* deg2 = (int*)alloc(KK1 * 4);
    int* roff3 = (int*)alloc(KK2 * 4); int* deg3 = (int*)alloc(KK2 * 4);
    int* roff4 = (int*)alloc(KK3 * 4); int* deg4 = (int*)alloc(KK3 * 4);
    int* csr1 = (int*)alloc((size_t)NN * PITCH * 4);   // 4 MB ELL each
    int* csr2 = (int*)alloc((size_t)NN * PITCH * 4);
    int* csr3 = (int*)alloc((size_t)NN * PITCH * 4);
    int* csr4 = (int*)alloc((size_t)NN * PITCH * 4);
    float* xW = (float*)alloc((size_t)262144 * 4);
    float* x1 = (float*)alloc((size_t)NN * 32 * 4);
    float* x2 = (float*)alloc((size_t)KK1 * 32 * 4);
    float* x3 = (float*)alloc((size_t)KK1 * 64 * 4);
    float* x4 = (float*)alloc((size_t)KK2 * 64 * 4);
    float* x5 = (float*)alloc((size_t)KK2 * 128 * 4);
    float* x6 = (float*)alloc((size_t)KK3 * 128 * 4);
    float* x7 = (float*)alloc((size_t)KK3 * 256 * 4);
    float* x9 = (float*)alloc((size_t)KK2 * 128 * 4);
    float* x11 = (float*)alloc((size_t)KK1 * 64 * 4);
    float* x13 = (float*)alloc((size_t)NN * 32 * 4);
    float* score1 = (float*)alloc(NN * 4);
    float* score2 = (float*)alloc(KK1 * 4);
    float* score3 = (float*)alloc(KK2 * 4);
    int* i2 = (int*)alloc(KK1 * 4);
    int* i4 = (int*)alloc(KK2 * 4);
    int* i6 = (int*)alloc(KK3 * 4);
    ull* keys = (ull*)alloc((size_t)NN * 8);
    int* gstart = (int*)alloc((GG + 1) * 4);
    float* gmaxf = (float*)alloc(GG * 32 * 4);
    float* gsum = (float*)alloc(GG * 32 * 4);
    int* gcnt = (int*)alloc(GG * 4);

    hipMemsetAsync(w + zero_begin, 0, zero_len, stream);
    hipMemsetAsync(w + ff_begin, 0xFF, ff_len, stream);

    const int B = 256;
    // ---- fused: level-1 edge pass (dedup + ELL scatter + gbounds) || gemm1 ----
    k_init<<<1280, B, 0, stream>>>(ei, bitmap, cnt1, csr1, batch, gstart, x, W1, xW);
    k_dinv1<<<32, B, 0, stream>>>(cnt1, dinv1);

    // ---- gcn1 propagate (+score1) ----
    k_prop<5, 1, 1><<<(NN * 8) / B, B, 0, stream>>>(csr1, nullptr, cnt1, dinv1, xW, b1,
                                                    x1, p1, score1);

    // ---- pool1: top-4096 of 8192 (invmap=pos2 written in topk) ----
    run_topk(score1, keys, NN, KK1, i2, pos2, stream);
    k_pool_sub<1><<<512 + KK1 / 4, B, 0, stream>>>(x1, score1, i2, KK1, 32, x2, 512,
                                                   csr1, nullptr, cnt1, pos2,
                                                   csr2, roff2, deg2, dinv2);

    // ---- gcn2 (+score2) ----
    k_gemm<<<dim3(KK1 / 32, 2), B, 0, stream>>>(x2, W2, xW, KK1, 32, 64);
    k_prop<6, 1, 0><<<(KK1 * 16) / B, B, 0, stream>>>(csr2, roff2, deg2, dinv2, xW, b2,
                                                      x3, p2, score2);

    // ---- pool2: top-2048 of 4096 ----
    run_topk(score2, keys, KK1, KK2, i4, inv4, stream);
    k_pool_sub<0><<<512 + KK2 / 4, B, 0, stream>>>(x3, score2, i4, KK2, 64, x4, 512,
                                                   csr2, roff2, deg2, inv4,
                                                   csr3, roff3, deg3, dinv3);

    // ---- gcn3 (+score3) ----
    k_gemm<<<dim3(KK2 / 32, 4), B, 0, stream>>>(x4, W3, xW, KK2, 64, 128);
    k_prop<7, 1, 0><<<(KK2 * 32) / B, B, 0, stream>>>(csr3, roff3, deg3, dinv3, xW, b3,
                                                      x5, p3, score3);

    // ---- pool3: top-1024 of 2048 ----
    run_topk(score3, keys, KK2, KK3, i6, inv6, stream);
    k_pool_sub<0><<<512 + KK3 / 4, B, 0, stream>>>(x5, score3, i6, KK3, 128, x6, 512,
                                                   csr3, roff3, deg3, inv6,
                                                   csr4, roff4, deg4, dinv4);

    // ---- gcn4 ----
    k_gemm<<<dim3(KK3 / 32, 8), B, 0, stream>>>(x6, W4, xW, KK3, 128, 256);
    k_prop<8, 0, 0><<<(KK3 * 64) / B, B, 0, stream>>>(csr4, roff4, deg4, dinv4, xW, b4,
                                                      x7, nullptr, nullptr);

    // ---- gcn5 (unpool3 fused into X staging) ----
    k_gemm_up<<<dim3(KK2 / 32, 4), B, 0, stream>>>(x7, inv6, x5, 256, 128,
                                                   W5, xW, KK2, 384, 128);
    k_prop<7, 0, 0><<<(KK2 * 32) / B, B, 0, stream>>>(csr3, roff3, deg3, dinv3, xW, b5,
                                                      x9, nullptr, nullptr);

    // ---- gcn6 (unpool2 fused) ----
    k_gemm_up<<<dim3(KK1 / 32, 2), B, 0, stream>>>(x9, inv4, x3, 128, 64,
                                                   W6, xW, KK1, 192, 64);
    k_prop<6, 0, 0><<<(KK1 * 16) / B, B, 0, stream>>>(csr2, roff2, deg2, dinv2, xW, b6,
                                                      x11, nullptr, nullptr);

    // ---- gcn7 (unpool1 fused; original weighted adjacency) ----
    k_gemm_up<<<dim3(NN / 32, 1), B, 0, stream>>>(x11, pos2, x1, 64, 32,
                                                  W7, xW, NN, 96, 32);
    k_prop<5, 0, 1><<<(NN * 8) / B, B, 0, stream>>>(csr1, nullptr, cnt1, dinv1, xW, b7,
                                                    x13, nullptr, nullptr);

    // ---- readout ----
    k_seg2<<<GG, B, 0, stream>>>(x13, gstart, gmaxf, gsum, gcnt);
    k_head<<<1, 1024, 0, stream>>>(gmaxf, gsum, gcnt, Wl1, Wc, bc, out);
}

// Round 11
// 333.373 us; speedup vs baseline: 1.7762x; 1.1037x over previous
//
#include <hip/hip_runtime.h>
#include <math.h>

#define NN 8192
#define EE 262144
#define GG 64
#define CC 10
#define KK1 4096
#define KK2 2048
#define KK3 1024
#define PITCH 128   // ELL row pitch; max in-degree of Poisson(32) is ~60, 128 is safe

typedef unsigned long long ull;

__device__ __forceinline__ float eluf(float x) { return x > 0.f ? x : expm1f(x); }
__device__ __forceinline__ float sigf(float x) { return 1.f / (1.f + expf(-x)); }
__device__ __forceinline__ unsigned f2s(float f) {
    unsigned u = __float_as_uint(f);
    return (u & 0x80000000u) ? ~u : (u | 0x80000000u);
}

// ---- fused init: blocks [0,1024) edge pass (dedup+ELL scatter+gstart);
//      blocks [1024,1280) gemm1 (x @ W1 -> xW), independent work ----
__global__ void k_init(const int* __restrict__ ei, unsigned* __restrict__ bitmap,
                       int* __restrict__ cnt1, int* __restrict__ csr1,
                       const int* __restrict__ batch, int* __restrict__ gstart,
                       const float* __restrict__ X, const float* __restrict__ W,
                       float* __restrict__ Y) {
    __shared__ float Xs[32][33];
    __shared__ float Ws[32][36];
    int tid = threadIdx.x;
    if ((int)blockIdx.x >= 1024) {
        // ---- gemm1: M=NN, K=128, F=32 ----
        int txn = tid & 7, tym = tid >> 3;
        int m0 = ((int)blockIdx.x - 1024) * 32;
        float4 acc = make_float4(0.f, 0.f, 0.f, 0.f);
        for (int k0 = 0; k0 < 128; k0 += 32) {
            int r = tid >> 3, c4 = (tid & 7) << 2;
            *(float4*)&Xs[r][c4] = *(const float4*)&X[(size_t)(m0 + r) * 128 + k0 + c4];
            *(float4*)&Ws[r][c4] = *(const float4*)&W[(size_t)(k0 + r) * 32 + c4];
            __syncthreads();
#pragma unroll 8
            for (int kk = 0; kk < 32; kk++) {
                float4 wv = *(const float4*)&Ws[kk][txn * 4];
                float xv = Xs[tym][kk];
                acc.x += xv * wv.x; acc.y += xv * wv.y;
                acc.z += xv * wv.z; acc.w += xv * wv.w;
            }
            __syncthreads();
        }
        *(float4*)&Y[(size_t)(m0 + tym) * 32 + txn * 4] = acc;
        return;
    }
    int e = blockIdx.x * 256 + tid;
    int s = ei[e], d = ei[EE + e];
    unsigned key = ((unsigned)s << 13) | (unsigned)d;   // N = 8192 = 2^13
    unsigned old = atomicOr(&bitmap[key >> 5], 1u << (key & 31u));
    int dup = (old >> (key & 31u)) & 1;
    int pos = atomicAdd(&cnt1[d], 1);
    csr1[(d << 7) + pos] = dup ? (s | 0x80000000) : s;   // dup flag in sign bit
    if (e < NN) {
        int g = batch[e];
        int prev = (e == 0) ? -1 : batch[e - 1];
        for (int gg = prev + 1; gg <= g; gg++) gstart[gg] = e;
        if (e == NN - 1)
            for (int gg = g + 1; gg <= GG; gg++) gstart[gg] = NN;
    }
}

// ---- merged pool-features + subset-filter kernel ----
// blocks [0,nPool): xout[r,f] = elu(x[idx[r],f]*sig(score[idx[r]]))
// blocks [nPool,..): wave-per-row CSR subset filter; invmap is rank+1 (0 = invalid)
template<int L1>
__global__ void k_pool_sub(const float* __restrict__ x, const float* __restrict__ score,
                           const int* __restrict__ idx, int k, int F,
                           float* __restrict__ xout, int nPool,
                           const int* __restrict__ csrP, const int* __restrict__ roffP,
                           const int* __restrict__ degP,
                           const int* __restrict__ invmap,
                           int* __restrict__ csrO, int* __restrict__ roffO,
                           int* __restrict__ degO, float* __restrict__ dinvO) {
    if ((int)blockIdx.x < nPool) {
        int t = blockIdx.x * 256 + threadIdx.x;
        if (t >= k * F) return;
        int r = t / F, f = t - r * F;
        int j = idx[r];
        xout[t] = eluf(x[(size_t)j * F + f] * sigf(score[j]));
        return;
    }
    int wid = (((int)blockIdx.x - nPool) * 256 + (int)threadIdx.x) >> 6;
    int lane = threadIdx.x & 63;
    if (wid >= k) return;
    int j = idx[wid];
    int j0 = L1 ? (j << 7) : roffP[j];
    int len = degP[j];
    int cnt = 0;
    for (int base = 0; base < len; base += 64) {
        bool sel = false;
        int val = 0;
        if (base + lane < len) {
            int e = csrP[j0 + base + lane];
            if (!L1 || e >= 0) {               // skip duplicate-flagged entries
                int s = L1 ? (e & 0x7fffffff) : e;
                int v = invmap[s];
                if (v > 0) { sel = true; val = v - 1; }
            }
        }
        ull m = __ballot(sel);
        if (sel) {
            int off = __popcll(m & ((1ull << lane) - 1ull));
            csrO[j0 + cnt + off] = val;
        }
        cnt += __popcll(m);
    }
    if (lane == 0) {
        roffO[wid] = j0;
        degO[wid] = cnt;
        dinvO[wid] = 1.f / sqrtf((float)(cnt + 1));
    }
}

// ---- tiled register-blocked GEMM: Y[M,F] = X[M,K] @ W[K,F], BN=32 ----
__global__ void k_gemm(const float* __restrict__ X, const float* __restrict__ W,
                       float* __restrict__ Y, int M, int K, int F) {
    __shared__ float Xs[32][33];
    __shared__ float Ws[32][36];
    int tid = threadIdx.x;
    int txn = tid & 7, tym = tid >> 3;
    int m0 = blockIdx.x * 32, n0 = blockIdx.y * 32;
    float4 acc = make_float4(0.f, 0.f, 0.f, 0.f);
    for (int k0 = 0; k0 < K; k0 += 32) {
        {
            int r = tid >> 3, c4 = (tid & 7) << 2;
            *(float4*)&Xs[r][c4] = *(const float4*)&X[(size_t)(m0 + r) * K + k0 + c4];
            *(float4*)&Ws[r][c4] = *(const float4*)&W[(size_t)(k0 + r) * F + n0 + c4];
        }
        __syncthreads();
#pragma unroll 8
        for (int kk = 0; kk < 32; kk++) {
            float4 wv = *(const float4*)&Ws[kk][txn * 4];
            float xv = Xs[tym][kk];
            acc.x += xv * wv.x; acc.y += xv * wv.y;
            acc.z += xv * wv.z; acc.w += xv * wv.w;
        }
        __syncthreads();
    }
    *(float4*)&Y[(size_t)(m0 + tym) * F + n0 + txn * 4] = acc;
}

// ---- GEMM with fused unpool+concat+elu on the X operand, BN=32 ----
// inv is rank+1 encoded (0 = not selected)
__global__ void k_gemm_up(const float* __restrict__ xl, const int* __restrict__ inv,
                          const float* __restrict__ xr, int Fl, int Fr,
                          const float* __restrict__ W, float* __restrict__ Y,
                          int M, int K, int F) {
    __shared__ float Xs[32][33];
    __shared__ float Ws[32][36];
    __shared__ int sIdx[32];
    int tid = threadIdx.x;
    int txn = tid & 7, tym = tid >> 3;
    int m0 = blockIdx.x * 32, n0 = blockIdx.y * 32;
    if (tid < 32) sIdx[tid] = inv[m0 + tid];
    float4 acc = make_float4(0.f, 0.f, 0.f, 0.f);
    __syncthreads();
    for (int k0 = 0; k0 < K; k0 += 32) {
        {
            int r = tid >> 3, c4 = (tid & 7) << 2;
            int kk = k0 + c4;
            float4 v;
            if (kk < Fl) {           // Fl,Fr multiples of 32 -> whole float4 on one side
                int rr = sIdx[r];
                v = (rr > 0) ? *(const float4*)&xl[(size_t)(rr - 1) * Fl + kk]
                             : make_float4(0.f, 0.f, 0.f, 0.f);
            } else {
                v = *(const float4*)&xr[(size_t)(m0 + r) * Fr + (kk - Fl)];
            }
            v.x = eluf(v.x); v.y = eluf(v.y); v.z = eluf(v.z); v.w = eluf(v.w);
            *(float4*)&Xs[r][c4] = v;
            *(float4*)&Ws[r][c4] = *(const float4*)&W[(size_t)(k0 + r) * F + n0 + c4];
        }
        __syncthreads();
#pragma unroll 8
        for (int kk = 0; kk < 32; kk++) {
            float4 wv = *(const float4*)&Ws[kk][txn * 4];
            float xv = Xs[tym][kk];
            acc.x += xv * wv.x; acc.y += xv * wv.y;
            acc.z += xv * wv.z; acc.w += xv * wv.w;
        }
        __syncthreads();
    }
    *(float4*)&Y[(size_t)(m0 + tym) * F + n0 + txn * 4] = acc;
}

// ---- split-row CSR/ELL gather propagate + self + bias + elu (+ score) ----
// S lanes share one (d,q): lane h handles neighbors j0+h, j0+h+S, ...; combined
// via shfl_xor(1..S/2). Layout: t = d*(FQ*S) + q*S + h. Grid exactly n*FQ*S/256.
// L1=1: j0 = d<<7, deg = cnt[d], dup flag in sign bit, dinv computed inline
//       (1/sqrtf(cnt+1), bit-identical to the precomputed version).
template<int LOGF, int SCORE, int L1, int LS>
__global__ void k_prop(const int* __restrict__ csr, const int* __restrict__ roff,
                       const int* __restrict__ deg, const float* __restrict__ dinv,
                       const float* __restrict__ xW, const float* __restrict__ b,
                       float* __restrict__ xout, const float* __restrict__ p,
                       float* __restrict__ score) {
    constexpr int FQ = 1 << (LOGF - 2);          // float4s per row
    constexpr int S = 1 << LS;                   // split factor
    constexpr int RL = FQ * S;                   // lanes per row
    const float4* xW4 = (const float4*)xW;
    int t = blockIdx.x * 256 + threadIdx.x;
    int d = t >> (LOGF - 2 + LS);
    int rem = t & (RL - 1);
    int q = rem >> LS, h = rem & (S - 1);
    int j0 = L1 ? (d << 7) : roff[d];
    int dg = deg[d];
    int j1 = j0 + dg;
    float dd = L1 ? (1.f / sqrtf((float)(dg + 1))) : dinv[d];
    int idx = (d << (LOGF - 2)) + q;
    float4 sum;
    if (h == 0) {
        float4 v0 = xW4[idx];
        sum = make_float4(dd * v0.x, dd * v0.y, dd * v0.z, dd * v0.w);
    } else {
        sum = make_float4(0.f, 0.f, 0.f, 0.f);
    }
    for (int j = j0 + h; j < j1; j += S) {
        int e = csr[j];
        int s = L1 ? (e & 0x7fffffff) : e;
        float ds = L1 ? (1.f / sqrtf((float)(deg[s] + 1))) : dinv[s];
        float4 xv = xW4[(s << (LOGF - 2)) + q];
        sum.x += ds * xv.x; sum.y += ds * xv.y;
        sum.z += ds * xv.z; sum.w += ds * xv.w;
    }
#pragma unroll
    for (int m = 1; m < S; m <<= 1) {
        sum.x += __shfl_xor(sum.x, m, 64);
        sum.y += __shfl_xor(sum.y, m, 64);
        sum.z += __shfl_xor(sum.z, m, 64);
        sum.w += __shfl_xor(sum.w, m, 64);
    }
    float4 bv = *(const float4*)&b[q << 2];
    float4 o;
    o.x = eluf(dd * sum.x + bv.x);
    o.y = eluf(dd * sum.y + bv.y);
    o.z = eluf(dd * sum.z + bv.z);
    o.w = eluf(dd * sum.w + bv.w);
    if (h == 0) ((float4*)xout)[idx] = o;
    if (SCORE) {
        // RL <= 64 guaranteed for SCORE instantiations
        float4 pv = *(const float4*)&p[q << 2];
        float sc = 0.f, nr = 0.f;
        if (h == 0) {
            sc = o.x * pv.x + o.y * pv.y + o.z * pv.z + o.w * pv.w;
            nr = pv.x * pv.x + pv.y * pv.y + pv.z * pv.z + pv.w * pv.w;
        }
#pragma unroll
        for (int m = RL >> 1; m >= 1; m >>= 1) {
            sc += __shfl_xor(sc, m, 64);
            nr += __shfl_xor(nr, m, 64);
        }
        if (rem == 0) score[d] = sc / sqrtf(nr);
    }
}

// ==== hybrid register/LDS bitonic top-k (network identical to verified rounds) ====
// invmap written as rank+1 (0 = invalid)
__device__ __forceinline__ ull cex_shfl(ull v, int st, bool takeMax) {
    ull pv = __shfl_xor(v, st, 64);
    return takeMax ? (v > pv ? v : pv) : (v < pv ? v : pv);
}
__device__ __forceinline__ void cexr(ull& a, ull& b, bool desc) {
    if (desc ? (a < b) : (a > b)) { ull x = a; a = b; b = x; }
}

// full sort of a 2048-key window (stages 2..2048)
__global__ void k_wsort(const float* __restrict__ score, ull* __restrict__ keys,
                        int last, int k, int* __restrict__ out_idx,
                        int* __restrict__ invmap) {
    __shared__ ull sk[2048];
    int tid = threadIdx.x;
    int base = blockIdx.x << 11;
    int giA = base + tid, giB = giA + 1024;
    ull a = ((ull)f2s(score[giA]) << 32) | (unsigned)(~giA);
    ull b = ((ull)f2s(score[giB]) << 32) | (unsigned)(~giB);
    for (int sz = 2; sz <= 2048; sz <<= 1) {
        int st = sz >> 1;
        if (st >= 64) {
            sk[tid] = a; sk[tid + 1024] = b;
            __syncthreads();
            for (; st >= 64; st >>= 1) {
                int i = ((tid & ~(st - 1)) << 1) | (tid & (st - 1));
                int j = i | st;
                ull u = sk[i], v = sk[j];
                bool desc = (((base + i) & sz) == 0);
                if (desc ? (u < v) : (u > v)) { sk[i] = v; sk[j] = u; }
                __syncthreads();
            }
            a = sk[tid]; b = sk[tid + 1024];
        }
        for (; st >= 1; st >>= 1) {
            bool low = (tid & st) == 0;
            bool descA = ((giA & sz) == 0);
            bool descB = ((giB & sz) == 0);
            a = cex_shfl(a, st, descA == low);
            b = cex_shfl(b, st, descB == low);
        }
    }
    if (last) {
        if (giA < k) {
            int j = (int)(~(unsigned)(a & 0xFFFFFFFFu));
            out_idx[giA] = j; invmap[j] = giA + 1;
        }
        if (giB < k) {
            int j = (int)(~(unsigned)(b & 0xFFFFFFFFu));
            out_idx[giB] = j; invmap[j] = giB + 1;
        }
    } else {
        keys[giA] = a; keys[giB] = b;
    }
}

// stage sz=4096 complete (strides 2048..1) per 4096-key block; writes all back
__global__ void k_stage4k_m(ull* __restrict__ keys) {
    __shared__ ull sk[4096];
    int tid = threadIdx.x;
    int base = blockIdx.x << 12;
    bool desc = ((base & 4096) == 0);
    ull k0 = keys[base + tid], k1 = keys[base + tid + 1024];
    ull k2 = keys[base + tid + 2048], k3 = keys[base + tid + 3072];
    cexr(k0, k2, desc); cexr(k1, k3, desc);          // stride 2048
    sk[tid] = k0; sk[tid + 1024] = k1; sk[tid + 2048] = k2; sk[tid + 3072] = k3;
    __syncthreads();
    for (int st = 1024; st >= 64; st >>= 1) {
        for (int pp = tid; pp < 2048; pp += 1024) {
            int i = ((pp & ~(st - 1)) << 1) | (pp & (st - 1));
            int j = i | st;
            ull u = sk[i], v = sk[j];
            if (desc ? (u < v) : (u > v)) { sk[i] = v; sk[j] = u; }
        }
        __syncthreads();
    }
    k0 = sk[tid]; k1 = sk[tid + 1024]; k2 = sk[tid + 2048]; k3 = sk[tid + 3072];
    for (int st = 32; st >= 1; st >>= 1) {
        bool low = (tid & st) == 0;
        k0 = cex_shfl(k0, st, desc == low);
        k1 = cex_shfl(k1, st, desc == low);
        k2 = cex_shfl(k2, st, desc == low);
        k3 = cex_shfl(k3, st, desc == low);
    }
    keys[base + tid] = k0; keys[base + tid + 1024] = k1;
    keys[base + tid + 2048] = k2; keys[base + tid + 3072] = k3;
}

// n=8192 final stage sz=8192 (desc everywhere); ranks [0,4096) = k; one block
__global__ void k_stage8k_f(const ull* __restrict__ keys, int* __restrict__ out_idx,
                            int* __restrict__ invmap) {
    __shared__ ull sk[4096];
    int tid = threadIdx.x;
    ull a0 = keys[tid],        a1 = keys[tid + 1024];
    ull a2 = keys[tid + 2048], a3 = keys[tid + 3072];
    ull b0 = keys[tid + 4096], b1 = keys[tid + 5120];
    ull b2 = keys[tid + 6144], b3 = keys[tid + 7168];
    cexr(a0, b0, true); cexr(a1, b1, true);          // stride 4096 (keep low half)
    cexr(a2, b2, true); cexr(a3, b3, true);
    cexr(a0, a2, true); cexr(a1, a3, true);          // stride 2048 within [0,4096)
    sk[tid] = a0; sk[tid + 1024] = a1; sk[tid + 2048] = a2; sk[tid + 3072] = a3;
    __syncthreads();
    for (int st = 1024; st >= 64; st >>= 1) {
        for (int pp = tid; pp < 2048; pp += 1024) {
            int i = ((pp & ~(st - 1)) << 1) | (pp & (st - 1));
            int j = i | st;
            ull u = sk[i], v = sk[j];
            if (u < v) { sk[i] = v; sk[j] = u; }     // desc
        }
        __syncthreads();
    }
    a0 = sk[tid]; a1 = sk[tid + 1024]; a2 = sk[tid + 2048]; a3 = sk[tid + 3072];
    for (int st = 32; st >= 1; st >>= 1) {
        bool low = (tid & st) == 0;
        a0 = cex_shfl(a0, st, low);
        a1 = cex_shfl(a1, st, low);
        a2 = cex_shfl(a2, st, low);
        a3 = cex_shfl(a3, st, low);
    }
    int p, j;
    p = tid;        j = (int)(~(unsigned)(a0 & 0xFFFFFFFFu)); out_idx[p] = j; invmap[j] = p + 1;
    p = tid + 1024; j = (int)(~(unsigned)(a1 & 0xFFFFFFFFu)); out_idx[p] = j; invmap[j] = p + 1;
    p = tid + 2048; j = (int)(~(unsigned)(a2 & 0xFFFFFFFFu)); out_idx[p] = j; invmap[j] = p + 1;
    p = tid + 3072; j = (int)(~(unsigned)(a3 & 0xFFFFFFFFu)); out_idx[p] = j; invmap[j] = p + 1;
}

// n=4096 final stage sz=4096; ranks [0,2048) = k; one block
__global__ void k_stage4k_f(const ull* __restrict__ keys, int* __restrict__ out_idx,
                            int* __restrict__ invmap) {
    __shared__ ull sk[2048];
    int tid = threadIdx.x;
    ull a0 = keys[tid],        a1 = keys[tid + 1024];
    ull a2 = keys[tid + 2048], a3 = keys[tid + 3072];
    cexr(a0, a2, true); cexr(a1, a3, true);          // stride 2048 (keep low half)
    sk[tid] = a0; sk[tid + 1024] = a1;
    __syncthreads();
    for (int st = 1024; st >= 64; st >>= 1) {
        int i = ((tid & ~(st - 1)) << 1) | (tid & (st - 1));
        int j = i | st;
        ull u = sk[i], v = sk[j];
        if (u < v) { sk[i] = v; sk[j] = u; }         // desc
        __syncthreads();
    }
    a0 = sk[tid]; a1 = sk[tid + 1024];
    for (int st = 32; st >= 1; st >>= 1) {
        bool low = (tid & st) == 0;
        a0 = cex_shfl(a0, st, low);
        a1 = cex_shfl(a1, st, low);
    }
    int p, j;
    p = tid;        j = (int)(~(unsigned)(a0 & 0xFFFFFFFFu)); out_idx[p] = j; invmap[j] = p + 1;
    p = tid + 1024; j = (int)(~(unsigned)(a1 & 0xFFFFFFFFu)); out_idx[p] = j; invmap[j] = p + 1;
}

// ---- atomic-free segment max/sum/count: one block per graph ----
__global__ void k_seg2(const float* __restrict__ x13, const int* __restrict__ gstart,
                       float* __restrict__ gmaxf, float* __restrict__ gsum,
                       int* __restrict__ gcnt) {
    __shared__ float sm[8][32], ss[8][32];
    int g = blockIdx.x;
    int j0 = gstart[g], j1 = gstart[g + 1];
    int t = threadIdx.x;
    int f = t & 31, r = t >> 5;
    float m = -INFINITY, s = 0.f;
    for (int j = j0 + r; j < j1; j += 8) {
        float v = x13[(j << 5) + f];
        m = fmaxf(m, v);
        s += v;
    }
    sm[r][f] = m; ss[r][f] = s;
    __syncthreads();
    if (t < 32) {
        float mm = sm[0][t], sss = ss[0][t];
        for (int i = 1; i < 8; i++) { mm = fmaxf(mm, sm[i][t]); sss += ss[i][t]; }
        gmaxf[(g << 5) + t] = mm;
        gsum[(g << 5) + t] = sss;
        if (t == 0) gcnt[g] = j1 - j0;
    }
}

// ---- head ----
__global__ void k_head(const float* __restrict__ gmaxf, const float* __restrict__ gsum,
                       const int* __restrict__ gcnt, const float* __restrict__ Wl1,
                       const float* __restrict__ Wc, const float* __restrict__ bc,
                       float* __restrict__ out) {
    __shared__ float h0[GG * 64];
    __shared__ float h1[GG * 64];
    __shared__ float lg[GG * CC];
    int tid = threadIdx.x;
    for (int t = tid; t < GG * 64; t += blockDim.x) {
        int g = t >> 6, c = t & 63;
        float v;
        if (c < 32) v = gmaxf[(g << 5) + c];
        else v = gsum[(g << 5) + (c - 32)] / (float)gcnt[g];
        h0[t] = eluf(v);
    }
    __syncthreads();
    for (int t = tid; t < GG * 64; t += blockDim.x) {
        int g = t >> 6, j = t & 63;
        float s = 0.f;
        for (int k = 0; k < 64; k++) s += h0[(g << 6) + k] * Wl1[k * 64 + j];
        h1[t] = eluf(s);
    }
    __syncthreads();
    for (int t = tid; t < GG * CC; t += blockDim.x) {
        int g = t / CC, c = t - g * CC;
        float s = bc[c];
        for (int k = 0; k < 64; k++) s += h1[(g << 6) + k] * Wc[k * CC + c];
        lg[t] = s;
    }
    __syncthreads();
    if (tid < GG) {
        int g = tid;
        float m = -1e30f;
        for (int c = 0; c < CC; c++) m = fmaxf(m, lg[g * CC + c]);
        float se = 0.f;
        for (int c = 0; c < CC; c++) se += expf(lg[g * CC + c] - m);
        float lse = m + logf(se);
        for (int c = 0; c < CC; c++) out[g * CC + c] = lg[g * CC + c] - lse;
    }
}

static void run_topk(const float* score, ull* keys, int n, int k, int* out_idx,
                     int* invmap, hipStream_t stream) {
    if (n == 2048) {
        k_wsort<<<1, 1024, 0, stream>>>(score, keys, 1, k, out_idx, invmap);
    } else if (n == 4096) {
        k_wsort<<<2, 1024, 0, stream>>>(score, keys, 0, k, out_idx, invmap);
        k_stage4k_f<<<1, 1024, 0, stream>>>(keys, out_idx, invmap);
    } else {                                   // 8192
        k_wsort<<<4, 1024, 0, stream>>>(score, keys, 0, k, out_idx, invmap);
        k_stage4k_m<<<2, 1024, 0, stream>>>(keys);
        k_stage8k_f<<<1, 1024, 0, stream>>>(keys, out_idx, invmap);
    }
}

extern "C" void kernel_launch(void* const* d_in, const int* in_sizes, int n_in,
                              void* d_out, int out_size, void* d_ws, size_t ws_size,
                              hipStream_t stream) {
    const float* x = (const float*)d_in[0];
    const int* ei = (const int*)d_in[1];
    const int* batch = (const int*)d_in[2];
    const float* W1 = (const float*)d_in[3];  const float* b1 = (const float*)d_in[4];
    const float* W2 = (const float*)d_in[5];  const float* b2 = (const float*)d_in[6];
    const float* W3 = (const float*)d_in[7];  const float* b3 = (const float*)d_in[8];
    const float* W4 = (const float*)d_in[9];  const float* b4 = (const float*)d_in[10];
    const float* W5 = (const float*)d_in[11]; const float* b5 = (const float*)d_in[12];
    const float* W6 = (const float*)d_in[13]; const float* b6 = (const float*)d_in[14];
    const float* W7 = (const float*)d_in[15]; const float* b7 = (const float*)d_in[16];
    const float* p1 = (const float*)d_in[17];
    const float* p2 = (const float*)d_in[18];
    const float* p3 = (const float*)d_in[19];
    const float* Wl1 = (const float*)d_in[20];
    const float* Wc = (const float*)d_in[21];
    const float* bc = (const float*)d_in[22];
    float* out = (float*)d_out;
    (void)in_sizes; (void)n_in; (void)out_size; (void)ws_size;

    char* w = (char*)d_ws;
    size_t off = 0;
    auto alloc = [&](size_t bytes) -> char* {
        char* p = w + off;
        off = (off + bytes + 255) & ~(size_t)255;
        return p;
    };

    // ---- zero-initialized span (single memset) ----
    size_t zero_begin = off;
    unsigned* bitmap = (unsigned*)alloc((size_t)NN * NN / 8);   // 8 MB
    int* cnt1 = (int*)alloc(NN * 4);
    int* pos2 = (int*)alloc(NN * 4);     // orig -> level2 rank+1 (0 = invalid)
    int* inv4 = (int*)alloc(KK1 * 4);    // level2 -> level3 rank+1
    int* inv6 = (int*)alloc(KK2 * 4);    // level3 -> level4 rank+1
    size_t zero_len = off - zero_begin;

    // ---- uninitialized scratch ----
    float* dinv2 = (float*)alloc(KK1 * 4);
    float* dinv3 = (float*)alloc(KK2 * 4);
    float* dinv4 = (float*)alloc(KK3 * 4);
    int* roff2 = (int*)alloc(KK1 * 4); int* deg2 = (int*)alloc(KK1 * 4);
    int* roff3 = (int*)alloc(KK2 * 4); int* deg3 = (int*)alloc(KK2 * 4);
    int* roff4 = (int*)alloc(KK3 * 4); int* deg4 = (int*)alloc(KK3 * 4);
    int* csr1 = (int*)alloc((size_t)NN * PITCH * 4);   // 4 MB ELL each
    int* csr2 = (int*)alloc((size_t)NN * PITCH * 4);
    int* csr3 = (int*)alloc((size_t)NN * PITCH * 4);
    int* csr4 = (int*)alloc((size_t)NN * PITCH * 4);
    float* xW = (float*)alloc((size_t)262144 * 4);
    float* x1 = (float*)alloc((size_t)NN * 32 * 4);
    float* x2 = (float*)alloc((size_t)KK1 * 32 * 4);
    float* x3 = (float*)alloc((size_t)KK1 * 64 * 4);
    float* x4 = (float*)alloc((size_t)KK2 * 64 * 4);
    float* x5 = (float*)alloc((size_t)KK2 * 128 * 4);
    float* x6 = (float*)alloc((size_t)KK3 * 128 * 4);
    float* x7 = (float*)alloc((size_t)KK3 * 256 * 4);
    float* x9 = (float*)alloc((size_t)KK2 * 128 * 4);
    float* x11 = (float*)alloc((size_t)KK1 * 64 * 4);
    float* x13 = (float*)alloc((size_t)NN * 32 * 4);
    float* score1 = (float*)alloc(NN * 4);
    float* score2 = (float*)alloc(KK1 * 4);
    float* score3 = (float*)alloc(KK2 * 4);
    int* i2 = (int*)alloc(KK1 * 4);
    int* i4 = (int*)alloc(KK2 * 4);
    int* i6 = (int*)alloc(KK3 * 4);
    ull* keys = (ull*)alloc((size_t)NN * 8);
    int* gstart = (int*)alloc((GG + 1) * 4);
    float* gmaxf = (float*)alloc(GG * 32 * 4);
    float* gsum = (float*)alloc(GG * 32 * 4);
    int* gcnt = (int*)alloc(GG * 4);

    hipMemsetAsync(w + zero_begin, 0, zero_len, stream);

    const int B = 256;
    // ---- fused: level-1 edge pass (dedup + ELL scatter + gbounds) || gemm1 ----
    k_init<<<1280, B, 0, stream>>>(ei, bitmap, cnt1, csr1, batch, gstart, x, W1, xW);

    // ---- gcn1 propagate (+score1), split S=8 ----
    k_prop<5, 1, 1, 3><<<2048, B, 0, stream>>>(csr1, nullptr, cnt1, nullptr, xW, b1,
                                               x1, p1, score1);

    // ---- pool1: top-4096 of 8192 (invmap=pos2 written in topk) ----
    run_topk(score1, keys, NN, KK1, i2, pos2, stream);
    k_pool_sub<1><<<512 + KK1 / 4, B, 0, stream>>>(x1, score1, i2, KK1, 32, x2, 512,
                                                   csr1, nullptr, cnt1, pos2,
                                                   csr2, roff2, deg2, dinv2);

    // ---- gcn2 (+score2), split S=4 ----
    k_gemm<<<dim3(KK1 / 32, 2), B, 0, stream>>>(x2, W2, xW, KK1, 32, 64);
    k_prop<6, 1, 0, 2><<<1024, B, 0, stream>>>(csr2, roff2, deg2, dinv2, xW, b2,
                                               x3, p2, score2);

    // ---- pool2: top-2048 of 4096 ----
    run_topk(score2, keys, KK1, KK2, i4, inv4, stream);
    k_pool_sub<0><<<512 + KK2 / 4, B, 0, stream>>>(x3, score2, i4, KK2, 64, x4, 512,
                                                   csr2, roff2, deg2, inv4,
                                                   csr3, roff3, deg3, dinv3);

    // ---- gcn3 (+score3), split S=2 ----
    k_gemm<<<dim3(KK2 / 32, 4), B, 0, stream>>>(x4, W3, xW, KK2, 64, 128);
    k_prop<7, 1, 0, 1><<<512, B, 0, stream>>>(csr3, roff3, deg3, dinv3, xW, b3,
                                              x5, p3, score3);

    // ---- pool3: top-1024 of 2048 ----
    run_topk(score3, keys, KK2, KK3, i6, inv6, stream);
    k_pool_sub<0><<<512 + KK3 / 4, B, 0, stream>>>(x5, score3, i6, KK3, 128, x6, 512,
                                                   csr3, roff3, deg3, inv6,
                                                   csr4, roff4, deg4, dinv4);

    // ---- gcn4, split S=2 ----
    k_gemm<<<dim3(KK3 / 32, 8), B, 0, stream>>>(x6, W4, xW, KK3, 128, 256);
    k_prop<8, 0, 0, 1><<<512, B, 0, stream>>>(csr4, roff4, deg4, dinv4, xW, b4,
                                              x7, nullptr, nullptr);

    // ---- gcn5 (unpool3 fused into X staging), split S=4 ----
    k_gemm_up<<<dim3(KK2 / 32, 4), B, 0, stream>>>(x7, inv6, x5, 256, 128,
                                                   W5, xW, KK2, 384, 128);
    k_prop<7, 0, 0, 2><<<1024, B, 0, stream>>>(csr3, roff3, deg3, dinv3, xW, b5,
                                               x9, nullptr, nullptr);

    // ---- gcn6 (unpool2 fused), split S=4 ----
    k_gemm_up<<<dim3(KK1 / 32, 2), B, 0, stream>>>(x9, inv4, x3, 128, 64,
                                                   W6, xW, KK1, 192, 64);
    k_prop<6, 0, 0, 2><<<1024, B, 0, stream>>>(csr2, roff2, deg2, dinv2, xW, b6,
                                               x11, nullptr, nullptr);

    // ---- gcn7 (unpool1 fused; original weighted adjacency), split S=8 ----
    k_gemm_up<<<dim3(NN / 32, 1), B, 0, stream>>>(x11, pos2, x1, 64, 32,
                                                  W7, xW, NN, 96, 32);
    k_prop<5, 0, 1, 3><<<2048, B, 0, stream>>>(csr1, nullptr, cnt1, nullptr, xW, b7,
                                               x13, nullptr, nullptr);

    // ---- readout ----
    k_seg2<<<GG, B, 0, stream>>>(x13, gstart, gmaxf, gsum, gcnt);
    k_head<<<1, 1024, 0, stream>>>(gmaxf, gsum, gcnt, Wl1, Wc, bc, out);
}